// Round 1
// baseline (464.724 us; speedup 1.0000x reference)
//
#include <hip/hip_runtime.h>
#include <math.h>

typedef unsigned short u16;
typedef __attribute__((ext_vector_type(4))) float f32x4;
typedef __attribute__((ext_vector_type(8))) short bf16x8;

#define GLOBAL_AS __attribute__((address_space(1)))
#define LDS_AS __attribute__((address_space(3)))

__device__ __forceinline__ u16 f2bf(float f) {
  unsigned u = __builtin_bit_cast(unsigned, f);
  unsigned lsb = (u >> 16) & 1u;
  u += 0x7fffu + lsb;            // round-to-nearest-even
  return (u16)(u >> 16);
}

__device__ __forceinline__ void gload16(const void* g, void* l) {
  __builtin_amdgcn_global_load_lds((const GLOBAL_AS void*)g, (LDS_AS void*)l, 16, 0, 0);
}

// ---------------- mean over axis 1: X[N][L][D] -> bf16 Y[N][D] ----------------
__global__ __launch_bounds__(256) void mean_rows_kernel(
    const float* __restrict__ X, u16* __restrict__ Y,
    int N, int L, int D, float inv)
{
  int id = blockIdx.x * 256 + threadIdx.x;
  int d4 = D >> 2;
  if (id >= N * d4) return;
  int n = id / d4, c = id % d4;
  const f32x4* x = (const f32x4*)X + (size_t)n * L * d4 + c;
  f32x4 s = {0.f, 0.f, 0.f, 0.f};
  for (int l = 0; l < L; ++l) s += x[(size_t)l * d4];
  s *= inv;
  ushort4 o;
  o.x = f2bf(s.x); o.y = f2bf(s.y); o.z = f2bf(s.z); o.w = f2bf(s.w);
  ((ushort4*)Y)[id] = o;
}

// ---------------- cast fp32 -> bf16 with zero padding ----------------
__global__ __launch_bounds__(256) void castpad_kernel(
    const float* __restrict__ src, u16* __restrict__ dst,
    int sr, int sc, int dr, int dc)
{
  int id = blockIdx.x * 256 + threadIdx.x;
  if (id >= dr * dc) return;
  int r = id / dc, c = id % dc;
  float v = (r < sr && c < sc) ? src[(size_t)r * sc + c] : 0.f;
  dst[id] = f2bf(v);
}

__global__ void padbias_kernel(const float* __restrict__ src, float* __restrict__ dst,
                               int n, int np)
{
  int t = threadIdx.x;
  if (t < np) dst[t] = (t < n) ? src[t] : 0.f;
}

// ---------------- NT bf16 MFMA GEMM: C[M,N] = alpha*A[M,K]@B[N,K]^T + bias ----
template<bool RELU, bool BF16OUT>
__global__ __launch_bounds__(256) void gemm_nt(
    const u16* __restrict__ A, const u16* __restrict__ B,
    const float* __restrict__ bias, float alpha,
    float* __restrict__ Cf, u16* __restrict__ Cb,
    int M, int N, int K)
{
  __shared__ u16 lA[128 * 32];
  __shared__ u16 lB[128 * 32];
  const int t = threadIdx.x;
  const int w = t >> 6, lane = t & 63;
  const int brow = blockIdx.y * 128, bcol = blockIdx.x * 128;
  const int wr = w >> 1, wc = w & 1;     // wave sub-tile 64x64

  f32x4 acc[4][4];
#pragma unroll
  for (int i = 0; i < 4; ++i)
#pragma unroll
    for (int j = 0; j < 4; ++j) acc[i][j] = (f32x4){0.f, 0.f, 0.f, 0.f};

  const int srow = t >> 2;               // 0..63
  const int scol = (t & 3) * 8;
  const size_t aoff0 = (size_t)(brow + srow) * K + scol;
  const size_t boff0 = (size_t)(bcol + srow) * K + scol;
  const size_t aoff1 = aoff0 + (size_t)64 * K;
  const size_t boff1 = boff0 + (size_t)64 * K;
  char* lAb = (char*)lA + w * 1024;      // wave-uniform LDS staging base
  char* lBb = (char*)lB + w * 1024;

  const int fr = lane & 15, fk = (lane >> 4) * 8;

  for (int k0 = 0; k0 < K; k0 += 32) {
    gload16(A + aoff0 + k0, lAb);
    gload16(A + aoff1 + k0, lAb + 4096);
    gload16(B + boff0 + k0, lBb);
    gload16(B + boff1 + k0, lBb + 4096);
    __syncthreads();

    bf16x8 av[4], bv[4];
#pragma unroll
    for (int mi = 0; mi < 4; ++mi)
      av[mi] = *(const bf16x8*)&lA[(wr * 64 + mi * 16 + fr) * 32 + fk];
#pragma unroll
    for (int ni = 0; ni < 4; ++ni)
      bv[ni] = *(const bf16x8*)&lB[(wc * 64 + ni * 16 + fr) * 32 + fk];

#pragma unroll
    for (int mi = 0; mi < 4; ++mi)
#pragma unroll
      for (int ni = 0; ni < 4; ++ni)
        acc[mi][ni] = __builtin_amdgcn_mfma_f32_16x16x32_bf16(av[mi], bv[ni], acc[mi][ni], 0, 0, 0);
    __syncthreads();
  }

  const int fq = lane >> 4;
#pragma unroll
  for (int mi = 0; mi < 4; ++mi) {
#pragma unroll
    for (int ni = 0; ni < 4; ++ni) {
      int col = bcol + wc * 64 + ni * 16 + fr;
      float bb = bias ? bias[col] : 0.f;
#pragma unroll
      for (int r = 0; r < 4; ++r) {
        int row = brow + wr * 64 + mi * 16 + fq * 4 + r;
        float v = acc[mi][ni][r] * alpha + bb;
        if (RELU) v = fmaxf(v, 0.f);
        if (BF16OUT) Cb[(size_t)row * N + col] = f2bf(v);
        else         Cf[(size_t)row * N + col] = v;
      }
    }
  }
}

// ---------------- cast + transpose: X[R][C] fp32 -> Y[R][C] bf16, YT[C][R] bf16
__global__ __launch_bounds__(256) void cast_transpose_kernel(
    const float* __restrict__ X, u16* __restrict__ Y, u16* __restrict__ YT,
    int R, int C)
{
  __shared__ float tile[32][33];
  int bx = blockIdx.x, by = blockIdx.y;
  int tx = threadIdx.x & 31, ty = threadIdx.x >> 5;   // ty 0..7
#pragma unroll
  for (int i = 0; i < 4; ++i) {
    int r = by * 32 + ty + i * 8, c = bx * 32 + tx;
    float v = X[(size_t)r * C + c];
    tile[ty + i * 8][tx] = v;
    Y[(size_t)r * C + c] = f2bf(v);
  }
  __syncthreads();
#pragma unroll
  for (int i = 0; i < 4; ++i) {
    int r = bx * 32 + ty + i * 8;   // C-dim index
    int c = by * 32 + tx;           // R-dim index
    YT[(size_t)r * R + c] = f2bf(tile[tx][ty + i * 8]);
  }
}

// ---------------- row softmax over 4096, fp32 in -> bf16 out ----------------
__global__ __launch_bounds__(256) void softmax_rows_kernel(
    const float* __restrict__ S, u16* __restrict__ P, int L)
{
  __shared__ float red[4];
  int row = blockIdx.x, t = threadIdx.x;
  const float* s = S + (size_t)row * L;
  float v[16];
  float mx = -INFINITY;
#pragma unroll
  for (int j = 0; j < 16; ++j) { v[j] = s[t + j * 256]; mx = fmaxf(mx, v[j]); }
#pragma unroll
  for (int off = 32; off > 0; off >>= 1) mx = fmaxf(mx, __shfl_xor(mx, off));
  if ((t & 63) == 0) red[t >> 6] = mx;
  __syncthreads();
  mx = fmaxf(fmaxf(red[0], red[1]), fmaxf(red[2], red[3]));
  __syncthreads();
  float sum = 0.f;
#pragma unroll
  for (int j = 0; j < 16; ++j) { v[j] = __expf(v[j] - mx); sum += v[j]; }
#pragma unroll
  for (int off = 32; off > 0; off >>= 1) sum += __shfl_xor(sum, off);
  if ((t & 63) == 0) red[t >> 6] = sum;
  __syncthreads();
  sum = red[0] + red[1] + red[2] + red[3];
  float inv = 1.f / sum;
  u16* pp = P + (size_t)row * L;
#pragma unroll
  for (int j = 0; j < 16; ++j) pp[t + j * 256] = f2bf(v[j] * inv);
}

// ---------------- LayerNorm rows (D=768) fp32 in -> bf16 out ----------------
__global__ __launch_bounds__(256) void ln_kernel(
    const float* __restrict__ X, const float* __restrict__ g,
    const float* __restrict__ b, u16* __restrict__ Y)
{
  __shared__ float red[4];
  int row = blockIdx.x, t = threadIdx.x;
  const float* x = X + (size_t)row * 768;
  float v0 = x[t], v1 = x[t + 256], v2 = x[t + 512];

  float s = v0 + v1 + v2;
#pragma unroll
  for (int off = 32; off > 0; off >>= 1) s += __shfl_xor(s, off);
  if ((t & 63) == 0) red[t >> 6] = s;
  __syncthreads();
  float mu = (red[0] + red[1] + red[2] + red[3]) * (1.f / 768.f);
  __syncthreads();

  float d0 = v0 - mu, d1 = v1 - mu, d2 = v2 - mu;
  float q = d0 * d0 + d1 * d1 + d2 * d2;
#pragma unroll
  for (int off = 32; off > 0; off >>= 1) q += __shfl_xor(q, off);
  if ((t & 63) == 0) red[t >> 6] = q;
  __syncthreads();
  float var = (red[0] + red[1] + red[2] + red[3]) * (1.f / 768.f);
  float inv = rsqrtf(var + 1e-5f);

  u16* y = Y + (size_t)row * 768;
  y[t]       = f2bf(d0 * inv * g[t]       + b[t]);
  y[t + 256] = f2bf(d1 * inv * g[t + 256] + b[t + 256]);
  y[t + 512] = f2bf(d2 * inv * g[t + 512] + b[t + 512]);
}

// ---------------- broadcast rows: H[N][D] -> O[N][Lv][D] (float4) ----------------
__global__ __launch_bounds__(256) void bcast_kernel(
    const f32x4* __restrict__ H, f32x4* __restrict__ O, int total, int L, int d4)
{
  int id = blockIdx.x * 256 + threadIdx.x;
  if (id >= total) return;
  int n = id / (L * d4);
  int c = id % d4;
  O[id] = H[(size_t)n * d4 + c];
}

extern "C" void kernel_launch(void* const* d_in, const int* in_sizes, int n_in,
                              void* d_out, int out_size, void* d_ws, size_t ws_size,
                              hipStream_t stream)
{
  const float* vision = (const float*)d_in[0];
  const float* text   = (const float*)d_in[1];
  const float* fc_w   = (const float*)d_in[2];
  const float* fc_b   = (const float*)d_in[3];
  const float* ln_g   = (const float*)d_in[4];
  const float* ln_b   = (const float*)d_in[5];
  const float* w1     = (const float*)d_in[6];
  const float* b1     = (const float*)d_in[7];
  const float* w2     = (const float*)d_in[8];
  const float* b2     = (const float*)d_in[9];
  float* out = (float*)d_out;

  const int N = 4096, Lv = 16, M = 4096, Lt = 77, Din = 512, D = 768, Dh = 192, Dhp = 256;

  char* p = (char*)d_ws;
  auto alloc = [&](size_t bytes) { char* r = p; p += (bytes + 255) & ~(size_t)255; return r; };
  u16*   mean_v = (u16*)alloc((size_t)N * D * 2);
  u16*   mean_t = (u16*)alloc((size_t)M * Din * 2);
  u16*   fcw_bf = (u16*)alloc((size_t)D * Din * 2);
  u16*   w1p    = (u16*)alloc((size_t)Dhp * D * 2);
  u16*   w2p    = (u16*)alloc((size_t)D * Dhp * 2);
  float* b1p    = (float*)alloc((size_t)Dhp * 4);
  float* t_f    = (float*)alloc((size_t)M * D * 4);
  u16*   t_bf   = (u16*)alloc((size_t)M * D * 2);
  u16*   tT_bf  = (u16*)alloc((size_t)D * M * 2);
  float* scores = (float*)alloc((size_t)N * M * 4);
  u16*   aff    = (u16*)alloc((size_t)N * M * 2);
  u16*   ln_o   = (u16*)alloc((size_t)N * D * 2);
  u16*   h1     = (u16*)alloc((size_t)N * Dhp * 2);
  float* agg = t_f;     // t_f free after cast_transpose
  float* h2  = scores;  // scores free after softmax

  // 1. means
  mean_rows_kernel<<<(N * (D / 4) + 255) / 256, 256, 0, stream>>>(vision, mean_v, N, Lv, D, 1.f / 16.f);
  mean_rows_kernel<<<(M * (Din / 4) + 255) / 256, 256, 0, stream>>>(text, mean_t, M, Lt, Din, 1.f / 77.f);

  // 2. weight casts (+ zero pad for MLP dims)
  castpad_kernel<<<(D * Din + 255) / 256, 256, 0, stream>>>(fc_w, fcw_bf, D, Din, D, Din);
  castpad_kernel<<<(Dhp * D + 255) / 256, 256, 0, stream>>>(w1, w1p, Dh, D, Dhp, D);
  castpad_kernel<<<(D * Dhp + 255) / 256, 256, 0, stream>>>(w2, w2p, D, Dh, D, Dhp);
  padbias_kernel<<<1, 256, 0, stream>>>(b1, b1p, Dh, Dhp);

  // 3. t = mean_t @ fc_w^T + fc_b   [M, D] fp32
  gemm_nt<false, false><<<dim3(D / 128, M / 128), 256, 0, stream>>>(
      mean_t, fcw_bf, fc_b, 1.f, t_f, nullptr, M, D, Din);

  // 4. t -> bf16 row-major + transposed
  cast_transpose_kernel<<<dim3(D / 32, M / 32), 256, 0, stream>>>(t_f, t_bf, tT_bf, M, D);

  // 5. scores = mean_v @ t^T / sqrt(D)   [N, M] fp32
  gemm_nt<false, false><<<dim3(M / 128, N / 128), 256, 0, stream>>>(
      mean_v, t_bf, nullptr, 1.f / sqrtf(768.f), scores, nullptr, N, M, D);

  // 6. softmax rows -> aff bf16
  softmax_rows_kernel<<<N, 256, 0, stream>>>(scores, aff, M);

  // 7. agg = aff @ t   [N, D] fp32   (B = tT, NT form)
  gemm_nt<false, false><<<dim3(D / 128, N / 128), 256, 0, stream>>>(
      aff, tT_bf, nullptr, 1.f, agg, nullptr, N, D, M);

  // 8. LayerNorm -> bf16
  ln_kernel<<<N, 256, 0, stream>>>(agg, ln_g, ln_b, ln_o);

  // 9. h1 = relu(ln @ w1^T + b1)   [N, Dhp] bf16  (padded 192->256)
  gemm_nt<true, true><<<dim3(Dhp / 128, N / 128), 256, 0, stream>>>(
      ln_o, w1p, b1p, 1.f, nullptr, h1, N, Dhp, D);

  // 10. h2 = h1 @ w2^T + b2   [N, D] fp32
  gemm_nt<false, false><<<dim3(D / 128, N / 128), 256, 0, stream>>>(
      h1, w2p, b2, 1.f, h2, nullptr, N, D, Dhp);

  // 11. broadcast to [N, Lv, D]
  int total4 = N * Lv * (D / 4);
  bcast_kernel<<<(total4 + 255) / 256, 256, 0, stream>>>(
      (const f32x4*)h2, (f32x4*)out, total4, Lv, D / 4);
}

// Round 2
// 412.764 us; speedup vs baseline: 1.1259x; 1.1259x over previous
//
#include <hip/hip_runtime.h>
#include <math.h>

typedef unsigned short u16;
typedef __attribute__((ext_vector_type(4))) float f32x4;
typedef __attribute__((ext_vector_type(8))) short bf16x8;

#define GLOBAL_AS __attribute__((address_space(1)))
#define LDS_AS __attribute__((address_space(3)))

__device__ __forceinline__ u16 f2bf(float f) {
  unsigned u = __builtin_bit_cast(unsigned, f);
  unsigned lsb = (u >> 16) & 1u;
  u += 0x7fffu + lsb;            // round-to-nearest-even
  return (u16)(u >> 16);
}

__device__ __forceinline__ void gload16(const void* g, void* l) {
  __builtin_amdgcn_global_load_lds((const GLOBAL_AS void*)g, (LDS_AS void*)l, 16, 0, 0);
}

// ---------------- mean over axis 1: X[N][L][D] -> bf16 Y[N][D] ----------------
__global__ __launch_bounds__(256) void mean_rows_kernel(
    const float* __restrict__ X, u16* __restrict__ Y,
    int N, int L, int D, float inv)
{
  int id = blockIdx.x * 256 + threadIdx.x;
  int d4 = D >> 2;
  if (id >= N * d4) return;
  int n = id / d4, c = id % d4;
  const f32x4* x = (const f32x4*)X + (size_t)n * L * d4 + c;
  f32x4 s = {0.f, 0.f, 0.f, 0.f};
  for (int l = 0; l < L; ++l) s += x[(size_t)l * d4];
  s *= inv;
  ushort4 o;
  o.x = f2bf(s.x); o.y = f2bf(s.y); o.z = f2bf(s.z); o.w = f2bf(s.w);
  ((ushort4*)Y)[id] = o;
}

// ------- fused weight prep: cast fc_w, pad-cast w1,w2, pad b1 (one launch) ----
__global__ __launch_bounds__(256) void prep_kernel(
    const float* __restrict__ fc_w, const float* __restrict__ w1,
    const float* __restrict__ w2, const float* __restrict__ b1,
    u16* __restrict__ fcw_bf, u16* __restrict__ w1p, u16* __restrict__ w2p,
    float* __restrict__ b1p)
{
  const int n_fcw = 768 * 512;          // D x Din
  const int n_w1  = 256 * 768;          // Dhp x D (src 192 x 768)
  const int n_w2  = 768 * 256;          // D x Dhp (src 768 x 192)
  int id = blockIdx.x * 256 + threadIdx.x;
  if (id < n_fcw) {
    fcw_bf[id] = f2bf(fc_w[id]);
    return;
  }
  id -= n_fcw;
  if (id < n_w1) {
    int r = id / 768;
    w1p[id] = (r < 192) ? f2bf(w1[id]) : (u16)0;
    return;
  }
  id -= n_w1;
  if (id < n_w2) {
    int r = id / 256, c = id % 256;
    w2p[id] = (c < 192) ? f2bf(w2[(size_t)r * 192 + c]) : (u16)0;
    return;
  }
  id -= n_w2;
  if (id < 256) b1p[id] = (id < 192) ? b1[id] : 0.f;
}

// ---------------- NT bf16 MFMA GEMM: C[M,N] = alpha*A[M,K]@B[N,K]^T + bias ----
// 128x128 tile, BK=32, double-buffered LDS with 2-phase prefetch pipeline.
// blockIdx.z = split-K slice: A/B advance by kofs elements, Cf by cofs.
template<bool RELU, bool BF16OUT>
__global__ __launch_bounds__(256) void gemm_nt(
    const u16* __restrict__ A, const u16* __restrict__ B,
    const float* __restrict__ bias, float alpha,
    float* __restrict__ Cf, u16* __restrict__ Cb,
    int M, int N, int K, int lda, int ldb,
    int kofs, long long cofs)
{
  __shared__ u16 lA[2][128 * 32];
  __shared__ u16 lB[2][128 * 32];
  const int t = threadIdx.x;
  const int w = t >> 6, lane = t & 63;
  const int brow = blockIdx.y * 128, bcol = blockIdx.x * 128;
  const int wr = w >> 1, wc = w & 1;     // wave sub-tile 64x64
  const int kz = blockIdx.z;

  A += (size_t)kz * kofs;
  B += (size_t)kz * kofs;
  Cf += kz * cofs;

  f32x4 acc[4][4];
#pragma unroll
  for (int i = 0; i < 4; ++i)
#pragma unroll
    for (int j = 0; j < 4; ++j) acc[i][j] = (f32x4){0.f, 0.f, 0.f, 0.f};

  const int srow = t >> 2;               // 0..63
  const int scol = (t & 3) * 8;
  const size_t aoff0 = (size_t)(brow + srow) * lda + scol;
  const size_t boff0 = (size_t)(bcol + srow) * ldb + scol;
  const size_t aoff1 = aoff0 + (size_t)64 * lda;
  const size_t boff1 = boff0 + (size_t)64 * ldb;

  const int fr = lane & 15, fk = (lane >> 4) * 8;
  const int NT = K >> 5;

  auto stage = [&](int ti, int b) {
    const int k0 = ti << 5;
    char* la = (char*)lA + b * 8192 + w * 1024;
    char* lb = (char*)lB + b * 8192 + w * 1024;
    gload16(A + aoff0 + k0, la);
    gload16(A + aoff1 + k0, la + 4096);
    gload16(B + boff0 + k0, lb);
    gload16(B + boff1 + k0, lb + 4096);
  };

  stage(0, 0);
  int cur = 0;
  for (int ti = 0; ti < NT; ++ti, cur ^= 1) {
    __syncthreads();                 // drains vmcnt -> buf[cur] ready; protects buf reuse
    if (ti + 1 < NT) stage(ti + 1, cur ^ 1);   // prefetch flies under compute

    const u16* la = lA[cur];
    const u16* lb = lB[cur];
    bf16x8 av[4], bv[4];
#pragma unroll
    for (int mi = 0; mi < 4; ++mi)
      av[mi] = *(const bf16x8*)&la[(wr * 64 + mi * 16 + fr) * 32 + fk];
#pragma unroll
    for (int ni = 0; ni < 4; ++ni)
      bv[ni] = *(const bf16x8*)&lb[(wc * 64 + ni * 16 + fr) * 32 + fk];

#pragma unroll
    for (int mi = 0; mi < 4; ++mi)
#pragma unroll
      for (int ni = 0; ni < 4; ++ni)
        acc[mi][ni] = __builtin_amdgcn_mfma_f32_16x16x32_bf16(av[mi], bv[ni], acc[mi][ni], 0, 0, 0);
  }

  const int fq = lane >> 4;
#pragma unroll
  for (int mi = 0; mi < 4; ++mi) {
#pragma unroll
    for (int ni = 0; ni < 4; ++ni) {
      int col = bcol + wc * 64 + ni * 16 + fr;
      float bb = bias ? bias[col] : 0.f;
#pragma unroll
      for (int r = 0; r < 4; ++r) {
        int row = brow + wr * 64 + mi * 16 + fq * 4 + r;
        float v = acc[mi][ni][r] * alpha + bb;
        if (RELU) v = fmaxf(v, 0.f);
        if (BF16OUT) Cb[(size_t)row * N + col] = f2bf(v);
        else         Cf[(size_t)row * N + col] = v;
      }
    }
  }
}

// ---------------- cast + transpose: X[R][C] fp32 -> Y[R][C] bf16, YT[C][R] bf16
__global__ __launch_bounds__(256) void cast_transpose_kernel(
    const float* __restrict__ X, u16* __restrict__ Y, u16* __restrict__ YT,
    int R, int C)
{
  __shared__ float tile[32][33];
  int bx = blockIdx.x, by = blockIdx.y;
  int tx = threadIdx.x & 31, ty = threadIdx.x >> 5;   // ty 0..7
#pragma unroll
  for (int i = 0; i < 4; ++i) {
    int r = by * 32 + ty + i * 8, c = bx * 32 + tx;
    float v = X[(size_t)r * C + c];
    tile[ty + i * 8][tx] = v;
    Y[(size_t)r * C + c] = f2bf(v);
  }
  __syncthreads();
#pragma unroll
  for (int i = 0; i < 4; ++i) {
    int r = bx * 32 + ty + i * 8;   // C-dim index
    int c = by * 32 + tx;           // R-dim index
    YT[(size_t)r * R + c] = f2bf(tile[tx][ty + i * 8]);
  }
}

// ---------------- row softmax over 4096, fp32 in -> bf16 out ----------------
__global__ __launch_bounds__(256) void softmax_rows_kernel(
    const float* __restrict__ S, u16* __restrict__ P, int L)
{
  __shared__ float red[4];
  int row = blockIdx.x, t = threadIdx.x;
  const float* s = S + (size_t)row * L;
  float v[16];
  float mx = -INFINITY;
#pragma unroll
  for (int j = 0; j < 16; ++j) { v[j] = s[t + j * 256]; mx = fmaxf(mx, v[j]); }
#pragma unroll
  for (int off = 32; off > 0; off >>= 1) mx = fmaxf(mx, __shfl_xor(mx, off));
  if ((t & 63) == 0) red[t >> 6] = mx;
  __syncthreads();
  mx = fmaxf(fmaxf(red[0], red[1]), fmaxf(red[2], red[3]));
  __syncthreads();
  float sum = 0.f;
#pragma unroll
  for (int j = 0; j < 16; ++j) { v[j] = __expf(v[j] - mx); sum += v[j]; }
#pragma unroll
  for (int off = 32; off > 0; off >>= 1) sum += __shfl_xor(sum, off);
  if ((t & 63) == 0) red[t >> 6] = sum;
  __syncthreads();
  sum = red[0] + red[1] + red[2] + red[3];
  float inv = 1.f / sum;
  u16* pp = P + (size_t)row * L;
#pragma unroll
  for (int j = 0; j < 16; ++j) pp[t + j * 256] = f2bf(v[j] * inv);
}

// ------- LayerNorm rows (D=768) over sum of two split-K partials -> bf16 -----
__global__ __launch_bounds__(256) void ln2_kernel(
    const float* __restrict__ X0, const float* __restrict__ X1,
    const float* __restrict__ g, const float* __restrict__ b,
    u16* __restrict__ Y)
{
  __shared__ float red[4];
  int row = blockIdx.x, t = threadIdx.x;
  const float* x0 = X0 + (size_t)row * 768;
  const float* x1 = X1 + (size_t)row * 768;
  float v0 = x0[t] + x1[t];
  float v1 = x0[t + 256] + x1[t + 256];
  float v2 = x0[t + 512] + x1[t + 512];

  float s = v0 + v1 + v2;
#pragma unroll
  for (int off = 32; off > 0; off >>= 1) s += __shfl_xor(s, off);
  if ((t & 63) == 0) red[t >> 6] = s;
  __syncthreads();
  float mu = (red[0] + red[1] + red[2] + red[3]) * (1.f / 768.f);
  __syncthreads();

  float d0 = v0 - mu, d1 = v1 - mu, d2 = v2 - mu;
  float q = d0 * d0 + d1 * d1 + d2 * d2;
#pragma unroll
  for (int off = 32; off > 0; off >>= 1) q += __shfl_xor(q, off);
  if ((t & 63) == 0) red[t >> 6] = q;
  __syncthreads();
  float var = (red[0] + red[1] + red[2] + red[3]) * (1.f / 768.f);
  float inv = rsqrtf(var + 1e-5f);

  u16* y = Y + (size_t)row * 768;
  y[t]       = f2bf(d0 * inv * g[t]       + b[t]);
  y[t + 256] = f2bf(d1 * inv * g[t + 256] + b[t + 256]);
  y[t + 512] = f2bf(d2 * inv * g[t + 512] + b[t + 512]);
}

// ---------------- broadcast rows: H[N][D] -> O[N][Lv][D] (float4) ----------------
__global__ __launch_bounds__(256) void bcast_kernel(
    const f32x4* __restrict__ H, f32x4* __restrict__ O, int total, int L, int d4)
{
  int id = blockIdx.x * 256 + threadIdx.x;
  if (id >= total) return;
  int n = id / (L * d4);
  int c = id % d4;
  O[id] = H[(size_t)n * d4 + c];
}

extern "C" void kernel_launch(void* const* d_in, const int* in_sizes, int n_in,
                              void* d_out, int out_size, void* d_ws, size_t ws_size,
                              hipStream_t stream)
{
  const float* vision = (const float*)d_in[0];
  const float* text   = (const float*)d_in[1];
  const float* fc_w   = (const float*)d_in[2];
  const float* fc_b   = (const float*)d_in[3];
  const float* ln_g   = (const float*)d_in[4];
  const float* ln_b   = (const float*)d_in[5];
  const float* w1     = (const float*)d_in[6];
  const float* b1     = (const float*)d_in[7];
  const float* w2     = (const float*)d_in[8];
  const float* b2     = (const float*)d_in[9];
  float* out = (float*)d_out;

  const int N = 4096, Lv = 16, M = 4096, Din = 512, D = 768, Dhp = 256;

  char* p = (char*)d_ws;
  auto alloc = [&](size_t bytes) { char* r = p; p += (bytes + 255) & ~(size_t)255; return r; };
  u16*   mean_v = (u16*)alloc((size_t)N * D * 2);
  u16*   mean_t = (u16*)alloc((size_t)M * Din * 2);
  u16*   fcw_bf = (u16*)alloc((size_t)D * Din * 2);
  u16*   w1p    = (u16*)alloc((size_t)Dhp * D * 2);
  u16*   w2p    = (u16*)alloc((size_t)D * Dhp * 2);
  float* b1p    = (float*)alloc((size_t)Dhp * 4);
  float* t_f    = (float*)alloc((size_t)M * D * 4);
  u16*   t_bf   = (u16*)alloc((size_t)M * D * 2);
  u16*   tT_bf  = (u16*)alloc((size_t)D * M * 2);
  float* scores = (float*)alloc((size_t)N * M * 4);
  u16*   aff    = (u16*)alloc((size_t)N * M * 2);
  u16*   ln_o   = (u16*)alloc((size_t)N * D * 2);
  u16*   h1     = (u16*)alloc((size_t)N * Dhp * 2);
  float* aggp1  = (float*)alloc((size_t)N * D * 4);   // split-K partial 1
  float* aggp0 = t_f;   // t_f free after cast_transpose; split-K partial 0
  float* h2    = scores;

  // 1. means
  mean_rows_kernel<<<(N * (D / 4) + 255) / 256, 256, 0, stream>>>(vision, mean_v, N, Lv, D, 1.f / 16.f);
  mean_rows_kernel<<<(M * (Din / 4) + 255) / 256, 256, 0, stream>>>(text, mean_t, M, 77, Din, 1.f / 77.f);

  // 2. weight prep (fused)
  {
    int total = 768 * 512 + 256 * 768 + 768 * 256 + 256;
    prep_kernel<<<(total + 255) / 256, 256, 0, stream>>>(fc_w, w1, w2, b1, fcw_bf, w1p, w2p, b1p);
  }

  // 3. t = mean_t @ fc_w^T + fc_b   [M, D] fp32
  gemm_nt<false, false><<<dim3(D / 128, M / 128), 256, 0, stream>>>(
      mean_t, fcw_bf, fc_b, 1.f, t_f, nullptr, M, D, Din, Din, Din, 0, 0);

  // 4. t -> bf16 row-major + transposed
  cast_transpose_kernel<<<dim3(D / 32, M / 32), 256, 0, stream>>>(t_f, t_bf, tT_bf, M, D);

  // 5. scores = mean_v @ t^T / sqrt(D)   [N, M] fp32
  gemm_nt<false, false><<<dim3(M / 128, N / 128), 256, 0, stream>>>(
      mean_v, t_bf, nullptr, 1.f / sqrtf(768.f), scores, nullptr, N, M, D, D, D, 0, 0);

  // 6. softmax rows -> aff bf16
  softmax_rows_kernel<<<N, 256, 0, stream>>>(scores, aff, M);

  // 7. agg = aff @ t  [N, D] fp32, split-K=2 partials (B = tT, NT form)
  gemm_nt<false, false><<<dim3(D / 128, N / 128, 2), 256, 0, stream>>>(
      aff, tT_bf, nullptr, 1.f, aggp0, nullptr, N, D, M / 2, M, M,
      M / 2, (long long)(aggp1 - aggp0));

  // 8. LayerNorm over partial sum -> bf16
  ln2_kernel<<<N, 256, 0, stream>>>(aggp0, aggp1, ln_g, ln_b, ln_o);

  // 9. h1 = relu(ln @ w1^T + b1)   [N, Dhp] bf16  (padded 192->256)
  gemm_nt<true, true><<<dim3(Dhp / 128, N / 128), 256, 0, stream>>>(
      ln_o, w1p, b1p, 1.f, nullptr, h1, N, Dhp, D, D, D, 0, 0);

  // 10. h2 = h1 @ w2^T + b2   [N, D] fp32
  gemm_nt<false, false><<<dim3(D / 128, N / 128), 256, 0, stream>>>(
      h1, w2p, b2, 1.f, h2, nullptr, N, D, Dhp, Dhp, Dhp, 0, 0);

  // 11. broadcast to [N, Lv, D]
  int total4 = N * Lv * (D / 4);
  bcast_kernel<<<(total4 + 255) / 256, 256, 0, stream>>>(
      (const f32x4*)h2, (f32x4*)out, total4, Lv, D / 4);
}

// Round 3
// 400.337 us; speedup vs baseline: 1.1608x; 1.0310x over previous
//
#include <hip/hip_runtime.h>
#include <math.h>

typedef unsigned short u16;
typedef __attribute__((ext_vector_type(4))) float f32x4;
typedef __attribute__((ext_vector_type(8))) short bf16x8;

#define GLOBAL_AS __attribute__((address_space(1)))
#define LDS_AS __attribute__((address_space(3)))

__device__ __forceinline__ u16 f2bf(float f) {
  unsigned u = __builtin_bit_cast(unsigned, f);
  unsigned lsb = (u >> 16) & 1u;
  u += 0x7fffu + lsb;            // round-to-nearest-even
  return (u16)(u >> 16);
}

__device__ __forceinline__ float bf2f(u16 b) {
  return __builtin_bit_cast(float, ((unsigned)b) << 16);
}

__device__ __forceinline__ void gload16(const void* g, void* l) {
  __builtin_amdgcn_global_load_lds((const GLOBAL_AS void*)g, (LDS_AS void*)l, 16, 0, 0);
}

// ---- fused prologue: mean_v, mean_t, cast fc_w, pad-cast w1,w2, pad b1 ------
// All segment sizes are multiples of 256 (except the 256-thread b1 tail), so
// branching is block-uniform.
__global__ __launch_bounds__(256) void prologue_kernel(
    const float* __restrict__ vision, const float* __restrict__ text,
    const float* __restrict__ fc_w, const float* __restrict__ w1,
    const float* __restrict__ w2, const float* __restrict__ b1,
    u16* __restrict__ mean_v, u16* __restrict__ mean_t,
    u16* __restrict__ fcw_bf, u16* __restrict__ w1p, u16* __restrict__ w2p,
    float* __restrict__ b1p)
{
  const int n_mv = 4096 * 192;   // N * D/4
  const int n_mt = 4096 * 128;   // M * Din/4
  const int n_fcw = 768 * 512;
  const int n_w1 = 256 * 768;
  const int n_w2 = 768 * 256;
  int id = blockIdx.x * 256 + threadIdx.x;

  if (id < n_mv) {               // mean over Lv=16 of vision[N][16][768]
    int n = id / 192, c = id % 192;
    const f32x4* x = (const f32x4*)vision + (size_t)n * 16 * 192 + c;
    f32x4 s = {0.f, 0.f, 0.f, 0.f};
#pragma unroll
    for (int l = 0; l < 16; ++l) s += x[(size_t)l * 192];
    s *= (1.f / 16.f);
    ushort4 o; o.x = f2bf(s.x); o.y = f2bf(s.y); o.z = f2bf(s.z); o.w = f2bf(s.w);
    ((ushort4*)mean_v)[id] = o;
    return;
  }
  id -= n_mv;
  if (id < n_mt) {               // mean over Lt=77 of text[M][77][512]
    int n = id / 128, c = id % 128;
    const f32x4* x = (const f32x4*)text + (size_t)n * 77 * 128 + c;
    f32x4 s = {0.f, 0.f, 0.f, 0.f};
    for (int l = 0; l < 77; ++l) s += x[(size_t)l * 128];
    s *= (1.f / 77.f);
    ushort4 o; o.x = f2bf(s.x); o.y = f2bf(s.y); o.z = f2bf(s.z); o.w = f2bf(s.w);
    ((ushort4*)mean_t)[id] = o;
    return;
  }
  id -= n_mt;
  if (id < n_fcw) { fcw_bf[id] = f2bf(fc_w[id]); return; }
  id -= n_fcw;
  if (id < n_w1) {               // w1 [192][768] -> [256][768] zero-pad rows
    int r = id / 768;
    w1p[id] = (r < 192) ? f2bf(w1[id]) : (u16)0;
    return;
  }
  id -= n_w1;
  if (id < n_w2) {               // w2 [768][192] -> [768][256] zero-pad cols
    int r = id / 256, c = id % 256;
    w2p[id] = (c < 192) ? f2bf(w2[(size_t)r * 192 + c]) : (u16)0;
    return;
  }
  id -= n_w2;
  if (id < 256) b1p[id] = (id < 192) ? b1[id] : 0.f;
}

// ---------------- NT bf16 MFMA GEMM: C[M,N] = alpha*A[M,K]@B[N,K]^T + bias ----
// 128x128 tile, BK=32, double-buffered LDS, 2-phase prefetch pipeline.
// blockIdx.z = split-K slice: A/B advance by kofs elements, Cf by cofs.
template<bool RELU, bool BF16OUT>
__global__ __launch_bounds__(256) void gemm_nt(
    const u16* __restrict__ A, const u16* __restrict__ B,
    const float* __restrict__ bias, float alpha,
    float* __restrict__ Cf, u16* __restrict__ Cb,
    int M, int N, int K, int lda, int ldb,
    int kofs, long long cofs)
{
  __shared__ u16 lA[2][128 * 32];
  __shared__ u16 lB[2][128 * 32];
  const int t = threadIdx.x;
  const int w = t >> 6, lane = t & 63;
  const int brow = blockIdx.y * 128, bcol = blockIdx.x * 128;
  const int wr = w >> 1, wc = w & 1;     // wave sub-tile 64x64
  const int kz = blockIdx.z;

  A += (size_t)kz * kofs;
  B += (size_t)kz * kofs;
  Cf += kz * cofs;

  f32x4 acc[4][4];
#pragma unroll
  for (int i = 0; i < 4; ++i)
#pragma unroll
    for (int j = 0; j < 4; ++j) acc[i][j] = (f32x4){0.f, 0.f, 0.f, 0.f};

  const int srow = t >> 2;               // 0..63
  const int scol = (t & 3) * 8;
  const size_t aoff0 = (size_t)(brow + srow) * lda + scol;
  const size_t boff0 = (size_t)(bcol + srow) * ldb + scol;
  const size_t aoff1 = aoff0 + (size_t)64 * lda;
  const size_t boff1 = boff0 + (size_t)64 * ldb;

  const int fr = lane & 15, fk = (lane >> 4) * 8;
  const int NT = K >> 5;

  auto stage = [&](int ti, int b) {
    const int k0 = ti << 5;
    char* la = (char*)lA + b * 8192 + w * 1024;
    char* lb = (char*)lB + b * 8192 + w * 1024;
    gload16(A + aoff0 + k0, la);
    gload16(A + aoff1 + k0, la + 4096);
    gload16(B + boff0 + k0, lb);
    gload16(B + boff1 + k0, lb + 4096);
  };

  stage(0, 0);
  int cur = 0;
  for (int ti = 0; ti < NT; ++ti, cur ^= 1) {
    __syncthreads();                 // drains vmcnt -> buf[cur] ready
    if (ti + 1 < NT) stage(ti + 1, cur ^ 1);   // prefetch flies under compute

    const u16* la = lA[cur];
    const u16* lb = lB[cur];
    bf16x8 av[4], bv[4];
#pragma unroll
    for (int mi = 0; mi < 4; ++mi)
      av[mi] = *(const bf16x8*)&la[(wr * 64 + mi * 16 + fr) * 32 + fk];
#pragma unroll
    for (int ni = 0; ni < 4; ++ni)
      bv[ni] = *(const bf16x8*)&lb[(wc * 64 + ni * 16 + fr) * 32 + fk];

#pragma unroll
    for (int mi = 0; mi < 4; ++mi)
#pragma unroll
      for (int ni = 0; ni < 4; ++ni)
        acc[mi][ni] = __builtin_amdgcn_mfma_f32_16x16x32_bf16(av[mi], bv[ni], acc[mi][ni], 0, 0, 0);
  }

  const int fq = lane >> 4;
#pragma unroll
  for (int mi = 0; mi < 4; ++mi) {
#pragma unroll
    for (int ni = 0; ni < 4; ++ni) {
      int col = bcol + wc * 64 + ni * 16 + fr;
      float bb = bias ? bias[col] : 0.f;
#pragma unroll
      for (int r = 0; r < 4; ++r) {
        int row = brow + wr * 64 + mi * 16 + fq * 4 + r;
        float v = acc[mi][ni][r] * alpha + bb;
        if (RELU) v = fmaxf(v, 0.f);
        if (BF16OUT) Cb[(size_t)row * N + col] = f2bf(v);
        else         Cf[(size_t)row * N + col] = v;
      }
    }
  }
}

// ---------------- cast + transpose: X[R][C] fp32 -> Y[R][C] bf16, YT[C][R] bf16
__global__ __launch_bounds__(256) void cast_transpose_kernel(
    const float* __restrict__ X, u16* __restrict__ Y, u16* __restrict__ YT,
    int R, int C)
{
  __shared__ float tile[32][33];
  int bx = blockIdx.x, by = blockIdx.y;
  int tx = threadIdx.x & 31, ty = threadIdx.x >> 5;   // ty 0..7
#pragma unroll
  for (int i = 0; i < 4; ++i) {
    int r = by * 32 + ty + i * 8, c = bx * 32 + tx;
    float v = X[(size_t)r * C + c];
    tile[ty + i * 8][tx] = v;
    Y[(size_t)r * C + c] = f2bf(v);
  }
  __syncthreads();
#pragma unroll
  for (int i = 0; i < 4; ++i) {
    int r = bx * 32 + ty + i * 8;   // C-dim index
    int c = by * 32 + tx;           // R-dim index
    YT[(size_t)r * R + c] = f2bf(tile[tx][ty + i * 8]);
  }
}

// ------------- row softmax over 4096, bf16 in -> bf16 out --------------------
__global__ __launch_bounds__(256) void softmax_rows_kernel(
    const u16* __restrict__ S, u16* __restrict__ P)
{
  __shared__ float red[4];
  int row = blockIdx.x, t = threadIdx.x;
  const u16* s = S + (size_t)row * 4096;
  bf16x8 c0 = *(const bf16x8*)&s[t * 8];
  bf16x8 c1 = *(const bf16x8*)&s[2048 + t * 8];
  float v[16];
#pragma unroll
  for (int j = 0; j < 8; ++j) v[j]     = bf2f((u16)c0[j]);
#pragma unroll
  for (int j = 0; j < 8; ++j) v[j + 8] = bf2f((u16)c1[j]);

  float mx = -INFINITY;
#pragma unroll
  for (int j = 0; j < 16; ++j) mx = fmaxf(mx, v[j]);
#pragma unroll
  for (int off = 32; off > 0; off >>= 1) mx = fmaxf(mx, __shfl_xor(mx, off));
  if ((t & 63) == 0) red[t >> 6] = mx;
  __syncthreads();
  mx = fmaxf(fmaxf(red[0], red[1]), fmaxf(red[2], red[3]));
  __syncthreads();
  float sum = 0.f;
#pragma unroll
  for (int j = 0; j < 16; ++j) { v[j] = __expf(v[j] - mx); sum += v[j]; }
#pragma unroll
  for (int off = 32; off > 0; off >>= 1) sum += __shfl_xor(sum, off);
  if ((t & 63) == 0) red[t >> 6] = sum;
  __syncthreads();
  sum = red[0] + red[1] + red[2] + red[3];
  float inv = 1.f / sum;
  bf16x8 o0, o1;
#pragma unroll
  for (int j = 0; j < 8; ++j) { o0[j] = (short)f2bf(v[j] * inv); o1[j] = (short)f2bf(v[j + 8] * inv); }
  u16* pp = P + (size_t)row * 4096;
  *(bf16x8*)&pp[t * 8] = o0;
  *(bf16x8*)&pp[2048 + t * 8] = o1;
}

// ------- LayerNorm rows (D=768) over sum of four split-K partials -> bf16 ----
__global__ __launch_bounds__(256) void ln4_kernel(
    const float* __restrict__ X, long long ps,
    const float* __restrict__ g, const float* __restrict__ b,
    u16* __restrict__ Y)
{
  __shared__ float red[4];
  int row = blockIdx.x, t = threadIdx.x;
  const float* x = X + (size_t)row * 768;
  float v0 = x[t]       + x[ps + t]       + x[2 * ps + t]       + x[3 * ps + t];
  float v1 = x[t + 256] + x[ps + t + 256] + x[2 * ps + t + 256] + x[3 * ps + t + 256];
  float v2 = x[t + 512] + x[ps + t + 512] + x[2 * ps + t + 512] + x[3 * ps + t + 512];

  float s = v0 + v1 + v2;
#pragma unroll
  for (int off = 32; off > 0; off >>= 1) s += __shfl_xor(s, off);
  if ((t & 63) == 0) red[t >> 6] = s;
  __syncthreads();
  float mu = (red[0] + red[1] + red[2] + red[3]) * (1.f / 768.f);
  __syncthreads();

  float d0 = v0 - mu, d1 = v1 - mu, d2 = v2 - mu;
  float q = d0 * d0 + d1 * d1 + d2 * d2;
#pragma unroll
  for (int off = 32; off > 0; off >>= 1) q += __shfl_xor(q, off);
  if ((t & 63) == 0) red[t >> 6] = q;
  __syncthreads();
  float var = (red[0] + red[1] + red[2] + red[3]) * (1.f / 768.f);
  float inv = rsqrtf(var + 1e-5f);

  u16* y = Y + (size_t)row * 768;
  y[t]       = f2bf(d0 * inv * g[t]       + b[t]);
  y[t + 256] = f2bf(d1 * inv * g[t + 256] + b[t + 256]);
  y[t + 512] = f2bf(d2 * inv * g[t + 512] + b[t + 512]);
}

// ---------------- broadcast rows: H[N][D] -> O[N][Lv][D] (float4) ------------
__global__ __launch_bounds__(256) void bcast_kernel(
    const f32x4* __restrict__ H, f32x4* __restrict__ O, int total, int L, int d4)
{
  int id = blockIdx.x * 256 + threadIdx.x;
  if (id >= total) return;
  int n = id / (L * d4);
  int c = id % d4;
  O[id] = H[(size_t)n * d4 + c];
}

extern "C" void kernel_launch(void* const* d_in, const int* in_sizes, int n_in,
                              void* d_out, int out_size, void* d_ws, size_t ws_size,
                              hipStream_t stream)
{
  const float* vision = (const float*)d_in[0];
  const float* text   = (const float*)d_in[1];
  const float* fc_w   = (const float*)d_in[2];
  const float* fc_b   = (const float*)d_in[3];
  const float* ln_g   = (const float*)d_in[4];
  const float* ln_b   = (const float*)d_in[5];
  const float* w1     = (const float*)d_in[6];
  const float* b1     = (const float*)d_in[7];
  const float* w2     = (const float*)d_in[8];
  const float* b2     = (const float*)d_in[9];
  float* out = (float*)d_out;

  const int N = 4096, Lv = 16, M = 4096, Din = 512, D = 768, Dhp = 256;

  char* p = (char*)d_ws;
  auto alloc = [&](size_t bytes) { char* r = p; p += (bytes + 255) & ~(size_t)255; return r; };
  u16*   mean_v = (u16*)alloc((size_t)N * D * 2);
  u16*   mean_t = (u16*)alloc((size_t)M * Din * 2);
  u16*   fcw_bf = (u16*)alloc((size_t)D * Din * 2);
  u16*   w1p    = (u16*)alloc((size_t)Dhp * D * 2);
  u16*   w2p    = (u16*)alloc((size_t)D * Dhp * 2);
  float* b1p    = (float*)alloc((size_t)Dhp * 4);
  float* t_f    = (float*)alloc((size_t)M * D * 4);
  u16*   t_bf   = (u16*)alloc((size_t)M * D * 2);
  u16*   tT_bf  = (u16*)alloc((size_t)D * M * 2);
  u16*   scores = (u16*)alloc((size_t)N * M * 2);   // bf16 scores
  u16*   aff    = (u16*)alloc((size_t)N * M * 2);
  u16*   ln_o   = (u16*)alloc((size_t)N * D * 2);
  u16*   h1     = (u16*)alloc((size_t)N * Dhp * 2);
  float* aggp   = (float*)alloc((size_t)4 * N * D * 4);  // 4 split-K partials
  float* h2     = (float*)scores;   // scores dead after softmax; 12.6MB <= 33.5MB

  // 1. fused prologue: means + weight casts/pads (one launch)
  {
    int total = 4096 * 192 + 4096 * 128 + 768 * 512 + 256 * 768 + 768 * 256 + 256;
    prologue_kernel<<<(total + 255) / 256, 256, 0, stream>>>(
        vision, text, fc_w, w1, w2, b1, mean_v, mean_t, fcw_bf, w1p, w2p, b1p);
  }

  // 2. t = mean_t @ fc_w^T + fc_b   [M, D] fp32
  gemm_nt<false, false><<<dim3(D / 128, M / 128), 256, 0, stream>>>(
      mean_t, fcw_bf, fc_b, 1.f, t_f, nullptr, M, D, Din, Din, Din, 0, 0);

  // 3. t -> bf16 row-major + transposed
  cast_transpose_kernel<<<dim3(D / 32, M / 32), 256, 0, stream>>>(t_f, t_bf, tT_bf, M, D);

  // 4. scores = mean_v @ t^T / sqrt(D)   [N, M] bf16
  gemm_nt<false, true><<<dim3(M / 128, N / 128), 256, 0, stream>>>(
      mean_v, t_bf, nullptr, 1.f / sqrtf(768.f), nullptr, scores, N, M, D, D, D, 0, 0);

  // 5. softmax rows -> aff bf16
  softmax_rows_kernel<<<N, 256, 0, stream>>>(scores, aff);

  // 6. agg = aff @ t  [N, D] fp32, split-K=4 partials (B = tT, NT form)
  gemm_nt<false, false><<<dim3(D / 128, N / 128, 4), 256, 0, stream>>>(
      aff, tT_bf, nullptr, 1.f, aggp, nullptr, N, D, M / 4, M, M,
      M / 4, (long long)N * D);

  // 7. LayerNorm over 4 partials -> bf16
  ln4_kernel<<<N, 256, 0, stream>>>(aggp, (long long)N * D, ln_g, ln_b, ln_o);

  // 8. h1 = relu(ln @ w1^T + b1)   [N, Dhp] bf16  (padded 192->256)
  gemm_nt<true, true><<<dim3(Dhp / 128, N / 128), 256, 0, stream>>>(
      ln_o, w1p, b1p, 1.f, nullptr, h1, N, Dhp, D, D, D, 0, 0);

  // 9. h2 = h1 @ w2^T + b2   [N, D] fp32
  gemm_nt<false, false><<<dim3(D / 128, N / 128), 256, 0, stream>>>(
      h1, w2p, b2, 1.f, h2, nullptr, N, D, Dhp, Dhp, Dhp, 0, 0);

  // 10. broadcast to [N, Lv, D]
  int total4 = N * Lv * (D / 4);
  bcast_kernel<<<(total4 + 255) / 256, 256, 0, stream>>>(
      (const f32x4*)h2, (f32x4*)out, total4, Lv, D / 4);
}

// Round 4
// 390.342 us; speedup vs baseline: 1.1906x; 1.0256x over previous
//
#include <hip/hip_runtime.h>
#include <math.h>

typedef unsigned short u16;
typedef __attribute__((ext_vector_type(4))) float f32x4;
typedef __attribute__((ext_vector_type(8))) short bf16x8;

#define GLOBAL_AS __attribute__((address_space(1)))
#define LDS_AS __attribute__((address_space(3)))

__device__ __forceinline__ u16 f2bf(float f) {
  unsigned u = __builtin_bit_cast(unsigned, f);
  unsigned lsb = (u >> 16) & 1u;
  u += 0x7fffu + lsb;            // round-to-nearest-even
  return (u16)(u >> 16);
}

__device__ __forceinline__ float bf2f(u16 b) {
  return __builtin_bit_cast(float, ((unsigned)b) << 16);
}

__device__ __forceinline__ void gload16(const void* g, void* l) {
  __builtin_amdgcn_global_load_lds((const GLOBAL_AS void*)g, (LDS_AS void*)l, 16, 0, 0);
}

// ---- fused prologue: mean_v, mean_t, cast fc_w, pad-cast w1,w2, pad b1 ------
__global__ __launch_bounds__(256) void prologue_kernel(
    const float* __restrict__ vision, const float* __restrict__ text,
    const float* __restrict__ fc_w, const float* __restrict__ w1,
    const float* __restrict__ w2, const float* __restrict__ b1,
    u16* __restrict__ mean_v, u16* __restrict__ mean_t,
    u16* __restrict__ fcw_bf, u16* __restrict__ w1p, u16* __restrict__ w2p,
    float* __restrict__ b1p)
{
  const int n_mv = 4096 * 192;   // N * D/4
  const int n_mt = 4096 * 128;   // M * Din/4
  const int n_fcw = 768 * 512;
  const int n_w1 = 256 * 768;
  const int n_w2 = 768 * 256;
  int id = blockIdx.x * 256 + threadIdx.x;

  if (id < n_mv) {               // mean over Lv=16 of vision[N][16][768]
    int n = id / 192, c = id % 192;
    const f32x4* x = (const f32x4*)vision + (size_t)n * 16 * 192 + c;
    f32x4 s = {0.f, 0.f, 0.f, 0.f};
#pragma unroll
    for (int l = 0; l < 16; ++l) s += x[(size_t)l * 192];
    s *= (1.f / 16.f);
    ushort4 o; o.x = f2bf(s.x); o.y = f2bf(s.y); o.z = f2bf(s.z); o.w = f2bf(s.w);
    ((ushort4*)mean_v)[id] = o;
    return;
  }
  id -= n_mv;
  if (id < n_mt) {               // mean over Lt=77 of text[M][77][512]
    int n = id / 128, c = id % 128;
    const f32x4* x = (const f32x4*)text + (size_t)n * 77 * 128 + c;
    f32x4 s = {0.f, 0.f, 0.f, 0.f};
    for (int l = 0; l < 77; ++l) s += x[(size_t)l * 128];
    s *= (1.f / 77.f);
    ushort4 o; o.x = f2bf(s.x); o.y = f2bf(s.y); o.z = f2bf(s.z); o.w = f2bf(s.w);
    ((ushort4*)mean_t)[id] = o;
    return;
  }
  id -= n_mt;
  if (id < n_fcw) { fcw_bf[id] = f2bf(fc_w[id]); return; }
  id -= n_fcw;
  if (id < n_w1) {
    int r = id / 768;
    w1p[id] = (r < 192) ? f2bf(w1[id]) : (u16)0;
    return;
  }
  id -= n_w1;
  if (id < n_w2) {
    int r = id / 256, c = id % 256;
    w2p[id] = (c < 192) ? f2bf(w2[(size_t)r * 192 + c]) : (u16)0;
    return;
  }
  id -= n_w2;
  if (id < 256) b1p[id] = (id < 192) ? b1[id] : 0.f;
}

// ------- 256x256 deep-pipelined NT bf16 GEMM, C bf16 = alpha * A@B^T --------
// BK=32, 3 LDS buffers, stage-2-ahead, counted vmcnt, 1 raw barrier per iter.
// 8 waves = 2M x 4N, per-wave output 128x64. Requires M%256==0, N%256==0,
// K%32==0, K/32 >= 2.
__global__ __launch_bounds__(512, 2) void gemm256_nt_bf16(
    const u16* __restrict__ A, const u16* __restrict__ B, float alpha,
    u16* __restrict__ C, int N, int K, int lda, int ldb)
{
  __shared__ u16 lA[3][256 * 32];   // 3 x 16 KB
  __shared__ u16 lB[3][256 * 32];   // 3 x 16 KB   (total 96 KB)
  const int tid = threadIdx.x;
  const int w = tid >> 6, lane = tid & 63;
  const int brow = blockIdx.y * 256, bcol = blockIdx.x * 256;
  const int wr = w >> 2, wc = w & 3;   // 2M x 4N wave grid

  f32x4 acc[8][4];
#pragma unroll
  for (int i = 0; i < 8; ++i)
#pragma unroll
    for (int j = 0; j < 4; ++j) acc[i][j] = (f32x4){0.f, 0.f, 0.f, 0.f};

  // staging: per wave 2 instrs for A + 2 for B; each instr = 64 lanes x 16B
  // covering 16 rows x 32 cols (64B/row, 4 lanes per row).
  const int srow = lane >> 2;          // 0..15
  const int scol = (lane & 3) * 8;     // 0,8,16,24
  const size_t ga0 = (size_t)(brow + (w * 2 + 0) * 16 + srow) * lda + scol;
  const size_t ga1 = (size_t)(brow + (w * 2 + 1) * 16 + srow) * lda + scol;
  const size_t gb0 = (size_t)(bcol + (w * 2 + 0) * 16 + srow) * ldb + scol;
  const size_t gb1 = (size_t)(bcol + (w * 2 + 1) * 16 + srow) * ldb + scol;

  const int fr = lane & 15, fk = (lane >> 4) * 8;
  const int NT = K >> 5;

  auto stage = [&](int ti, int b) {
    const int k0 = ti << 5;
    char* la = (char*)&lA[b][0] + w * 2048;
    char* lb = (char*)&lB[b][0] + w * 2048;
    gload16(A + ga0 + k0, la);
    gload16(A + ga1 + k0, la + 1024);
    gload16(B + gb0 + k0, lb);
    gload16(B + gb1 + k0, lb + 1024);
  };

  stage(0, 0);
  stage(1, 1);

  int bR = 0;
  for (int it = 0; it < NT; ++it) {
    // retire stage(it); allow stage(it+1) (4 loads/wave) to stay in flight
    if (it + 1 < NT) { asm volatile("s_waitcnt vmcnt(4)" ::: "memory"); }
    else             { asm volatile("s_waitcnt vmcnt(0)" ::: "memory"); }
    __builtin_amdgcn_s_barrier();
    asm volatile("" ::: "memory");

    int bW = bR + 2; if (bW >= 3) bW -= 3;
    if (it + 2 < NT) stage(it + 2, bW);   // into free buffer: no collision

    const u16* la = lA[bR];
    const u16* lb = lB[bR];
    bf16x8 av[8], bv[4];
#pragma unroll
    for (int mi = 0; mi < 8; ++mi)
      av[mi] = *(const bf16x8*)&la[(wr * 128 + mi * 16 + fr) * 32 + fk];
#pragma unroll
    for (int ni = 0; ni < 4; ++ni)
      bv[ni] = *(const bf16x8*)&lb[(wc * 64 + ni * 16 + fr) * 32 + fk];

    __builtin_amdgcn_s_setprio(1);
#pragma unroll
    for (int mi = 0; mi < 8; ++mi)
#pragma unroll
      for (int ni = 0; ni < 4; ++ni)
        acc[mi][ni] = __builtin_amdgcn_mfma_f32_16x16x32_bf16(av[mi], bv[ni], acc[mi][ni], 0, 0, 0);
    __builtin_amdgcn_s_setprio(0);

    bR = (bR + 1 == 3) ? 0 : bR + 1;
  }

  const int fq = lane >> 4;
#pragma unroll
  for (int mi = 0; mi < 8; ++mi) {
#pragma unroll
    for (int ni = 0; ni < 4; ++ni) {
      int col = bcol + wc * 64 + ni * 16 + fr;
#pragma unroll
      for (int r = 0; r < 4; ++r) {
        int row = brow + wr * 128 + mi * 16 + fq * 4 + r;
        C[(size_t)row * N + col] = f2bf(acc[mi][ni][r] * alpha);
      }
    }
  }
}

// ---------------- NT bf16 MFMA GEMM: C[M,N] = alpha*A[M,K]@B[N,K]^T + bias ----
// 128x128 tile, BK=32, double-buffered LDS, 2-phase prefetch pipeline.
template<bool RELU, bool BF16OUT>
__global__ __launch_bounds__(256) void gemm_nt(
    const u16* __restrict__ A, const u16* __restrict__ B,
    const float* __restrict__ bias, float alpha,
    float* __restrict__ Cf, u16* __restrict__ Cb,
    int M, int N, int K, int lda, int ldb,
    int kofs, long long cofs)
{
  __shared__ u16 lA[2][128 * 32];
  __shared__ u16 lB[2][128 * 32];
  const int t = threadIdx.x;
  const int w = t >> 6, lane = t & 63;
  const int brow = blockIdx.y * 128, bcol = blockIdx.x * 128;
  const int wr = w >> 1, wc = w & 1;     // wave sub-tile 64x64
  const int kz = blockIdx.z;

  A += (size_t)kz * kofs;
  B += (size_t)kz * kofs;
  Cf += kz * cofs;

  f32x4 acc[4][4];
#pragma unroll
  for (int i = 0; i < 4; ++i)
#pragma unroll
    for (int j = 0; j < 4; ++j) acc[i][j] = (f32x4){0.f, 0.f, 0.f, 0.f};

  const int srow = t >> 2;               // 0..63
  const int scol = (t & 3) * 8;
  const size_t aoff0 = (size_t)(brow + srow) * lda + scol;
  const size_t boff0 = (size_t)(bcol + srow) * ldb + scol;
  const size_t aoff1 = aoff0 + (size_t)64 * lda;
  const size_t boff1 = boff0 + (size_t)64 * ldb;

  const int fr = lane & 15, fk = (lane >> 4) * 8;
  const int NT = K >> 5;

  auto stage = [&](int ti, int b) {
    const int k0 = ti << 5;
    char* la = (char*)lA + b * 8192 + w * 1024;
    char* lb = (char*)lB + b * 8192 + w * 1024;
    gload16(A + aoff0 + k0, la);
    gload16(A + aoff1 + k0, la + 4096);
    gload16(B + boff0 + k0, lb);
    gload16(B + boff1 + k0, lb + 4096);
  };

  stage(0, 0);
  int cur = 0;
  for (int ti = 0; ti < NT; ++ti, cur ^= 1) {
    __syncthreads();
    if (ti + 1 < NT) stage(ti + 1, cur ^ 1);

    const u16* la = lA[cur];
    const u16* lb = lB[cur];
    bf16x8 av[4], bv[4];
#pragma unroll
    for (int mi = 0; mi < 4; ++mi)
      av[mi] = *(const bf16x8*)&la[(wr * 64 + mi * 16 + fr) * 32 + fk];
#pragma unroll
    for (int ni = 0; ni < 4; ++ni)
      bv[ni] = *(const bf16x8*)&lb[(wc * 64 + ni * 16 + fr) * 32 + fk];

#pragma unroll
    for (int mi = 0; mi < 4; ++mi)
#pragma unroll
      for (int ni = 0; ni < 4; ++ni)
        acc[mi][ni] = __builtin_amdgcn_mfma_f32_16x16x32_bf16(av[mi], bv[ni], acc[mi][ni], 0, 0, 0);
  }

  const int fq = lane >> 4;
#pragma unroll
  for (int mi = 0; mi < 4; ++mi) {
#pragma unroll
    for (int ni = 0; ni < 4; ++ni) {
      int col = bcol + wc * 64 + ni * 16 + fr;
      float bb = bias ? bias[col] : 0.f;
#pragma unroll
      for (int r = 0; r < 4; ++r) {
        int row = brow + wr * 64 + mi * 16 + fq * 4 + r;
        float v = acc[mi][ni][r] * alpha + bb;
        if (RELU) v = fmaxf(v, 0.f);
        if (BF16OUT) Cb[(size_t)row * N + col] = f2bf(v);
        else         Cf[(size_t)row * N + col] = v;
      }
    }
  }
}

// ---------------- bf16 transpose: X[R][C] -> Y[C][R] ----------------
__global__ __launch_bounds__(256) void transpose_bf16_kernel(
    const u16* __restrict__ X, u16* __restrict__ Y, int R, int C)
{
  __shared__ u16 tile[32][33];
  int bx = blockIdx.x, by = blockIdx.y;
  int tx = threadIdx.x & 31, ty = threadIdx.x >> 5;   // ty 0..7
#pragma unroll
  for (int i = 0; i < 4; ++i) {
    int r = by * 32 + ty + i * 8, c = bx * 32 + tx;
    tile[ty + i * 8][tx] = X[(size_t)r * C + c];
  }
  __syncthreads();
#pragma unroll
  for (int i = 0; i < 4; ++i) {
    int r = bx * 32 + ty + i * 8;   // C-dim index
    int c = by * 32 + tx;           // R-dim index
    Y[(size_t)r * R + c] = tile[tx][ty + i * 8];
  }
}

// ------------- row softmax over 4096, bf16 in -> bf16 out --------------------
__global__ __launch_bounds__(256) void softmax_rows_kernel(
    const u16* __restrict__ S, u16* __restrict__ P)
{
  __shared__ float red[4];
  int row = blockIdx.x, t = threadIdx.x;
  const u16* s = S + (size_t)row * 4096;
  bf16x8 c0 = *(const bf16x8*)&s[t * 8];
  bf16x8 c1 = *(const bf16x8*)&s[2048 + t * 8];
  float v[16];
#pragma unroll
  for (int j = 0; j < 8; ++j) v[j]     = bf2f((u16)c0[j]);
#pragma unroll
  for (int j = 0; j < 8; ++j) v[j + 8] = bf2f((u16)c1[j]);

  float mx = -INFINITY;
#pragma unroll
  for (int j = 0; j < 16; ++j) mx = fmaxf(mx, v[j]);
#pragma unroll
  for (int off = 32; off > 0; off >>= 1) mx = fmaxf(mx, __shfl_xor(mx, off));
  if ((t & 63) == 0) red[t >> 6] = mx;
  __syncthreads();
  mx = fmaxf(fmaxf(red[0], red[1]), fmaxf(red[2], red[3]));
  __syncthreads();
  float sum = 0.f;
#pragma unroll
  for (int j = 0; j < 16; ++j) { v[j] = __expf(v[j] - mx); sum += v[j]; }
#pragma unroll
  for (int off = 32; off > 0; off >>= 1) sum += __shfl_xor(sum, off);
  if ((t & 63) == 0) red[t >> 6] = sum;
  __syncthreads();
  sum = red[0] + red[1] + red[2] + red[3];
  float inv = 1.f / sum;
  bf16x8 o0, o1;
#pragma unroll
  for (int j = 0; j < 8; ++j) { o0[j] = (short)f2bf(v[j] * inv); o1[j] = (short)f2bf(v[j + 8] * inv); }
  u16* pp = P + (size_t)row * 4096;
  *(bf16x8*)&pp[t * 8] = o0;
  *(bf16x8*)&pp[2048 + t * 8] = o1;
}

// ------- LayerNorm rows (D=768) over sum of four split-K partials -> bf16 ----
__global__ __launch_bounds__(256) void ln4_kernel(
    const float* __restrict__ X, long long ps,
    const float* __restrict__ g, const float* __restrict__ b,
    u16* __restrict__ Y)
{
  __shared__ float red[4];
  int row = blockIdx.x, t = threadIdx.x;
  const float* x = X + (size_t)row * 768;
  float v0 = x[t]       + x[ps + t]       + x[2 * ps + t]       + x[3 * ps + t];
  float v1 = x[t + 256] + x[ps + t + 256] + x[2 * ps + t + 256] + x[3 * ps + t + 256];
  float v2 = x[t + 512] + x[ps + t + 512] + x[2 * ps + t + 512] + x[3 * ps + t + 512];

  float s = v0 + v1 + v2;
#pragma unroll
  for (int off = 32; off > 0; off >>= 1) s += __shfl_xor(s, off);
  if ((t & 63) == 0) red[t >> 6] = s;
  __syncthreads();
  float mu = (red[0] + red[1] + red[2] + red[3]) * (1.f / 768.f);
  __syncthreads();

  float d0 = v0 - mu, d1 = v1 - mu, d2 = v2 - mu;
  float q = d0 * d0 + d1 * d1 + d2 * d2;
#pragma unroll
  for (int off = 32; off > 0; off >>= 1) q += __shfl_xor(q, off);
  if ((t & 63) == 0) red[t >> 6] = q;
  __syncthreads();
  float var = (red[0] + red[1] + red[2] + red[3]) * (1.f / 768.f);
  float inv = rsqrtf(var + 1e-5f);

  u16* y = Y + (size_t)row * 768;
  y[t]       = f2bf(d0 * inv * g[t]       + b[t]);
  y[t + 256] = f2bf(d1 * inv * g[t + 256] + b[t + 256]);
  y[t + 512] = f2bf(d2 * inv * g[t + 512] + b[t + 512]);
}

// ---------------- broadcast rows: H[N][D] -> O[N][Lv][D] (float4) ------------
__global__ __launch_bounds__(256) void bcast_kernel(
    const f32x4* __restrict__ H, f32x4* __restrict__ O, int total, int L, int d4)
{
  int id = blockIdx.x * 256 + threadIdx.x;
  if (id >= total) return;
  int n = id / (L * d4);
  int c = id % d4;
  O[id] = H[(size_t)n * d4 + c];
}

extern "C" void kernel_launch(void* const* d_in, const int* in_sizes, int n_in,
                              void* d_out, int out_size, void* d_ws, size_t ws_size,
                              hipStream_t stream)
{
  const float* vision = (const float*)d_in[0];
  const float* text   = (const float*)d_in[1];
  const float* fc_w   = (const float*)d_in[2];
  const float* fc_b   = (const float*)d_in[3];
  const float* ln_g   = (const float*)d_in[4];
  const float* ln_b   = (const float*)d_in[5];
  const float* w1     = (const float*)d_in[6];
  const float* b1     = (const float*)d_in[7];
  const float* w2     = (const float*)d_in[8];
  const float* b2     = (const float*)d_in[9];
  float* out = (float*)d_out;

  const int N = 4096, Lv = 16, M = 4096, Din = 512, D = 768, Dhp = 256;

  char* p = (char*)d_ws;
  auto alloc = [&](size_t bytes) { char* r = p; p += (bytes + 255) & ~(size_t)255; return r; };
  u16*   mean_v = (u16*)alloc((size_t)N * D * 2);
  u16*   mean_t = (u16*)alloc((size_t)M * Din * 2);
  u16*   fcw_bf = (u16*)alloc((size_t)D * Din * 2);
  u16*   w1p    = (u16*)alloc((size_t)Dhp * D * 2);
  u16*   w2p    = (u16*)alloc((size_t)D * Dhp * 2);
  float* b1p    = (float*)alloc((size_t)Dhp * 4);
  u16*   t_bf   = (u16*)alloc((size_t)M * D * 2);
  u16*   tT_bf  = (u16*)alloc((size_t)D * M * 2);
  u16*   scores = (u16*)alloc((size_t)N * M * 2);   // bf16 scores
  u16*   aff    = (u16*)alloc((size_t)N * M * 2);
  u16*   ln_o   = (u16*)alloc((size_t)N * D * 2);
  u16*   h1     = (u16*)alloc((size_t)N * Dhp * 2);
  float* aggp   = (float*)alloc((size_t)4 * N * D * 4);  // 4 split-K partials
  float* h2     = (float*)scores;   // scores dead after softmax; 12.6MB fits

  // 1. fused prologue: means + weight casts/pads (one launch)
  {
    int total = 4096 * 192 + 4096 * 128 + 768 * 512 + 256 * 768 + 768 * 256 + 256;
    prologue_kernel<<<(total + 255) / 256, 256, 0, stream>>>(
        vision, text, fc_w, w1, w2, b1, mean_v, mean_t, fcw_bf, w1p, w2p, b1p);
  }

  // 2. t = mean_t @ fc_w^T + fc_b   [M, D] bf16 (direct)
  gemm_nt<false, true><<<dim3(D / 128, M / 128), 256, 0, stream>>>(
      mean_t, fcw_bf, fc_b, 1.f, nullptr, t_bf, M, D, Din, Din, Din, 0, 0);

  // 3. tT = t^T  (bf16 -> bf16)
  transpose_bf16_kernel<<<dim3(D / 32, M / 32), 256, 0, stream>>>(t_bf, tT_bf, M, D);

  // 4. scores = mean_v @ t^T / sqrt(D)   [N, M] bf16  (deep-pipelined 256^2)
  gemm256_nt_bf16<<<dim3(M / 256, N / 256), 512, 0, stream>>>(
      mean_v, t_bf, 1.f / sqrtf(768.f), scores, M, D, D, D);

  // 5. softmax rows -> aff bf16
  softmax_rows_kernel<<<N, 256, 0, stream>>>(scores, aff);

  // 6. agg = aff @ t  [N, D] fp32, split-K=4 partials (B = tT, NT form)
  gemm_nt<false, false><<<dim3(D / 128, N / 128, 4), 256, 0, stream>>>(
      aff, tT_bf, nullptr, 1.f, aggp, nullptr, N, D, M / 4, M, M,
      M / 4, (long long)N * D);

  // 7. LayerNorm over 4 partials -> bf16
  ln4_kernel<<<N, 256, 0, stream>>>(aggp, (long long)N * D, ln_g, ln_b, ln_o);

  // 8. h1 = relu(ln @ w1^T + b1)   [N, Dhp] bf16  (padded 192->256)
  gemm_nt<true, true><<<dim3(Dhp / 128, N / 128), 256, 0, stream>>>(
      ln_o, w1p, b1p, 1.f, nullptr, h1, N, Dhp, D, D, D, 0, 0);

  // 9. h2 = h1 @ w2^T + b2   [N, D] fp32
  gemm_nt<false, false><<<dim3(D / 128, N / 128), 256, 0, stream>>>(
      h1, w2p, b2, 1.f, h2, nullptr, N, D, Dhp, Dhp, Dhp, 0, 0);

  // 10. broadcast to [N, Lv, D]
  int total4 = N * Lv * (D / 4);
  bcast_kernel<<<(total4 + 255) / 256, 256, 0, stream>>>(
      (const f32x4*)h2, (f32x4*)out, total4, Lv, D / 4);
}

// Round 6
// 385.825 us; speedup vs baseline: 1.2045x; 1.0117x over previous
//
#include <hip/hip_runtime.h>
#include <math.h>

typedef unsigned short u16;
typedef __attribute__((ext_vector_type(4))) float f32x4;
typedef __attribute__((ext_vector_type(8))) short bf16x8;

#define GLOBAL_AS __attribute__((address_space(1)))
#define LDS_AS __attribute__((address_space(3)))

__device__ __forceinline__ u16 f2bf(float f) {
  unsigned u = __builtin_bit_cast(unsigned, f);
  unsigned lsb = (u >> 16) & 1u;
  u += 0x7fffu + lsb;            // round-to-nearest-even
  return (u16)(u >> 16);
}

__device__ __forceinline__ float bf2f(u16 b) {
  return __builtin_bit_cast(float, ((unsigned)b) << 16);
}

__device__ __forceinline__ void gload16(const void* g, void* l) {
  __builtin_amdgcn_global_load_lds((const GLOBAL_AS void*)g, (LDS_AS void*)l, 16, 0, 0);
}

// ---- fused prologue: mean_v, mean_t, cast fc_w, pad-cast w1,w2, pad b1 ------
__global__ __launch_bounds__(256) void prologue_kernel(
    const float* __restrict__ vision, const float* __restrict__ text,
    const float* __restrict__ fc_w, const float* __restrict__ w1,
    const float* __restrict__ w2, const float* __restrict__ b1,
    u16* __restrict__ mean_v, u16* __restrict__ mean_t,
    u16* __restrict__ fcw_bf, u16* __restrict__ w1p, u16* __restrict__ w2p,
    float* __restrict__ b1p)
{
  const int n_mv = 4096 * 192;   // N * D/4
  const int n_mt = 4096 * 128;   // M * Din/4
  const int n_fcw = 768 * 512;
  const int n_w1 = 256 * 768;
  const int n_w2 = 768 * 256;
  int id = blockIdx.x * 256 + threadIdx.x;

  if (id < n_mv) {               // mean over Lv=16 of vision[N][16][768]
    int n = id / 192, c = id % 192;
    const f32x4* x = (const f32x4*)vision + (size_t)n * 16 * 192 + c;
    f32x4 s = {0.f, 0.f, 0.f, 0.f};
#pragma unroll
    for (int l = 0; l < 16; ++l) s += x[(size_t)l * 192];
    s *= (1.f / 16.f);
    ushort4 o; o.x = f2bf(s.x); o.y = f2bf(s.y); o.z = f2bf(s.z); o.w = f2bf(s.w);
    ((ushort4*)mean_v)[id] = o;
    return;
  }
  id -= n_mv;
  if (id < n_mt) {               // mean over Lt=77 of text[M][77][512]
    int n = id / 128, c = id % 128;
    const f32x4* x = (const f32x4*)text + (size_t)n * 77 * 128 + c;
    f32x4 s = {0.f, 0.f, 0.f, 0.f};
    for (int l = 0; l < 77; ++l) s += x[(size_t)l * 128];
    s *= (1.f / 77.f);
    ushort4 o; o.x = f2bf(s.x); o.y = f2bf(s.y); o.z = f2bf(s.z); o.w = f2bf(s.w);
    ((ushort4*)mean_t)[id] = o;
    return;
  }
  id -= n_mt;
  if (id < n_fcw) { fcw_bf[id] = f2bf(fc_w[id]); return; }
  id -= n_fcw;
  if (id < n_w1) {
    int r = id / 768;
    w1p[id] = (r < 192) ? f2bf(w1[id]) : (u16)0;
    return;
  }
  id -= n_w1;
  if (id < n_w2) {
    int r = id / 256, c = id % 256;
    w2p[id] = (c < 192) ? f2bf(w2[(size_t)r * 192 + c]) : (u16)0;
    return;
  }
  id -= n_w2;
  if (id < 256) b1p[id] = (id < 192) ? b1[id] : 0.f;
}

// ------- 256x256 deep-pipelined NT bf16 GEMM, C bf16 = f(alpha * A@B^T) -----
// BK=32, 3 LDS buffers, stage-2-ahead, counted vmcnt, 1 raw barrier per iter.
// EXP: write exp(alpha*s) (unnormalized softmax; denom recovered separately).
template<bool EXP>
__global__ __launch_bounds__(512, 2) void gemm256_nt_bf16(
    const u16* __restrict__ A, const u16* __restrict__ B, float alpha,
    u16* __restrict__ C, int N, int K, int lda, int ldb)
{
  __shared__ u16 lA[3][256 * 32];   // 3 x 16 KB
  __shared__ u16 lB[3][256 * 32];   // 3 x 16 KB   (total 96 KB)
  const int tid = threadIdx.x;
  const int w = tid >> 6, lane = tid & 63;
  const int brow = blockIdx.y * 256, bcol = blockIdx.x * 256;
  const int wr = w >> 2, wc = w & 3;   // 2M x 4N wave grid

  f32x4 acc[8][4];
#pragma unroll
  for (int i = 0; i < 8; ++i)
#pragma unroll
    for (int j = 0; j < 4; ++j) acc[i][j] = (f32x4){0.f, 0.f, 0.f, 0.f};

  const int srow = lane >> 2;          // 0..15
  const int scol = (lane & 3) * 8;     // 0,8,16,24
  const size_t ga0 = (size_t)(brow + (w * 2 + 0) * 16 + srow) * lda + scol;
  const size_t ga1 = (size_t)(brow + (w * 2 + 1) * 16 + srow) * lda + scol;
  const size_t gb0 = (size_t)(bcol + (w * 2 + 0) * 16 + srow) * ldb + scol;
  const size_t gb1 = (size_t)(bcol + (w * 2 + 1) * 16 + srow) * ldb + scol;

  const int fr = lane & 15, fk = (lane >> 4) * 8;
  const int NT = K >> 5;

  auto stage = [&](int ti, int b) {
    const int k0 = ti << 5;
    char* la = (char*)&lA[b][0] + w * 2048;
    char* lb = (char*)&lB[b][0] + w * 2048;
    gload16(A + ga0 + k0, la);
    gload16(A + ga1 + k0, la + 1024);
    gload16(B + gb0 + k0, lb);
    gload16(B + gb1 + k0, lb + 1024);
  };

  stage(0, 0);
  stage(1, 1);

  int bR = 0;
  for (int it = 0; it < NT; ++it) {
    if (it + 1 < NT) { asm volatile("s_waitcnt vmcnt(4)" ::: "memory"); }
    else             { asm volatile("s_waitcnt vmcnt(0)" ::: "memory"); }
    __builtin_amdgcn_s_barrier();
    asm volatile("" ::: "memory");

    int bW = bR + 2; if (bW >= 3) bW -= 3;
    if (it + 2 < NT) stage(it + 2, bW);

    const u16* la = lA[bR];
    const u16* lb = lB[bR];
    bf16x8 av[8], bv[4];
#pragma unroll
    for (int mi = 0; mi < 8; ++mi)
      av[mi] = *(const bf16x8*)&la[(wr * 128 + mi * 16 + fr) * 32 + fk];
#pragma unroll
    for (int ni = 0; ni < 4; ++ni)
      bv[ni] = *(const bf16x8*)&lb[(wc * 64 + ni * 16 + fr) * 32 + fk];

    __builtin_amdgcn_s_setprio(1);
#pragma unroll
    for (int mi = 0; mi < 8; ++mi)
#pragma unroll
      for (int ni = 0; ni < 4; ++ni)
        acc[mi][ni] = __builtin_amdgcn_mfma_f32_16x16x32_bf16(av[mi], bv[ni], acc[mi][ni], 0, 0, 0);
    __builtin_amdgcn_s_setprio(0);

    bR = (bR + 1 == 3) ? 0 : bR + 1;
  }

  const int fq = lane >> 4;
#pragma unroll
  for (int mi = 0; mi < 8; ++mi) {
#pragma unroll
    for (int ni = 0; ni < 4; ++ni) {
      int col = bcol + wc * 64 + ni * 16 + fr;
#pragma unroll
      for (int r = 0; r < 4; ++r) {
        int row = brow + wr * 128 + mi * 16 + fq * 4 + r;
        float v = acc[mi][ni][r] * alpha;
        if (EXP) v = __expf(v);
        C[(size_t)row * N + col] = f2bf(v);
      }
    }
  }
}

// ---------------- NT bf16 MFMA GEMM: C[M,N] = alpha*A[M,K]@B[N,K]^T + bias ----
// 128x128 tile, BK=32, 3 LDS buffers, stage-2-ahead, counted vmcnt,
// 1 raw barrier per iter (same schedule as gemm256). K/32 >= 2 required.
// blockIdx.z = split-K slice: A/B advance by kofs elements, Cf by cofs.
template<bool RELU, bool BF16OUT>
__global__ __launch_bounds__(256) void gemm_nt(
    const u16* __restrict__ A, const u16* __restrict__ B,
    const float* __restrict__ bias, float alpha,
    float* __restrict__ Cf, u16* __restrict__ Cb,
    int M, int N, int K, int lda, int ldb,
    int kofs, long long cofs)
{
  __shared__ u16 lA[3][128 * 32];   // 3 x 8 KB
  __shared__ u16 lB[3][128 * 32];   // 3 x 8 KB   (total 48 KB)
  const int t = threadIdx.x;
  const int w = t >> 6, lane = t & 63;
  const int brow = blockIdx.y * 128, bcol = blockIdx.x * 128;
  const int wr = w >> 1, wc = w & 1;     // wave sub-tile 64x64
  const int kz = blockIdx.z;

  A += (size_t)kz * kofs;
  B += (size_t)kz * kofs;
  Cf += kz * cofs;

  f32x4 acc[4][4];
#pragma unroll
  for (int i = 0; i < 4; ++i)
#pragma unroll
    for (int j = 0; j < 4; ++j) acc[i][j] = (f32x4){0.f, 0.f, 0.f, 0.f};

  const int srow = t >> 2;               // 0..63
  const int scol = (t & 3) * 8;
  const size_t aoff0 = (size_t)(brow + srow) * lda + scol;
  const size_t boff0 = (size_t)(bcol + srow) * ldb + scol;
  const size_t aoff1 = aoff0 + (size_t)64 * lda;
  const size_t boff1 = boff0 + (size_t)64 * ldb;

  const int fr = lane & 15, fk = (lane >> 4) * 8;
  const int NT = K >> 5;

  auto stage = [&](int ti, int b) {
    const int k0 = ti << 5;
    char* la = (char*)&lA[b][0] + w * 1024;
    char* lb = (char*)&lB[b][0] + w * 1024;
    gload16(A + aoff0 + k0, la);
    gload16(A + aoff1 + k0, la + 4096);
    gload16(B + boff0 + k0, lb);
    gload16(B + boff1 + k0, lb + 4096);
  };

  stage(0, 0);
  stage(1, 1);

  int bR = 0;
  for (int it = 0; it < NT; ++it) {
    if (it + 1 < NT) { asm volatile("s_waitcnt vmcnt(4)" ::: "memory"); }
    else             { asm volatile("s_waitcnt vmcnt(0)" ::: "memory"); }
    __builtin_amdgcn_s_barrier();
    asm volatile("" ::: "memory");

    int bW = bR + 2; if (bW >= 3) bW -= 3;
    if (it + 2 < NT) stage(it + 2, bW);

    const u16* la = lA[bR];
    const u16* lb = lB[bR];
    bf16x8 av[4], bv[4];
#pragma unroll
    for (int mi = 0; mi < 4; ++mi)
      av[mi] = *(const bf16x8*)&la[(wr * 64 + mi * 16 + fr) * 32 + fk];
#pragma unroll
    for (int ni = 0; ni < 4; ++ni)
      bv[ni] = *(const bf16x8*)&lb[(wc * 64 + ni * 16 + fr) * 32 + fk];

    __builtin_amdgcn_s_setprio(1);
#pragma unroll
    for (int mi = 0; mi < 4; ++mi)
#pragma unroll
      for (int ni = 0; ni < 4; ++ni)
        acc[mi][ni] = __builtin_amdgcn_mfma_f32_16x16x32_bf16(av[mi], bv[ni], acc[mi][ni], 0, 0, 0);
    __builtin_amdgcn_s_setprio(0);

    bR = (bR + 1 == 3) ? 0 : bR + 1;
  }

  const int fq = lane >> 4;
#pragma unroll
  for (int mi = 0; mi < 4; ++mi) {
#pragma unroll
    for (int ni = 0; ni < 4; ++ni) {
      int col = bcol + wc * 64 + ni * 16 + fr;
      float bb = bias ? bias[col] : 0.f;
#pragma unroll
      for (int r = 0; r < 4; ++r) {
        int row = brow + wr * 64 + mi * 16 + fq * 4 + r;
        float v = acc[mi][ni][r] * alpha + bb;
        if (RELU) v = fmaxf(v, 0.f);
        if (BF16OUT) Cb[(size_t)row * N + col] = f2bf(v);
        else         Cf[(size_t)row * N + col] = v;
      }
    }
  }
}

// ---------------- bf16 transpose: X[R][C] -> Y[C][R] ----------------
__global__ __launch_bounds__(256) void transpose_bf16_kernel(
    const u16* __restrict__ X, u16* __restrict__ Y, int R, int C)
{
  __shared__ u16 tile[32][33];
  int bx = blockIdx.x, by = blockIdx.y;
  int tx = threadIdx.x & 31, ty = threadIdx.x >> 5;   // ty 0..7
#pragma unroll
  for (int i = 0; i < 4; ++i) {
    int r = by * 32 + ty + i * 8, c = bx * 32 + tx;
    tile[ty + i * 8][tx] = X[(size_t)r * C + c];
  }
  __syncthreads();
#pragma unroll
  for (int i = 0; i < 4; ++i) {
    int r = bx * 32 + ty + i * 8;   // C-dim index
    int c = by * 32 + tx;           // R-dim index
    Y[(size_t)r * R + c] = tile[tx][ty + i * 8];
  }
}

// -------- row sums of aff [4096 x 4096] bf16 -> denom[4096] fp32 -------------
__global__ __launch_bounds__(256) void rowsum_kernel(
    const u16* __restrict__ A, float* __restrict__ denom)
{
  __shared__ float red[4];
  int row = blockIdx.x, t = threadIdx.x;
  const u16* s = A + (size_t)row * 4096;
  bf16x8 c0 = *(const bf16x8*)&s[t * 8];
  bf16x8 c1 = *(const bf16x8*)&s[2048 + t * 8];
  float sum = 0.f;
#pragma unroll
  for (int j = 0; j < 8; ++j) sum += bf2f((u16)c0[j]) + bf2f((u16)c1[j]);
#pragma unroll
  for (int off = 32; off > 0; off >>= 1) sum += __shfl_xor(sum, off);
  if ((t & 63) == 0) red[t >> 6] = sum;
  __syncthreads();
  if (t == 0) denom[row] = red[0] + red[1] + red[2] + red[3];
}

// -- LayerNorm rows (D=768): sum 4 split-K partials, scale by 1/denom, LN -----
// Dividing by denom BEFORE LN restores exact reference eps semantics
// (var(agg) ~ 3e-6 is comparable to eps=1e-5, so the scale is NOT absorbed).
__global__ __launch_bounds__(256) void ln4_kernel(
    const float* __restrict__ X, long long ps, const float* __restrict__ denom,
    const float* __restrict__ g, const float* __restrict__ b,
    u16* __restrict__ Y)
{
  __shared__ float red[4];
  int row = blockIdx.x, t = threadIdx.x;
  const float* x = X + (size_t)row * 768;
  float inv_d = 1.f / denom[row];
  float v0 = (x[t]       + x[ps + t]       + x[2 * ps + t]       + x[3 * ps + t]) * inv_d;
  float v1 = (x[t + 256] + x[ps + t + 256] + x[2 * ps + t + 256] + x[3 * ps + t + 256]) * inv_d;
  float v2 = (x[t + 512] + x[ps + t + 512] + x[2 * ps + t + 512] + x[3 * ps + t + 512]) * inv_d;

  float s = v0 + v1 + v2;
#pragma unroll
  for (int off = 32; off > 0; off >>= 1) s += __shfl_xor(s, off);
  if ((t & 63) == 0) red[t >> 6] = s;
  __syncthreads();
  float mu = (red[0] + red[1] + red[2] + red[3]) * (1.f / 768.f);
  __syncthreads();

  float d0 = v0 - mu, d1 = v1 - mu, d2 = v2 - mu;
  float q = d0 * d0 + d1 * d1 + d2 * d2;
#pragma unroll
  for (int off = 32; off > 0; off >>= 1) q += __shfl_xor(q, off);
  if ((t & 63) == 0) red[t >> 6] = q;
  __syncthreads();
  float var = (red[0] + red[1] + red[2] + red[3]) * (1.f / 768.f);
  float inv = rsqrtf(var + 1e-5f);

  u16* y = Y + (size_t)row * 768;
  y[t]       = f2bf(d0 * inv * g[t]       + b[t]);
  y[t + 256] = f2bf(d1 * inv * g[t + 256] + b[t + 256]);
  y[t + 512] = f2bf(d2 * inv * g[t + 512] + b[t + 512]);
}

// ---------------- broadcast rows: H[N][D] -> O[N][Lv][D] (float4) ------------
__global__ __launch_bounds__(256) void bcast_kernel(
    const f32x4* __restrict__ H, f32x4* __restrict__ O, int total, int L, int d4)
{
  int id = blockIdx.x * 256 + threadIdx.x;
  if (id >= total) return;
  int n = id / (L * d4);
  int c = id % d4;
  O[id] = H[(size_t)n * d4 + c];
}

extern "C" void kernel_launch(void* const* d_in, const int* in_sizes, int n_in,
                              void* d_out, int out_size, void* d_ws, size_t ws_size,
                              hipStream_t stream)
{
  const float* vision = (const float*)d_in[0];
  const float* text   = (const float*)d_in[1];
  const float* fc_w   = (const float*)d_in[2];
  const float* fc_b   = (const float*)d_in[3];
  const float* ln_g   = (const float*)d_in[4];
  const float* ln_b   = (const float*)d_in[5];
  const float* w1     = (const float*)d_in[6];
  const float* b1     = (const float*)d_in[7];
  const float* w2     = (const float*)d_in[8];
  const float* b2     = (const float*)d_in[9];
  float* out = (float*)d_out;

  const int N = 4096, Lv = 16, M = 4096, Din = 512, D = 768, Dhp = 256;

  char* p = (char*)d_ws;
  auto alloc = [&](size_t bytes) { char* r = p; p += (bytes + 255) & ~(size_t)255; return r; };
  u16*   mean_v = (u16*)alloc((size_t)N * D * 2);
  u16*   mean_t = (u16*)alloc((size_t)M * Din * 2);
  u16*   fcw_bf = (u16*)alloc((size_t)D * Din * 2);
  u16*   w1p    = (u16*)alloc((size_t)Dhp * D * 2);
  u16*   w2p    = (u16*)alloc((size_t)D * Dhp * 2);
  float* b1p    = (float*)alloc((size_t)Dhp * 4);
  float* denom  = (float*)alloc((size_t)N * 4);
  u16*   t_bf   = (u16*)alloc((size_t)M * D * 2);
  u16*   tT_bf  = (u16*)alloc((size_t)D * M * 2);
  u16*   aff    = (u16*)alloc((size_t)N * M * 2);   // exp(scores), unnormalized
  u16*   ln_o   = (u16*)alloc((size_t)N * D * 2);
  u16*   h1     = (u16*)alloc((size_t)N * Dhp * 2);
  float* aggp   = (float*)alloc((size_t)4 * N * D * 4);  // 4 split-K partials
  float* h2     = (float*)aff;   // aff dead after agg GEMM; 12.6MB <= 33.5MB

  // 1. fused prologue: means + weight casts/pads (one launch)
  {
    int total = 4096 * 192 + 4096 * 128 + 768 * 512 + 256 * 768 + 768 * 256 + 256;
    prologue_kernel<<<(total + 255) / 256, 256, 0, stream>>>(
        vision, text, fc_w, w1, w2, b1, mean_v, mean_t, fcw_bf, w1p, w2p, b1p);
  }

  // 2. t = mean_t @ fc_w^T + fc_b   [M, D] bf16 (direct)
  gemm_nt<false, true><<<dim3(D / 128, M / 128), 256, 0, stream>>>(
      mean_t, fcw_bf, fc_b, 1.f, nullptr, t_bf, M, D, Din, Din, Din, 0, 0);

  // 3. tT = t^T  (bf16 -> bf16)
  transpose_bf16_kernel<<<dim3(D / 32, M / 32), 256, 0, stream>>>(t_bf, tT_bf, M, D);

  // 4. aff = exp(mean_v @ t^T / sqrt(D))  [N, M] bf16 — unnormalized softmax
  gemm256_nt_bf16<true><<<dim3(M / 256, N / 256), 512, 0, stream>>>(
      mean_v, t_bf, 1.f / sqrtf(768.f), aff, M, D, D, D);

  // 5. denom_n = sum_m aff[n][m]  (softmax denominator, from the same bf16
  //    values the agg GEMM consumes)
  rowsum_kernel<<<N, 256, 0, stream>>>(aff, denom);

  // 6. agg~ = aff @ t  [N, D] fp32, split-K=4 partials (B = tT, NT form)
  gemm_nt<false, false><<<dim3(D / 128, N / 128, 4), 256, 0, stream>>>(
      aff, tT_bf, nullptr, 1.f, aggp, nullptr, N, D, M / 4, M, M,
      M / 4, (long long)N * D);

  // 7. LayerNorm of (partial-sum / denom) -> bf16 (exact reference eps)
  ln4_kernel<<<N, 256, 0, stream>>>(aggp, (long long)N * D, denom, ln_g, ln_b, ln_o);

  // 8. h1 = relu(ln @ w1^T + b1)   [N, Dhp] bf16  (padded 192->256)
  gemm_nt<true, true><<<dim3(Dhp / 128, N / 128), 256, 0, stream>>>(
      ln_o, w1p, b1p, 1.f, nullptr, h1, N, Dhp, D, D, D, 0, 0);

  // 9. h2 = h1 @ w2^T + b2   [N, D] fp32
  gemm_nt<false, false><<<dim3(D / 128, N / 128), 256, 0, stream>>>(
      h1, w2p, b2, 1.f, h2, nullptr, N, D, Dhp, Dhp, Dhp, 0, 0);

  // 10. broadcast to [N, Lv, D]
  int total4 = N * Lv * (D / 4);
  bcast_kernel<<<(total4 + 255) / 256, 256, 0, stream>>>(
      (const f32x4*)h2, (f32x4*)out, total4, Lv, D / 4);
}

// Round 7
// 385.326 us; speedup vs baseline: 1.2061x; 1.0013x over previous
//
#include <hip/hip_runtime.h>
#include <math.h>

typedef unsigned short u16;
typedef __attribute__((ext_vector_type(4))) float f32x4;
typedef __attribute__((ext_vector_type(8))) short bf16x8;

#define GLOBAL_AS __attribute__((address_space(1)))
#define LDS_AS __attribute__((address_space(3)))

__device__ __forceinline__ u16 f2bf(float f) {
  unsigned u = __builtin_bit_cast(unsigned, f);
  unsigned lsb = (u >> 16) & 1u;
  u += 0x7fffu + lsb;            // round-to-nearest-even
  return (u16)(u >> 16);
}

__device__ __forceinline__ float bf2f(u16 b) {
  return __builtin_bit_cast(float, ((unsigned)b) << 16);
}

__device__ __forceinline__ void gload16(const void* g, void* l) {
  __builtin_amdgcn_global_load_lds((const GLOBAL_AS void*)g, (LDS_AS void*)l, 16, 0, 0);
}

// ---- fused prologue: mean_v, mean_t, cast fc_w, pad-cast w1,w2, pad b1 ------
__global__ __launch_bounds__(256) void prologue_kernel(
    const float* __restrict__ vision, const float* __restrict__ text,
    const float* __restrict__ fc_w, const float* __restrict__ w1,
    const float* __restrict__ w2, const float* __restrict__ b1,
    u16* __restrict__ mean_v, u16* __restrict__ mean_t,
    u16* __restrict__ fcw_bf, u16* __restrict__ w1p, u16* __restrict__ w2p,
    float* __restrict__ b1p)
{
  const int n_mv = 4096 * 192;   // N * D/4
  const int n_mt = 4096 * 128;   // M * Din/4
  const int n_fcw = 768 * 512;
  const int n_w1 = 256 * 768;
  const int n_w2 = 768 * 256;
  int id = blockIdx.x * 256 + threadIdx.x;

  if (id < n_mv) {               // mean over Lv=16 of vision[N][16][768]
    int n = id / 192, c = id % 192;
    const f32x4* x = (const f32x4*)vision + (size_t)n * 16 * 192 + c;
    f32x4 s = {0.f, 0.f, 0.f, 0.f};
#pragma unroll
    for (int l = 0; l < 16; ++l) s += x[(size_t)l * 192];
    s *= (1.f / 16.f);
    ushort4 o; o.x = f2bf(s.x); o.y = f2bf(s.y); o.z = f2bf(s.z); o.w = f2bf(s.w);
    ((ushort4*)mean_v)[id] = o;
    return;
  }
  id -= n_mv;
  if (id < n_mt) {               // mean over Lt=77 of text[M][77][512]
    int n = id / 128, c = id % 128;
    const f32x4* x = (const f32x4*)text + (size_t)n * 77 * 128 + c;
    f32x4 s = {0.f, 0.f, 0.f, 0.f};
    for (int l = 0; l < 77; ++l) s += x[(size_t)l * 128];
    s *= (1.f / 77.f);
    ushort4 o; o.x = f2bf(s.x); o.y = f2bf(s.y); o.z = f2bf(s.z); o.w = f2bf(s.w);
    ((ushort4*)mean_t)[id] = o;
    return;
  }
  id -= n_mt;
  if (id < n_fcw) { fcw_bf[id] = f2bf(fc_w[id]); return; }
  id -= n_fcw;
  if (id < n_w1) {
    int r = id / 768;
    w1p[id] = (r < 192) ? f2bf(w1[id]) : (u16)0;
    return;
  }
  id -= n_w1;
  if (id < n_w2) {
    int r = id / 256, c = id % 256;
    w2p[id] = (c < 192) ? f2bf(w2[(size_t)r * 192 + c]) : (u16)0;
    return;
  }
  id -= n_w2;
  if (id < 256) b1p[id] = (id < 192) ? b1[id] : 0.f;
}

// ------- 256x256 deep-pipelined NT bf16 GEMM, C bf16 = exp(alpha * A@B^T) ---
// BK=32, 3 LDS buffers, stage-2-ahead, counted vmcnt, 1 raw barrier per iter.
// Epilogue also emits per-row sums of exp into dsum[row][gridDim.x] partials
// (fp32, deterministic; no atomics) -> softmax denominator recovered free.
__global__ __launch_bounds__(512, 2) void gemm256_exp_bf16(
    const u16* __restrict__ A, const u16* __restrict__ B, float alpha,
    u16* __restrict__ C, float* __restrict__ dsum, int N, int K, int lda, int ldb)
{
  __shared__ u16 lA[3][256 * 32];   // 3 x 16 KB
  __shared__ u16 lB[3][256 * 32];   // 3 x 16 KB   (total 96 KB)
  const int tid = threadIdx.x;
  const int w = tid >> 6, lane = tid & 63;
  const int brow = blockIdx.y * 256, bcol = blockIdx.x * 256;
  const int wr = w >> 2, wc = w & 3;   // 2M x 4N wave grid

  f32x4 acc[8][4];
#pragma unroll
  for (int i = 0; i < 8; ++i)
#pragma unroll
    for (int j = 0; j < 4; ++j) acc[i][j] = (f32x4){0.f, 0.f, 0.f, 0.f};

  const int srow = lane >> 2;          // 0..15
  const int scol = (lane & 3) * 8;     // 0,8,16,24
  const size_t ga0 = (size_t)(brow + (w * 2 + 0) * 16 + srow) * lda + scol;
  const size_t ga1 = (size_t)(brow + (w * 2 + 1) * 16 + srow) * lda + scol;
  const size_t gb0 = (size_t)(bcol + (w * 2 + 0) * 16 + srow) * ldb + scol;
  const size_t gb1 = (size_t)(bcol + (w * 2 + 1) * 16 + srow) * ldb + scol;

  const int fr = lane & 15, fk = (lane >> 4) * 8;
  const int NT = K >> 5;

  auto stage = [&](int ti, int b) {
    const int k0 = ti << 5;
    char* la = (char*)&lA[b][0] + w * 2048;
    char* lb = (char*)&lB[b][0] + w * 2048;
    gload16(A + ga0 + k0, la);
    gload16(A + ga1 + k0, la + 1024);
    gload16(B + gb0 + k0, lb);
    gload16(B + gb1 + k0, lb + 1024);
  };

  stage(0, 0);
  stage(1, 1);

  int bR = 0;
  for (int it = 0; it < NT; ++it) {
    if (it + 1 < NT) { asm volatile("s_waitcnt vmcnt(4)" ::: "memory"); }
    else             { asm volatile("s_waitcnt vmcnt(0)" ::: "memory"); }
    __builtin_amdgcn_s_barrier();
    asm volatile("" ::: "memory");

    int bW = bR + 2; if (bW >= 3) bW -= 3;
    if (it + 2 < NT) stage(it + 2, bW);

    const u16* la = lA[bR];
    const u16* lb = lB[bR];
    bf16x8 av[8], bv[4];
#pragma unroll
    for (int mi = 0; mi < 8; ++mi)
      av[mi] = *(const bf16x8*)&la[(wr * 128 + mi * 16 + fr) * 32 + fk];
#pragma unroll
    for (int ni = 0; ni < 4; ++ni)
      bv[ni] = *(const bf16x8*)&lb[(wc * 64 + ni * 16 + fr) * 32 + fk];

    __builtin_amdgcn_s_setprio(1);
#pragma unroll
    for (int mi = 0; mi < 8; ++mi)
#pragma unroll
      for (int ni = 0; ni < 4; ++ni)
        acc[mi][ni] = __builtin_amdgcn_mfma_f32_16x16x32_bf16(av[mi], bv[ni], acc[mi][ni], 0, 0, 0);
    __builtin_amdgcn_s_setprio(0);

    bR = (bR + 1 == 3) ? 0 : bR + 1;
  }

  const int fq = lane >> 4;
  float rsum[8][4];
#pragma unroll
  for (int mi = 0; mi < 8; ++mi)
#pragma unroll
    for (int r = 0; r < 4; ++r) rsum[mi][r] = 0.f;

  // exp + store + in-lane row partials (sum over ni)
#pragma unroll
  for (int mi = 0; mi < 8; ++mi) {
#pragma unroll
    for (int ni = 0; ni < 4; ++ni) {
      int col = bcol + wc * 64 + ni * 16 + fr;
#pragma unroll
      for (int r = 0; r < 4; ++r) {
        int row = brow + wr * 128 + mi * 16 + fq * 4 + r;
        float v = __expf(acc[mi][ni][r] * alpha);
        C[(size_t)row * N + col] = f2bf(v);
        rsum[mi][r] += v;
      }
    }
  }
  // reduce over the 16 fr-lanes of each fq group
#pragma unroll
  for (int mi = 0; mi < 8; ++mi)
#pragma unroll
    for (int r = 0; r < 4; ++r) {
      float s = rsum[mi][r];
      s += __shfl_xor(s, 1); s += __shfl_xor(s, 2);
      s += __shfl_xor(s, 4); s += __shfl_xor(s, 8);
      rsum[mi][r] = s;
    }
  __syncthreads();                       // all waves done reading lA/lB
  float* wsum = (float*)&lA[0][0];       // [4 wc][256 rows]
  if (fr == 0) {
#pragma unroll
    for (int mi = 0; mi < 8; ++mi)
#pragma unroll
      for (int r = 0; r < 4; ++r)
        wsum[wc * 256 + wr * 128 + mi * 16 + fq * 4 + r] = rsum[mi][r];
  }
  __syncthreads();
  if (tid < 256) {
    float s = wsum[tid] + wsum[256 + tid] + wsum[512 + tid] + wsum[768 + tid];
    dsum[(size_t)(brow + tid) * 16 + blockIdx.x] = s;
  }
}

// ---------------- NT bf16 MFMA GEMM: C[M,N] = alpha*A[M,K]@B[N,K]^T + bias ----
// 128x128 tile, BK=32, 3 LDS buffers, stage-2-ahead, counted vmcnt.
// TRANST: additionally write C^T (bf16) via LDS-transposed coalesced stores.
// BCAST16: write each C value to 16 consecutive row-copies (out[N][16][D]).
// blockIdx.z = split-K slice: A/B advance by kofs elements, Cf by cofs.
template<bool RELU, bool BF16OUT, bool TRANST, bool BCAST16>
__global__ __launch_bounds__(256) void gemm_nt(
    const u16* __restrict__ A, const u16* __restrict__ B,
    const float* __restrict__ bias, float alpha,
    float* __restrict__ Cf, u16* __restrict__ Cb,
    u16* __restrict__ Ct, int ldt,
    int M, int N, int K, int lda, int ldb,
    int kofs, long long cofs)
{
  __shared__ char lds[49152];            // 3 bufs x (A 8KB + B 8KB)
  const int t = threadIdx.x;
  const int w = t >> 6, lane = t & 63;
  const int brow = blockIdx.y * 128, bcol = blockIdx.x * 128;
  const int wr = w >> 1, wc = w & 1;     // wave sub-tile 64x64
  const int kz = blockIdx.z;

  A += (size_t)kz * kofs;
  B += (size_t)kz * kofs;
  Cf += kz * cofs;

  f32x4 acc[4][4];
#pragma unroll
  for (int i = 0; i < 4; ++i)
#pragma unroll
    for (int j = 0; j < 4; ++j) acc[i][j] = (f32x4){0.f, 0.f, 0.f, 0.f};

  const int srow = t >> 2;               // 0..63
  const int scol = (t & 3) * 8;
  const size_t aoff0 = (size_t)(brow + srow) * lda + scol;
  const size_t boff0 = (size_t)(bcol + srow) * ldb + scol;
  const size_t aoff1 = aoff0 + (size_t)64 * lda;
  const size_t boff1 = boff0 + (size_t)64 * ldb;

  const int fr = lane & 15, fk = (lane >> 4) * 8;
  const int NT = K >> 5;

  auto stage = [&](int ti, int b) {
    const int k0 = ti << 5;
    char* la = lds + b * 16384 + w * 1024;
    char* lb = lds + b * 16384 + 8192 + w * 1024;
    gload16(A + aoff0 + k0, la);
    gload16(A + aoff1 + k0, la + 4096);
    gload16(B + boff0 + k0, lb);
    gload16(B + boff1 + k0, lb + 4096);
  };

  stage(0, 0);
  stage(1, 1);

  int bR = 0;
  for (int it = 0; it < NT; ++it) {
    if (it + 1 < NT) { asm volatile("s_waitcnt vmcnt(4)" ::: "memory"); }
    else             { asm volatile("s_waitcnt vmcnt(0)" ::: "memory"); }
    __builtin_amdgcn_s_barrier();
    asm volatile("" ::: "memory");

    int bW = bR + 2; if (bW >= 3) bW -= 3;
    if (it + 2 < NT) stage(it + 2, bW);

    const u16* la = (const u16*)(lds + bR * 16384);
    const u16* lb = (const u16*)(lds + bR * 16384 + 8192);
    bf16x8 av[4], bv[4];
#pragma unroll
    for (int mi = 0; mi < 4; ++mi)
      av[mi] = *(const bf16x8*)&la[(wr * 64 + mi * 16 + fr) * 32 + fk];
#pragma unroll
    for (int ni = 0; ni < 4; ++ni)
      bv[ni] = *(const bf16x8*)&lb[(wc * 64 + ni * 16 + fr) * 32 + fk];

    __builtin_amdgcn_s_setprio(1);
#pragma unroll
    for (int mi = 0; mi < 4; ++mi)
#pragma unroll
      for (int ni = 0; ni < 4; ++ni)
        acc[mi][ni] = __builtin_amdgcn_mfma_f32_16x16x32_bf16(av[mi], bv[ni], acc[mi][ni], 0, 0, 0);
    __builtin_amdgcn_s_setprio(0);

    bR = (bR + 1 == 3) ? 0 : bR + 1;
  }

  const int fq = lane >> 4;
  u16* tileT = (u16*)lds;                // [128 cols][130] when TRANST
  if (TRANST) __syncthreads();           // all waves done reading lds bufs

#pragma unroll
  for (int mi = 0; mi < 4; ++mi) {
#pragma unroll
    for (int ni = 0; ni < 4; ++ni) {
      int cl = wc * 64 + ni * 16 + fr;
      int col = bcol + cl;
      float bb = bias ? bias[col] : 0.f;
#pragma unroll
      for (int r = 0; r < 4; ++r) {
        int rl = wr * 64 + mi * 16 + fq * 4 + r;
        int row = brow + rl;
        float v = acc[mi][ni][r] * alpha + bb;
        if (RELU) v = fmaxf(v, 0.f);
        if (BF16OUT) {
          u16 bf = f2bf(v);
          Cb[(size_t)row * N + col] = bf;
          if (TRANST) tileT[cl * 130 + rl] = bf;
        } else if (BCAST16) {
          size_t b0 = ((size_t)row * 16) * (size_t)N + col;
#pragma unroll
          for (int l = 0; l < 16; ++l) Cf[b0 + (size_t)l * N] = v;
        } else {
          Cf[(size_t)row * N + col] = v;
        }
      }
    }
  }

  if (TRANST) {
    __syncthreads();
    int c2 = t >> 1, off = (t & 1) * 64;
    size_t base = (size_t)(bcol + c2) * ldt + brow + off;
#pragma unroll
    for (int j = 0; j < 8; ++j)
      *(bf16x8*)&Ct[base + j * 8] = *(const bf16x8*)&tileT[c2 * 130 + off + j * 8];
  }
}

// -- LayerNorm rows (D=768): sum 4 split-K partials, scale by 1/denom, LN -----
// denom = sum of 16 dsum partials per row (fp32, deterministic).
__global__ __launch_bounds__(256) void ln4_kernel(
    const float* __restrict__ X, long long ps, const float* __restrict__ dsum,
    const float* __restrict__ g, const float* __restrict__ b,
    u16* __restrict__ Y)
{
  __shared__ float red[4];
  int row = blockIdx.x, t = threadIdx.x;
  const float* x = X + (size_t)row * 768;
  float s16 = 0.f;
#pragma unroll
  for (int j = 0; j < 16; ++j) s16 += dsum[(size_t)row * 16 + j];
  float inv_d = 1.f / s16;

  float v0 = (x[t]       + x[ps + t]       + x[2 * ps + t]       + x[3 * ps + t]) * inv_d;
  float v1 = (x[t + 256] + x[ps + t + 256] + x[2 * ps + t + 256] + x[3 * ps + t + 256]) * inv_d;
  float v2 = (x[t + 512] + x[ps + t + 512] + x[2 * ps + t + 512] + x[3 * ps + t + 512]) * inv_d;

  float s = v0 + v1 + v2;
#pragma unroll
  for (int off = 32; off > 0; off >>= 1) s += __shfl_xor(s, off);
  if ((t & 63) == 0) red[t >> 6] = s;
  __syncthreads();
  float mu = (red[0] + red[1] + red[2] + red[3]) * (1.f / 768.f);
  __syncthreads();

  float d0 = v0 - mu, d1 = v1 - mu, d2 = v2 - mu;
  float q = d0 * d0 + d1 * d1 + d2 * d2;
#pragma unroll
  for (int off = 32; off > 0; off >>= 1) q += __shfl_xor(q, off);
  if ((t & 63) == 0) red[t >> 6] = q;
  __syncthreads();
  float var = (red[0] + red[1] + red[2] + red[3]) * (1.f / 768.f);
  float inv = rsqrtf(var + 1e-5f);

  u16* y = Y + (size_t)row * 768;
  y[t]       = f2bf(d0 * inv * g[t]       + b[t]);
  y[t + 256] = f2bf(d1 * inv * g[t + 256] + b[t + 256]);
  y[t + 512] = f2bf(d2 * inv * g[t + 512] + b[t + 512]);
}

extern "C" void kernel_launch(void* const* d_in, const int* in_sizes, int n_in,
                              void* d_out, int out_size, void* d_ws, size_t ws_size,
                              hipStream_t stream)
{
  const float* vision = (const float*)d_in[0];
  const float* text   = (const float*)d_in[1];
  const float* fc_w   = (const float*)d_in[2];
  const float* fc_b   = (const float*)d_in[3];
  const float* ln_g   = (const float*)d_in[4];
  const float* ln_b   = (const float*)d_in[5];
  const float* w1     = (const float*)d_in[6];
  const float* b1     = (const float*)d_in[7];
  const float* w2     = (const float*)d_in[8];
  const float* b2     = (const float*)d_in[9];
  float* out = (float*)d_out;

  const int N = 4096, M = 4096, Din = 512, D = 768, Dhp = 256;

  char* p = (char*)d_ws;
  auto alloc = [&](size_t bytes) { char* r = p; p += (bytes + 255) & ~(size_t)255; return r; };
  u16*   mean_v = (u16*)alloc((size_t)N * D * 2);
  u16*   mean_t = (u16*)alloc((size_t)M * Din * 2);
  u16*   fcw_bf = (u16*)alloc((size_t)D * Din * 2);
  u16*   w1p    = (u16*)alloc((size_t)Dhp * D * 2);
  u16*   w2p    = (u16*)alloc((size_t)D * Dhp * 2);
  float* b1p    = (float*)alloc((size_t)Dhp * 4);
  float* dsum   = (float*)alloc((size_t)N * 16 * 4);
  u16*   t_bf   = (u16*)alloc((size_t)M * D * 2);
  u16*   tT_bf  = (u16*)alloc((size_t)D * M * 2);
  u16*   aff    = (u16*)alloc((size_t)N * M * 2);   // exp(scores), unnormalized
  u16*   ln_o   = (u16*)alloc((size_t)N * D * 2);
  u16*   h1     = (u16*)alloc((size_t)N * Dhp * 2);
  float* aggp   = (float*)alloc((size_t)4 * N * D * 4);  // 4 split-K partials

  // 1. fused prologue: means + weight casts/pads
  {
    int total = 4096 * 192 + 4096 * 128 + 768 * 512 + 256 * 768 + 768 * 256 + 256;
    prologue_kernel<<<(total + 255) / 256, 256, 0, stream>>>(
        vision, text, fc_w, w1, w2, b1, mean_v, mean_t, fcw_bf, w1p, w2p, b1p);
  }

  // 2. t = mean_t @ fc_w^T + fc_b  [M, D] bf16 + fused transpose tT [D, M]
  gemm_nt<false, true, true, false><<<dim3(D / 128, M / 128), 256, 0, stream>>>(
      mean_t, fcw_bf, fc_b, 1.f, nullptr, t_bf, tT_bf, M, M, D, Din, Din, Din, 0, 0);

  // 3. aff = exp(mean_v @ t^T / sqrt(D))  [N, M] bf16 + fused row-sum partials
  gemm256_exp_bf16<<<dim3(M / 256, N / 256), 512, 0, stream>>>(
      mean_v, t_bf, 1.f / sqrtf(768.f), aff, dsum, M, D, D, D);

  // 4. agg~ = aff @ t  [N, D] fp32, split-K=4 partials (B = tT, NT form)
  gemm_nt<false, false, false, false><<<dim3(D / 128, N / 128, 4), 256, 0, stream>>>(
      aff, tT_bf, nullptr, 1.f, aggp, nullptr, nullptr, 0, N, D, M / 4, M, M,
      M / 4, (long long)N * D);

  // 5. LayerNorm of (partial-sum / denom) -> bf16
  ln4_kernel<<<N, 256, 0, stream>>>(aggp, (long long)N * D, dsum, ln_g, ln_b, ln_o);

  // 6. h1 = relu(ln @ w1^T + b1)   [N, Dhp] bf16  (padded 192->256)
  gemm_nt<true, true, false, false><<<dim3(Dhp / 128, N / 128), 256, 0, stream>>>(
      ln_o, w1p, b1p, 1.f, nullptr, h1, nullptr, 0, N, Dhp, D, D, D, 0, 0);

  // 7. h2 = h1 @ w2^T + b2, broadcast-stored to out[N][16][D]
  gemm_nt<false, false, false, true><<<dim3(D / 128, N / 128), 256, 0, stream>>>(
      h1, w2p, b2, 1.f, out, nullptr, nullptr, 0, N, D, Dhp, Dhp, Dhp, 0, 0);
}

// Round 8
// 379.084 us; speedup vs baseline: 1.2259x; 1.0165x over previous
//
#include <hip/hip_runtime.h>
#include <math.h>

typedef unsigned short u16;
typedef __attribute__((ext_vector_type(4))) float f32x4;
typedef __attribute__((ext_vector_type(8))) short bf16x8;

#define GLOBAL_AS __attribute__((address_space(1)))
#define LDS_AS __attribute__((address_space(3)))

__device__ __forceinline__ u16 f2bf(float f) {
  unsigned u = __builtin_bit_cast(unsigned, f);
  unsigned lsb = (u >> 16) & 1u;
  u += 0x7fffu + lsb;            // round-to-nearest-even
  return (u16)(u >> 16);
}

__device__ __forceinline__ float bf2f(u16 b) {
  return __builtin_bit_cast(float, ((unsigned)b) << 16);
}

__device__ __forceinline__ void gload16(const void* g, void* l) {
  __builtin_amdgcn_global_load_lds((const GLOBAL_AS void*)g, (LDS_AS void*)l, 16, 0, 0);
}

// ---- fused prologue: mean_v, mean_t, cast fc_w, pad-cast w1,w2, pad b1 ------
__global__ __launch_bounds__(256) void prologue_kernel(
    const float* __restrict__ vision, const float* __restrict__ text,
    const float* __restrict__ fc_w, const float* __restrict__ w1,
    const float* __restrict__ w2, const float* __restrict__ b1,
    u16* __restrict__ mean_v, u16* __restrict__ mean_t,
    u16* __restrict__ fcw_bf, u16* __restrict__ w1p, u16* __restrict__ w2p,
    float* __restrict__ b1p)
{
  const int n_mv = 4096 * 192;   // N * D/4
  const int n_mt = 4096 * 128;   // M * Din/4
  const int n_fcw = 768 * 512;
  const int n_w1 = 256 * 768;
  const int n_w2 = 768 * 256;
  int id = blockIdx.x * 256 + threadIdx.x;

  if (id < n_mv) {               // mean over Lv=16 of vision[N][16][768]
    int n = id / 192, c = id % 192;
    const f32x4* x = (const f32x4*)vision + (size_t)n * 16 * 192 + c;
    f32x4 s = {0.f, 0.f, 0.f, 0.f};
#pragma unroll
    for (int l = 0; l < 16; ++l) s += x[(size_t)l * 192];
    s *= (1.f / 16.f);
    ushort4 o; o.x = f2bf(s.x); o.y = f2bf(s.y); o.z = f2bf(s.z); o.w = f2bf(s.w);
    ((ushort4*)mean_v)[id] = o;
    return;
  }
  id -= n_mv;
  if (id < n_mt) {               // mean over Lt=77 of text[M][77][512]
    int n = id / 128, c = id % 128;
    const f32x4* x = (const f32x4*)text + (size_t)n * 77 * 128 + c;
    f32x4 s = {0.f, 0.f, 0.f, 0.f};
#pragma unroll 7
    for (int l = 0; l < 77; ++l) s += x[(size_t)l * 128];
    s *= (1.f / 77.f);
    ushort4 o; o.x = f2bf(s.x); o.y = f2bf(s.y); o.z = f2bf(s.z); o.w = f2bf(s.w);
    ((ushort4*)mean_t)[id] = o;
    return;
  }
  id -= n_mt;
  if (id < n_fcw) { fcw_bf[id] = f2bf(fc_w[id]); return; }
  id -= n_fcw;
  if (id < n_w1) {
    int r = id / 768;
    w1p[id] = (r < 192) ? f2bf(w1[id]) : (u16)0;
    return;
  }
  id -= n_w1;
  if (id < n_w2) {
    int r = id / 256, c = id % 256;
    w2p[id] = (c < 192) ? f2bf(w2[(size_t)r * 192 + c]) : (u16)0;
    return;
  }
  id -= n_w2;
  if (id < 256) b1p[id] = (id < 192) ? b1[id] : 0.f;
}

// ------- 256x256 deep-pipelined NT bf16 GEMM, C bf16 = exp(alpha * A@B^T) ---
// BK=32, 3 LDS buffers, stage-2-ahead, counted vmcnt, 1 raw barrier per iter.
// XCD-swizzled blockIdx (grid must be %8==0). C written via LDS-staged
// 256x128 stripes (coalesced 256B rows vs 32B scatter). Row exp-sums ->
// dsum[row][gridx] fp32 partials (deterministic, no atomics).
__global__ __launch_bounds__(512, 2) void gemm256_exp_bf16(
    const u16* __restrict__ A, const u16* __restrict__ B, float alpha,
    u16* __restrict__ C, float* __restrict__ dsum, int N, int K, int lda, int ldb)
{
  __shared__ char lds[98304];          // A bufs 0..48K, B bufs 48K..96K
  const int tid = threadIdx.x;
  const int w = tid >> 6, lane = tid & 63;

  // XCD-aware bijective swizzle
  const int gx = gridDim.x;
  const int nb = gx * gridDim.y;
  int b0 = blockIdx.y * gx + blockIdx.x;
  int swz = (b0 & 7) * (nb >> 3) + (b0 >> 3);
  const int bx = swz % gx, by = swz / gx;
  const int brow = by * 256, bcol = bx * 256;
  const int wr = w >> 2, wc = w & 3;   // 2M x 4N wave grid

  f32x4 acc[8][4];
#pragma unroll
  for (int i = 0; i < 8; ++i)
#pragma unroll
    for (int j = 0; j < 4; ++j) acc[i][j] = (f32x4){0.f, 0.f, 0.f, 0.f};

  const int srow = lane >> 2;          // 0..15
  const int scol = (lane & 3) * 8;     // 0,8,16,24
  const size_t ga0 = (size_t)(brow + (w * 2 + 0) * 16 + srow) * lda + scol;
  const size_t ga1 = (size_t)(brow + (w * 2 + 1) * 16 + srow) * lda + scol;
  const size_t gb0 = (size_t)(bcol + (w * 2 + 0) * 16 + srow) * ldb + scol;
  const size_t gb1 = (size_t)(bcol + (w * 2 + 1) * 16 + srow) * ldb + scol;

  const int fr = lane & 15, fk = (lane >> 4) * 8;
  const int NT = K >> 5;

  auto stage = [&](int ti, int b) {
    const int k0 = ti << 5;
    char* la = lds + b * 16384 + w * 2048;
    char* lb = lds + 49152 + b * 16384 + w * 2048;
    gload16(A + ga0 + k0, la);
    gload16(A + ga1 + k0, la + 1024);
    gload16(B + gb0 + k0, lb);
    gload16(B + gb1 + k0, lb + 1024);
  };

  stage(0, 0);
  stage(1, 1);

  int bR = 0;
  for (int it = 0; it < NT; ++it) {
    if (it + 1 < NT) { asm volatile("s_waitcnt vmcnt(4)" ::: "memory"); }
    else             { asm volatile("s_waitcnt vmcnt(0)" ::: "memory"); }
    __builtin_amdgcn_s_barrier();
    asm volatile("" ::: "memory");

    int bW = bR + 2; if (bW >= 3) bW -= 3;
    if (it + 2 < NT) stage(it + 2, bW);

    const u16* la = (const u16*)(lds + bR * 16384);
    const u16* lb = (const u16*)(lds + 49152 + bR * 16384);
    bf16x8 av[8], bv[4];
#pragma unroll
    for (int mi = 0; mi < 8; ++mi)
      av[mi] = *(const bf16x8*)&la[(wr * 128 + mi * 16 + fr) * 32 + fk];
#pragma unroll
    for (int ni = 0; ni < 4; ++ni)
      bv[ni] = *(const bf16x8*)&lb[(wc * 64 + ni * 16 + fr) * 32 + fk];

    __builtin_amdgcn_s_setprio(1);
#pragma unroll
    for (int mi = 0; mi < 8; ++mi)
#pragma unroll
      for (int ni = 0; ni < 4; ++ni)
        acc[mi][ni] = __builtin_amdgcn_mfma_f32_16x16x32_bf16(av[mi], bv[ni], acc[mi][ni], 0, 0, 0);
    __builtin_amdgcn_s_setprio(0);

    bR = (bR + 1 == 3) ? 0 : bR + 1;
  }

  const int fq = lane >> 4;
  __syncthreads();                     // retire all main-loop LDS reads

  // exp in place + per-row partial sums (over this wave's 64-col slice)
  float rsum[8][4];
#pragma unroll
  for (int mi = 0; mi < 8; ++mi) {
#pragma unroll
    for (int r = 0; r < 4; ++r) rsum[mi][r] = 0.f;
#pragma unroll
    for (int ni = 0; ni < 4; ++ni)
#pragma unroll
      for (int r = 0; r < 4; ++r) {
        float v = __expf(acc[mi][ni][r] * alpha);
        acc[mi][ni][r] = v;
        rsum[mi][r] += v;
      }
  }
#pragma unroll
  for (int mi = 0; mi < 8; ++mi)
#pragma unroll
    for (int r = 0; r < 4; ++r) {
      float s = rsum[mi][r];
      s += __shfl_xor(s, 1); s += __shfl_xor(s, 2);
      s += __shfl_xor(s, 4); s += __shfl_xor(s, 8);
      rsum[mi][r] = s;
    }
  float* wsum = (float*)(lds + 73728);   // [4 wc][256 rows], disjoint from tile
  if (fr == 0) {
#pragma unroll
    for (int mi = 0; mi < 8; ++mi)
#pragma unroll
      for (int r = 0; r < 4; ++r)
        wsum[wc * 256 + wr * 128 + mi * 16 + fq * 4 + r] = rsum[mi][r];
  }

  // C-write via two 256x128 LDS stripes (coalesced 256B rows)
  u16* tile = (u16*)lds;                 // [256][136] u16 = 68KB
#pragma unroll
  for (int s = 0; s < 2; ++s) {
    if ((wc >> 1) == s) {
#pragma unroll
      for (int mi = 0; mi < 8; ++mi)
#pragma unroll
        for (int ni = 0; ni < 4; ++ni) {
          int cc = (wc & 1) * 64 + ni * 16 + fr;
#pragma unroll
          for (int r = 0; r < 4; ++r) {
            int rr = wr * 128 + mi * 16 + fq * 4 + r;
            tile[rr * 136 + cc] = f2bf(acc[mi][ni][r]);
          }
        }
    }
    __syncthreads();                     // tile written (also fences wsum)
    {
      int row = tid >> 1, part = tid & 1;
      size_t base = (size_t)(brow + row) * N + bcol + s * 128 + part * 64;
      const u16* tr = &tile[row * 136 + part * 64];
#pragma unroll
      for (int j = 0; j < 8; ++j)
        *(bf16x8*)&C[base + j * 8] = *(const bf16x8*)&tr[j * 8];
    }
    __syncthreads();                     // stores done before tile reuse
  }

  if (tid < 256) {
    float s = wsum[tid] + wsum[256 + tid] + wsum[512 + tid] + wsum[768 + tid];
    dsum[(size_t)(brow + tid) * 16 + bx] = s;
  }
}

// ---------------- NT bf16 MFMA GEMM: C[M,N] = alpha*A[M,K]@B[N,K]^T + bias ----
// 128x128 tile, BK=32, 3 LDS buffers, stage-2-ahead, counted vmcnt,
// XCD-swizzled blockIdx (total grid %8==0 required).
// TRANST: additionally write C^T (bf16) via LDS-transposed coalesced stores.
// BCAST16: write each C value to 16 consecutive row-copies (out[N][16][D]).
// blockIdx.z = split-K slice: A/B advance by kofs elements, Cf by cofs.
template<bool RELU, bool BF16OUT, bool TRANST, bool BCAST16>
__global__ __launch_bounds__(256) void gemm_nt(
    const u16* __restrict__ A, const u16* __restrict__ B,
    const float* __restrict__ bias, float alpha,
    float* __restrict__ Cf, u16* __restrict__ Cb,
    u16* __restrict__ Ct, int ldt,
    int M, int N, int K, int lda, int ldb,
    int kofs, long long cofs)
{
  __shared__ char lds[49152];            // 3 bufs x (A 8KB + B 8KB)
  const int t = threadIdx.x;
  const int w = t >> 6, lane = t & 63;

  // XCD-aware bijective swizzle over the flattened grid
  const int gx = gridDim.x, gy = gridDim.y;
  const int nb = gx * gy * gridDim.z;
  int b0 = (blockIdx.z * gy + blockIdx.y) * gx + blockIdx.x;
  int swz = (b0 & 7) * (nb >> 3) + (b0 >> 3);
  const int bx = swz % gx;
  int tmp = swz / gx;
  const int by = tmp % gy, kz = tmp / gy;

  const int brow = by * 128, bcol = bx * 128;
  const int wr = w >> 1, wc = w & 1;     // wave sub-tile 64x64

  A += (size_t)kz * kofs;
  B += (size_t)kz * kofs;
  Cf += kz * cofs;

  f32x4 acc[4][4];
#pragma unroll
  for (int i = 0; i < 4; ++i)
#pragma unroll
    for (int j = 0; j < 4; ++j) acc[i][j] = (f32x4){0.f, 0.f, 0.f, 0.f};

  const int srow = t >> 2;               // 0..63
  const int scol = (t & 3) * 8;
  const size_t aoff0 = (size_t)(brow + srow) * lda + scol;
  const size_t boff0 = (size_t)(bcol + srow) * ldb + scol;
  const size_t aoff1 = aoff0 + (size_t)64 * lda;
  const size_t boff1 = boff0 + (size_t)64 * ldb;

  const int fr = lane & 15, fk = (lane >> 4) * 8;
  const int NT = K >> 5;

  auto stage = [&](int ti, int b) {
    const int k0 = ti << 5;
    char* la = lds + b * 16384 + w * 1024;
    char* lb = lds + b * 16384 + 8192 + w * 1024;
    gload16(A + aoff0 + k0, la);
    gload16(A + aoff1 + k0, la + 4096);
    gload16(B + boff0 + k0, lb);
    gload16(B + boff1 + k0, lb + 4096);
  };

  stage(0, 0);
  stage(1, 1);

  int bR = 0;
  for (int it = 0; it < NT; ++it) {
    if (it + 1 < NT) { asm volatile("s_waitcnt vmcnt(4)" ::: "memory"); }
    else             { asm volatile("s_waitcnt vmcnt(0)" ::: "memory"); }
    __builtin_amdgcn_s_barrier();
    asm volatile("" ::: "memory");

    int bW = bR + 2; if (bW >= 3) bW -= 3;
    if (it + 2 < NT) stage(it + 2, bW);

    const u16* la = (const u16*)(lds + bR * 16384);
    const u16* lb = (const u16*)(lds + bR * 16384 + 8192);
    bf16x8 av[4], bv[4];
#pragma unroll
    for (int mi = 0; mi < 4; ++mi)
      av[mi] = *(const bf16x8*)&la[(wr * 64 + mi * 16 + fr) * 32 + fk];
#pragma unroll
    for (int ni = 0; ni < 4; ++ni)
      bv[ni] = *(const bf16x8*)&lb[(wc * 64 + ni * 16 + fr) * 32 + fk];

    __builtin_amdgcn_s_setprio(1);
#pragma unroll
    for (int mi = 0; mi < 4; ++mi)
#pragma unroll
      for (int ni = 0; ni < 4; ++ni)
        acc[mi][ni] = __builtin_amdgcn_mfma_f32_16x16x32_bf16(av[mi], bv[ni], acc[mi][ni], 0, 0, 0);
    __builtin_amdgcn_s_setprio(0);

    bR = (bR + 1 == 3) ? 0 : bR + 1;
  }

  const int fq = lane >> 4;
  u16* tileT = (u16*)lds;                // [128 cols][130] when TRANST
  if (TRANST) __syncthreads();           // all waves done reading lds bufs

#pragma unroll
  for (int mi = 0; mi < 4; ++mi) {
#pragma unroll
    for (int ni = 0; ni < 4; ++ni) {
      int cl = wc * 64 + ni * 16 + fr;
      int col = bcol + cl;
      float bb = bias ? bias[col] : 0.f;
#pragma unroll
      for (int r = 0; r < 4; ++r) {
        int rl = wr * 64 + mi * 16 + fq * 4 + r;
        int row = brow + rl;
        float v = acc[mi][ni][r] * alpha + bb;
        if (RELU) v = fmaxf(v, 0.f);
        if (BF16OUT) {
          u16 bf = f2bf(v);
          Cb[(size_t)row * N + col] = bf;
          if (TRANST) tileT[cl * 130 + rl] = bf;
        } else if (BCAST16) {
          size_t b0o = ((size_t)row * 16) * (size_t)N + col;
#pragma unroll
          for (int l = 0; l < 16; ++l) Cf[b0o + (size_t)l * N] = v;
        } else {
          Cf[(size_t)row * N + col] = v;
        }
      }
    }
  }

  if (TRANST) {
    __syncthreads();
    int c2 = t >> 1, off = (t & 1) * 64;
    size_t base = (size_t)(bcol + c2) * ldt + brow + off;
#pragma unroll
    for (int j = 0; j < 8; ++j)
      *(bf16x8*)&Ct[base + j * 8] = *(const bf16x8*)&tileT[c2 * 130 + off + j * 8];
  }
}

// -- LayerNorm rows (D=768): sum 4 split-K partials, scale by 1/denom, LN -----
__global__ __launch_bounds__(256) void ln4_kernel(
    const float* __restrict__ X, long long ps, const float* __restrict__ dsum,
    const float* __restrict__ g, const float* __restrict__ b,
    u16* __restrict__ Y)
{
  __shared__ float red[4];
  int row = blockIdx.x, t = threadIdx.x;
  const float* x = X + (size_t)row * 768;
  const f32x4* dv = (const f32x4*)(dsum + (size_t)row * 16);
  f32x4 d4 = dv[0] + dv[1] + dv[2] + dv[3];
  float inv_d = 1.f / (d4.x + d4.y + d4.z + d4.w);

  float v0 = (x[t]       + x[ps + t]       + x[2 * ps + t]       + x[3 * ps + t]) * inv_d;
  float v1 = (x[t + 256] + x[ps + t + 256] + x[2 * ps + t + 256] + x[3 * ps + t + 256]) * inv_d;
  float v2 = (x[t + 512] + x[ps + t + 512] + x[2 * ps + t + 512] + x[3 * ps + t + 512]) * inv_d;

  float s = v0 + v1 + v2;
#pragma unroll
  for (int off = 32; off > 0; off >>= 1) s += __shfl_xor(s, off);
  if ((t & 63) == 0) red[t >> 6] = s;
  __syncthreads();
  float mu = (red[0] + red[1] + red[2] + red[3]) * (1.f / 768.f);
  __syncthreads();

  float d0 = v0 - mu, d1 = v1 - mu, d2 = v2 - mu;
  float q = d0 * d0 + d1 * d1 + d2 * d2;
#pragma unroll
  for (int off = 32; off > 0; off >>= 1) q += __shfl_xor(q, off);
  if ((t & 63) == 0) red[t >> 6] = q;
  __syncthreads();
  float var = (red[0] + red[1] + red[2] + red[3]) * (1.f / 768.f);
  float inv = rsqrtf(var + 1e-5f);

  u16* y = Y + (size_t)row * 768;
  y[t]       = f2bf(d0 * inv * g[t]       + b[t]);
  y[t + 256] = f2bf(d1 * inv * g[t + 256] + b[t + 256]);
  y[t + 512] = f2bf(d2 * inv * g[t + 512] + b[t + 512]);
}

extern "C" void kernel_launch(void* const* d_in, const int* in_sizes, int n_in,
                              void* d_out, int out_size, void* d_ws, size_t ws_size,
                              hipStream_t stream)
{
  const float* vision = (const float*)d_in[0];
  const float* text   = (const float*)d_in[1];
  const float* fc_w   = (const float*)d_in[2];
  const float* fc_b   = (const float*)d_in[3];
  const float* ln_g   = (const float*)d_in[4];
  const float* ln_b   = (const float*)d_in[5];
  const float* w1     = (const float*)d_in[6];
  const float* b1     = (const float*)d_in[7];
  const float* w2     = (const float*)d_in[8];
  const float* b2     = (const float*)d_in[9];
  float* out = (float*)d_out;

  const int N = 4096, M = 4096, Din = 512, D = 768, Dhp = 256;

  char* p = (char*)d_ws;
  auto alloc = [&](size_t bytes) { char* r = p; p += (bytes + 255) & ~(size_t)255; return r; };
  u16*   mean_v = (u16*)alloc((size_t)N * D * 2);
  u16*   mean_t = (u16*)alloc((size_t)M * Din * 2);
  u16*   fcw_bf = (u16*)alloc((size_t)D * Din * 2);
  u16*   w1p    = (u16*)alloc((size_t)Dhp * D * 2);
  u16*   w2p    = (u16*)alloc((size_t)D * Dhp * 2);
  float* b1p    = (float*)alloc((size_t)Dhp * 4);
  float* dsum   = (float*)alloc((size_t)N * 16 * 4);
  u16*   t_bf   = (u16*)alloc((size_t)M * D * 2);
  u16*   tT_bf  = (u16*)alloc((size_t)D * M * 2);
  u16*   aff    = (u16*)alloc((size_t)N * M * 2);   // exp(scores), unnormalized
  u16*   ln_o   = (u16*)alloc((size_t)N * D * 2);
  u16*   h1     = (u16*)alloc((size_t)N * Dhp * 2);
  float* aggp   = (float*)alloc((size_t)4 * N * D * 4);  // 4 split-K partials

  // 1. fused prologue: means + weight casts/pads
  {
    int total = 4096 * 192 + 4096 * 128 + 768 * 512 + 256 * 768 + 768 * 256 + 256;
    prologue_kernel<<<(total + 255) / 256, 256, 0, stream>>>(
        vision, text, fc_w, w1, w2, b1, mean_v, mean_t, fcw_bf, w1p, w2p, b1p);
  }

  // 2. t = mean_t @ fc_w^T + fc_b  [M, D] bf16 + fused transpose tT [D, M]
  gemm_nt<false, true, true, false><<<dim3(D / 128, M / 128), 256, 0, stream>>>(
      mean_t, fcw_bf, fc_b, 1.f, nullptr, t_bf, tT_bf, M, M, D, Din, Din, Din, 0, 0);

  // 3. aff = exp(mean_v @ t^T / sqrt(D))  [N, M] bf16 + fused row-sum partials
  gemm256_exp_bf16<<<dim3(M / 256, N / 256), 512, 0, stream>>>(
      mean_v, t_bf, 1.f / sqrtf(768.f), aff, dsum, M, D, D, D);

  // 4. agg~ = aff @ t  [N, D] fp32, split-K=4 partials (B = tT, NT form)
  gemm_nt<false, false, false, false><<<dim3(D / 128, N / 128, 4), 256, 0, stream>>>(
      aff, tT_bf, nullptr, 1.f, aggp, nullptr, nullptr, 0, N, D, M / 4, M, M,
      M / 4, (long long)N * D);

  // 5. LayerNorm of (partial-sum / denom) -> bf16
  ln4_kernel<<<N, 256, 0, stream>>>(aggp, (long long)N * D, dsum, ln_g, ln_b, ln_o);

  // 6. h1 = relu(ln @ w1^T + b1)   [N, Dhp] bf16  (padded 192->256)
  gemm_nt<true, true, false, false><<<dim3(Dhp / 128, N / 128), 256, 0, stream>>>(
      ln_o, w1p, b1p, 1.f, nullptr, h1, nullptr, 0, N, Dhp, D, D, D, 0, 0);

  // 7. h2 = h1 @ w2^T + b2, broadcast-stored to out[N][16][D]
  gemm_nt<false, false, false, true><<<dim3(D / 128, N / 128), 256, 0, stream>>>(
      h1, w2p, b2, 1.f, out, nullptr, nullptr, 0, N, D, Dhp, Dhp, Dhp, 0, 0);
}

// Round 9
// 331.398 us; speedup vs baseline: 1.4023x; 1.1439x over previous
//
#include <hip/hip_runtime.h>
#include <math.h>

typedef unsigned short u16;
typedef __attribute__((ext_vector_type(4))) float f32x4;
typedef __attribute__((ext_vector_type(8))) short bf16x8;

#define GLOBAL_AS __attribute__((address_space(1)))
#define LDS_AS __attribute__((address_space(3)))

__device__ __forceinline__ u16 f2bf(float f) {
  unsigned u = __builtin_bit_cast(unsigned, f);
  unsigned lsb = (u >> 16) & 1u;
  u += 0x7fffu + lsb;            // round-to-nearest-even
  return (u16)(u >> 16);
}

__device__ __forceinline__ float bf2f(u16 b) {
  return __builtin_bit_cast(float, ((unsigned)b) << 16);
}

__device__ __forceinline__ void gload16(const void* g, void* l) {
  __builtin_amdgcn_global_load_lds((const GLOBAL_AS void*)g, (LDS_AS void*)l, 16, 0, 0);
}

// ---- fused prologue: mean_v, mean_t, cast fc_w, pad-cast w1,w2, pad b1 ------
__global__ __launch_bounds__(256) void prologue_kernel(
    const float* __restrict__ vision, const float* __restrict__ text,
    const float* __restrict__ fc_w, const float* __restrict__ w1,
    const float* __restrict__ w2, const float* __restrict__ b1,
    u16* __restrict__ mean_v, u16* __restrict__ mean_t,
    u16* __restrict__ fcw_bf, u16* __restrict__ w1p, u16* __restrict__ w2p,
    float* __restrict__ b1p)
{
  const int n_mv = 4096 * 192;   // N * D/4
  const int n_mt = 4096 * 128;   // M * Din/4
  const int n_fcw = 768 * 512;
  const int n_w1 = 256 * 768;
  const int n_w2 = 768 * 256;
  int id = blockIdx.x * 256 + threadIdx.x;

  if (id < n_mv) {               // mean over Lv=16 of vision[N][16][768]
    int n = id / 192, c = id % 192;
    const f32x4* x = (const f32x4*)vision + (size_t)n * 16 * 192 + c;
    f32x4 s = {0.f, 0.f, 0.f, 0.f};
#pragma unroll
    for (int l = 0; l < 16; ++l) s += __builtin_nontemporal_load(&x[(size_t)l * 192]);
    s *= (1.f / 16.f);
    ushort4 o; o.x = f2bf(s.x); o.y = f2bf(s.y); o.z = f2bf(s.z); o.w = f2bf(s.w);
    ((ushort4*)mean_v)[id] = o;
    return;
  }
  id -= n_mv;
  if (id < n_mt) {               // mean over Lt=77 of text[M][77][512]
    int n = id / 128, c = id % 128;
    const f32x4* x = (const f32x4*)text + (size_t)n * 77 * 128 + c;
    f32x4 s = {0.f, 0.f, 0.f, 0.f};
#pragma unroll 11
    for (int l = 0; l < 77; ++l) s += __builtin_nontemporal_load(&x[(size_t)l * 128]);
    s *= (1.f / 77.f);
    ushort4 o; o.x = f2bf(s.x); o.y = f2bf(s.y); o.z = f2bf(s.z); o.w = f2bf(s.w);
    ((ushort4*)mean_t)[id] = o;
    return;
  }
  id -= n_mt;
  if (id < n_fcw) { fcw_bf[id] = f2bf(fc_w[id]); return; }
  id -= n_fcw;
  if (id < n_w1) {
    int r = id / 768;
    w1p[id] = (r < 192) ? f2bf(w1[id]) : (u16)0;
    return;
  }
  id -= n_w1;
  if (id < n_w2) {
    int r = id / 256, c = id % 256;
    w2p[id] = (c < 192) ? f2bf(w2[(size_t)r * 192 + c]) : (u16)0;
    return;
  }
  id -= n_w2;
  if (id < 256) b1p[id] = (id < 192) ? b1[id] : 0.f;
}

// ------- 256x256 deep-pipelined NT bf16 GEMM, C bf16 = exp(alpha * A@B^T) ---
// BK=32, 3 LDS buffers, stage-2-ahead, counted vmcnt, 1 raw barrier per iter.
// XCD-swizzled blockIdx. C written via LDS-staged 256x128 stripes. Row
// exp-sums -> dsum[row][gridx] fp32 partials (deterministic, no atomics).
__global__ __launch_bounds__(512, 2) void gemm256_exp_bf16(
    const u16* __restrict__ A, const u16* __restrict__ B, float alpha,
    u16* __restrict__ C, float* __restrict__ dsum, int N, int K, int lda, int ldb)
{
  __shared__ char lds[98304];          // A bufs 0..48K, B bufs 48K..96K
  const int tid = threadIdx.x;
  const int w = tid >> 6, lane = tid & 63;

  // XCD-aware bijective swizzle
  const int gx = gridDim.x;
  const int nb = gx * gridDim.y;
  int b0 = blockIdx.y * gx + blockIdx.x;
  int swz = (b0 & 7) * (nb >> 3) + (b0 >> 3);
  const int bx = swz % gx, by = swz / gx;
  const int brow = by * 256, bcol = bx * 256;
  const int wr = w >> 2, wc = w & 3;   // 2M x 4N wave grid

  f32x4 acc[8][4];
#pragma unroll
  for (int i = 0; i < 8; ++i)
#pragma unroll
    for (int j = 0; j < 4; ++j) acc[i][j] = (f32x4){0.f, 0.f, 0.f, 0.f};

  const int srow = lane >> 2;          // 0..15
  const int scol = (lane & 3) * 8;     // 0,8,16,24
  const size_t ga0 = (size_t)(brow + (w * 2 + 0) * 16 + srow) * lda + scol;
  const size_t ga1 = (size_t)(brow + (w * 2 + 1) * 16 + srow) * lda + scol;
  const size_t gb0 = (size_t)(bcol + (w * 2 + 0) * 16 + srow) * ldb + scol;
  const size_t gb1 = (size_t)(bcol + (w * 2 + 1) * 16 + srow) * ldb + scol;

  const int fr = lane & 15, fk = (lane >> 4) * 8;
  const int NT = K >> 5;

  auto stage = [&](int ti, int b) {
    const int k0 = ti << 5;
    char* la = lds + b * 16384 + w * 2048;
    char* lb = lds + 49152 + b * 16384 + w * 2048;
    gload16(A + ga0 + k0, la);
    gload16(A + ga1 + k0, la + 1024);
    gload16(B + gb0 + k0, lb);
    gload16(B + gb1 + k0, lb + 1024);
  };

  stage(0, 0);
  stage(1, 1);

  int bR = 0;
  for (int it = 0; it < NT; ++it) {
    if (it + 1 < NT) { asm volatile("s_waitcnt vmcnt(4)" ::: "memory"); }
    else             { asm volatile("s_waitcnt vmcnt(0)" ::: "memory"); }
    __builtin_amdgcn_s_barrier();
    asm volatile("" ::: "memory");

    int bW = bR + 2; if (bW >= 3) bW -= 3;
    if (it + 2 < NT) stage(it + 2, bW);

    const u16* la = (const u16*)(lds + bR * 16384);
    const u16* lb = (const u16*)(lds + 49152 + bR * 16384);
    bf16x8 av[8], bv[4];
#pragma unroll
    for (int mi = 0; mi < 8; ++mi)
      av[mi] = *(const bf16x8*)&la[(wr * 128 + mi * 16 + fr) * 32 + fk];
#pragma unroll
    for (int ni = 0; ni < 4; ++ni)
      bv[ni] = *(const bf16x8*)&lb[(wc * 64 + ni * 16 + fr) * 32 + fk];

    __builtin_amdgcn_s_setprio(1);
#pragma unroll
    for (int mi = 0; mi < 8; ++mi)
#pragma unroll
      for (int ni = 0; ni < 4; ++ni)
        acc[mi][ni] = __builtin_amdgcn_mfma_f32_16x16x32_bf16(av[mi], bv[ni], acc[mi][ni], 0, 0, 0);
    __builtin_amdgcn_s_setprio(0);

    bR = (bR + 1 == 3) ? 0 : bR + 1;
  }

  const int fq = lane >> 4;
  __syncthreads();                     // retire all main-loop LDS reads

  // exp in place + per-row partial sums (over this wave's 64-col slice)
  float rsum[8][4];
#pragma unroll
  for (int mi = 0; mi < 8; ++mi) {
#pragma unroll
    for (int r = 0; r < 4; ++r) rsum[mi][r] = 0.f;
#pragma unroll
    for (int ni = 0; ni < 4; ++ni)
#pragma unroll
      for (int r = 0; r < 4; ++r) {
        float v = __expf(acc[mi][ni][r] * alpha);
        acc[mi][ni][r] = v;
        rsum[mi][r] += v;
      }
  }
#pragma unroll
  for (int mi = 0; mi < 8; ++mi)
#pragma unroll
    for (int r = 0; r < 4; ++r) {
      float s = rsum[mi][r];
      s += __shfl_xor(s, 1); s += __shfl_xor(s, 2);
      s += __shfl_xor(s, 4); s += __shfl_xor(s, 8);
      rsum[mi][r] = s;
    }
  float* wsum = (float*)(lds + 73728);   // [4 wc][256 rows], disjoint from tile
  if (fr == 0) {
#pragma unroll
    for (int mi = 0; mi < 8; ++mi)
#pragma unroll
      for (int r = 0; r < 4; ++r)
        wsum[wc * 256 + wr * 128 + mi * 16 + fq * 4 + r] = rsum[mi][r];
  }

  // C-write via two 256x128 LDS stripes (coalesced 256B rows)
  u16* tile = (u16*)lds;                 // [256][136] u16 = 68KB
#pragma unroll
  for (int s = 0; s < 2; ++s) {
    if ((wc >> 1) == s) {
#pragma unroll
      for (int mi = 0; mi < 8; ++mi)
#pragma unroll
        for (int ni = 0; ni < 4; ++ni) {
          int cc = (wc & 1) * 64 + ni * 16 + fr;
#pragma unroll
          for (int r = 0; r < 4; ++r) {
            int rr = wr * 128 + mi * 16 + fq * 4 + r;
            tile[rr * 136 + cc] = f2bf(acc[mi][ni][r]);
          }
        }
    }
    __syncthreads();                     // tile written (also fences wsum)
    {
      int row = tid >> 1, part = tid & 1;
      size_t base = (size_t)(brow + row) * N + bcol + s * 128 + part * 64;
      const u16* tr = &tile[row * 136 + part * 64];
#pragma unroll
      for (int j = 0; j < 8; ++j)
        *(bf16x8*)&C[base + j * 8] = *(const bf16x8*)&tr[j * 8];
    }
    __syncthreads();                     // stores done before tile reuse
  }

  if (tid < 256) {
    float s = wsum[tid] + wsum[256 + tid] + wsum[512 + tid] + wsum[768 + tid];
    dsum[(size_t)(brow + tid) * 16 + bx] = s;
  }
}

// ---------------- NT bf16 MFMA GEMM: C[M,N] = alpha*A[M,K]@B[N,K]^T + bias ----
// 128x128 tile, BK=32, 3 LDS buffers, stage-2-ahead, counted vmcnt,
// XCD-swizzled blockIdx (total grid %8==0 required).
// TRANST: additionally write C^T (bf16) via LDS-transposed coalesced stores.
// BCAST16: write each C value to 16 consecutive row-copies (out[N][16][D]).
// blockIdx.z = split-K slice: A/B advance by kofs elements, Cf by cofs.
template<bool RELU, bool BF16OUT, bool TRANST, bool BCAST16>
__global__ __launch_bounds__(256) void gemm_nt(
    const u16* __restrict__ A, const u16* __restrict__ B,
    const float* __restrict__ bias, float alpha,
    float* __restrict__ Cf, u16* __restrict__ Cb,
    u16* __restrict__ Ct, int ldt,
    int M, int N, int K, int lda, int ldb,
    int kofs, long long cofs)
{
  __shared__ char lds[49152];            // 3 bufs x (A 8KB + B 8KB)
  const int t = threadIdx.x;
  const int w = t >> 6, lane = t & 63;

  // XCD-aware bijective swizzle over the flattened grid
  const int gx = gridDim.x, gy = gridDim.y;
  const int nb = gx * gy * gridDim.z;
  int b0 = (blockIdx.z * gy + blockIdx.y) * gx + blockIdx.x;
  int swz = (b0 & 7) * (nb >> 3) + (b0 >> 3);
  const int bx = swz % gx;
  int tmp = swz / gx;
  const int by = tmp % gy, kz = tmp / gy;

  const int brow = by * 128, bcol = bx * 128;
  const int wr = w >> 1, wc = w & 1;     // wave sub-tile 64x64

  A += (size_t)kz * kofs;
  B += (size_t)kz * kofs;
  Cf += kz * cofs;

  f32x4 acc[4][4];
#pragma unroll
  for (int i = 0; i < 4; ++i)
#pragma unroll
    for (int j = 0; j < 4; ++j) acc[i][j] = (f32x4){0.f, 0.f, 0.f, 0.f};

  const int srow = t >> 2;               // 0..63
  const int scol = (t & 3) * 8;
  const size_t aoff0 = (size_t)(brow + srow) * lda + scol;
  const size_t boff0 = (size_t)(bcol + srow) * ldb + scol;
  const size_t aoff1 = aoff0 + (size_t)64 * lda;
  const size_t boff1 = boff0 + (size_t)64 * ldb;

  const int fr = lane & 15, fk = (lane >> 4) * 8;
  const int NT = K >> 5;

  auto stage = [&](int ti, int b) {
    const int k0 = ti << 5;
    char* la = lds + b * 16384 + w * 1024;
    char* lb = lds + b * 16384 + 8192 + w * 1024;
    gload16(A + aoff0 + k0, la);
    gload16(A + aoff1 + k0, la + 4096);
    gload16(B + boff0 + k0, lb);
    gload16(B + boff1 + k0, lb + 4096);
  };

  stage(0, 0);
  stage(1, 1);

  int bR = 0;
  for (int it = 0; it < NT; ++it) {
    if (it + 1 < NT) { asm volatile("s_waitcnt vmcnt(4)" ::: "memory"); }
    else             { asm volatile("s_waitcnt vmcnt(0)" ::: "memory"); }
    __builtin_amdgcn_s_barrier();
    asm volatile("" ::: "memory");

    int bW = bR + 2; if (bW >= 3) bW -= 3;
    if (it + 2 < NT) stage(it + 2, bW);

    const u16* la = (const u16*)(lds + bR * 16384);
    const u16* lb = (const u16*)(lds + bR * 16384 + 8192);
    bf16x8 av[4], bv[4];
#pragma unroll
    for (int mi = 0; mi < 4; ++mi)
      av[mi] = *(const bf16x8*)&la[(wr * 64 + mi * 16 + fr) * 32 + fk];
#pragma unroll
    for (int ni = 0; ni < 4; ++ni)
      bv[ni] = *(const bf16x8*)&lb[(wc * 64 + ni * 16 + fr) * 32 + fk];

    __builtin_amdgcn_s_setprio(1);
#pragma unroll
    for (int mi = 0; mi < 4; ++mi)
#pragma unroll
      for (int ni = 0; ni < 4; ++ni)
        acc[mi][ni] = __builtin_amdgcn_mfma_f32_16x16x32_bf16(av[mi], bv[ni], acc[mi][ni], 0, 0, 0);
    __builtin_amdgcn_s_setprio(0);

    bR = (bR + 1 == 3) ? 0 : bR + 1;
  }

  const int fq = lane >> 4;
  u16* tileT = (u16*)lds;                // [128 cols][130] when TRANST
  if (TRANST) __syncthreads();           // all waves done reading lds bufs

#pragma unroll
  for (int mi = 0; mi < 4; ++mi) {
#pragma unroll
    for (int ni = 0; ni < 4; ++ni) {
      int cl = wc * 64 + ni * 16 + fr;
      int col = bcol + cl;
      float bb = bias ? bias[col] : 0.f;
#pragma unroll
      for (int r = 0; r < 4; ++r) {
        int rl = wr * 64 + mi * 16 + fq * 4 + r;
        int row = brow + rl;
        float v = acc[mi][ni][r] * alpha + bb;
        if (RELU) v = fmaxf(v, 0.f);
        if (BF16OUT) {
          u16 bf = f2bf(v);
          Cb[(size_t)row * N + col] = bf;
          if (TRANST) tileT[cl * 130 + rl] = bf;
        } else if (BCAST16) {
          size_t b0o = ((size_t)row * 16) * (size_t)N + col;
#pragma unroll
          for (int l = 0; l < 16; ++l)
            __builtin_nontemporal_store(v, &Cf[b0o + (size_t)l * N]);
        } else {
          Cf[(size_t)row * N + col] = v;
        }
      }
    }
  }

  if (TRANST) {
    __syncthreads();
    int c2 = t >> 1, off = (t & 1) * 64;
    size_t base = (size_t)(bcol + c2) * ldt + brow + off;
#pragma unroll
    for (int j = 0; j < 8; ++j)
      *(bf16x8*)&Ct[base + j * 8] = *(const bf16x8*)&tileT[c2 * 130 + off + j * 8];
  }
}

// -- LayerNorm rows (D=768): sum 2 split-K partials, scale by 1/denom, LN -----
__global__ __launch_bounds__(256) void ln2_kernel(
    const float* __restrict__ X, long long ps, const float* __restrict__ dsum,
    const float* __restrict__ g, const float* __restrict__ b,
    u16* __restrict__ Y)
{
  __shared__ float red[4];
  int row = blockIdx.x, t = threadIdx.x;
  const float* x = X + (size_t)row * 768;
  const f32x4* dv = (const f32x4*)(dsum + (size_t)row * 16);
  f32x4 d4 = dv[0] + dv[1] + dv[2] + dv[3];
  float inv_d = 1.f / (d4.x + d4.y + d4.z + d4.w);

  float v0 = (x[t]       + x[ps + t])       * inv_d;
  float v1 = (x[t + 256] + x[ps + t + 256]) * inv_d;
  float v2 = (x[t + 512] + x[ps + t + 512]) * inv_d;

  float s = v0 + v1 + v2;
#pragma unroll
  for (int off = 32; off > 0; off >>= 1) s += __shfl_xor(s, off);
  if ((t & 63) == 0) red[t >> 6] = s;
  __syncthreads();
  float mu = (red[0] + red[1] + red[2] + red[3]) * (1.f / 768.f);
  __syncthreads();

  float d0 = v0 - mu, d1 = v1 - mu, d2 = v2 - mu;
  float q = d0 * d0 + d1 * d1 + d2 * d2;
#pragma unroll
  for (int off = 32; off > 0; off >>= 1) q += __shfl_xor(q, off);
  if ((t & 63) == 0) red[t >> 6] = q;
  __syncthreads();
  float var = (red[0] + red[1] + red[2] + red[3]) * (1.f / 768.f);
  float inv = rsqrtf(var + 1e-5f);

  u16* y = Y + (size_t)row * 768;
  y[t]       = f2bf(d0 * inv * g[t]       + b[t]);
  y[t + 256] = f2bf(d1 * inv * g[t + 256] + b[t + 256]);
  y[t + 512] = f2bf(d2 * inv * g[t + 512] + b[t + 512]);
}

extern "C" void kernel_launch(void* const* d_in, const int* in_sizes, int n_in,
                              void* d_out, int out_size, void* d_ws, size_t ws_size,
                              hipStream_t stream)
{
  const float* vision = (const float*)d_in[0];
  const float* text   = (const float*)d_in[1];
  const float* fc_w   = (const float*)d_in[2];
  const float* fc_b   = (const float*)d_in[3];
  const float* ln_g   = (const float*)d_in[4];
  const float* ln_b   = (const float*)d_in[5];
  const float* w1     = (const float*)d_in[6];
  const float* b1     = (const float*)d_in[7];
  const float* w2     = (const float*)d_in[8];
  const float* b2     = (const float*)d_in[9];
  float* out = (float*)d_out;

  const int N = 4096, M = 4096, Din = 512, D = 768, Dhp = 256;

  char* p = (char*)d_ws;
  auto alloc = [&](size_t bytes) { char* r = p; p += (bytes + 255) & ~(size_t)255; return r; };
  u16*   mean_v = (u16*)alloc((size_t)N * D * 2);
  u16*   mean_t = (u16*)alloc((size_t)M * Din * 2);
  u16*   fcw_bf = (u16*)alloc((size_t)D * Din * 2);
  u16*   w1p    = (u16*)alloc((size_t)Dhp * D * 2);
  u16*   w2p    = (u16*)alloc((size_t)D * Dhp * 2);
  float* b1p    = (float*)alloc((size_t)Dhp * 4);
  float* dsum   = (float*)alloc((size_t)N * 16 * 4);
  u16*   t_bf   = (u16*)alloc((size_t)M * D * 2);
  u16*   tT_bf  = (u16*)alloc((size_t)D * M * 2);
  u16*   aff    = (u16*)alloc((size_t)N * M * 2);   // exp(scores), unnormalized
  u16*   ln_o   = (u16*)alloc((size_t)N * D * 2);
  u16*   h1     = (u16*)alloc((size_t)N * Dhp * 2);
  float* aggp   = (float*)alloc((size_t)2 * N * D * 4);  // 2 split-K partials

  // 1. fused prologue: means + weight casts/pads
  {
    int total = 4096 * 192 + 4096 * 128 + 768 * 512 + 256 * 768 + 768 * 256 + 256;
    prologue_kernel<<<(total + 255) / 256, 256, 0, stream>>>(
        vision, text, fc_w, w1, w2, b1, mean_v, mean_t, fcw_bf, w1p, w2p, b1p);
  }

  // 2. t = mean_t @ fc_w^T + fc_b  [M, D] bf16 + fused transpose tT [D, M]
  gemm_nt<false, true, true, false><<<dim3(D / 128, M / 128), 256, 0, stream>>>(
      mean_t, fcw_bf, fc_b, 1.f, nullptr, t_bf, tT_bf, M, M, D, Din, Din, Din, 0, 0);

  // 3. aff = exp(mean_v @ t^T / sqrt(D))  [N, M] bf16 + fused row-sum partials
  gemm256_exp_bf16<<<dim3(M / 256, N / 256), 512, 0, stream>>>(
      mean_v, t_bf, 1.f / sqrtf(768.f), aff, dsum, M, D, D, D);

  // 4. agg~ = aff @ t  [N, D] fp32, split-K=2 partials (B = tT, NT form)
  gemm_nt<false, false, false, false><<<dim3(D / 128, N / 128, 2), 256, 0, stream>>>(
      aff, tT_bf, nullptr, 1.f, aggp, nullptr, nullptr, 0, N, D, M / 2, M, M,
      M / 2, (long long)N * D);

  // 5. LayerNorm of (partial-sum / denom) -> bf16
  ln2_kernel<<<N, 256, 0, stream>>>(aggp, (long long)N * D, dsum, ln_g, ln_b, ln_o);

  // 6. h1 = relu(ln @ w1^T + b1)   [N, Dhp] bf16  (padded 192->256)
  gemm_nt<true, true, false, false><<<dim3(Dhp / 128, N / 128), 256, 0, stream>>>(
      ln_o, w1p, b1p, 1.f, nullptr, h1, nullptr, 0, N, Dhp, D, D, D, 0, 0);

  // 7. h2 = h1 @ w2^T + b2, broadcast-stored (non-temporal) to out[N][16][D]
  gemm_nt<false, false, false, true><<<dim3(D / 128, N / 128), 256, 0, stream>>>(
      h1, w2p, b2, 1.f, out, nullptr, nullptr, 0, N, D, Dhp, Dhp, Dhp, 0, 0);
}

// Round 10
// 319.979 us; speedup vs baseline: 1.4524x; 1.0357x over previous
//
#include <hip/hip_runtime.h>
#include <math.h>

typedef unsigned short u16;
typedef __attribute__((ext_vector_type(4))) float f32x4;
typedef __attribute__((ext_vector_type(8))) short bf16x8;

#define GLOBAL_AS __attribute__((address_space(1)))
#define LDS_AS __attribute__((address_space(3)))

__device__ __forceinline__ u16 f2bf(float f) {
  unsigned u = __builtin_bit_cast(unsigned, f);
  unsigned lsb = (u >> 16) & 1u;
  u += 0x7fffu + lsb;            // round-to-nearest-even
  return (u16)(u >> 16);
}

__device__ __forceinline__ float bf2f(u16 b) {
  return __builtin_bit_cast(float, ((unsigned)b) << 16);
}

__device__ __forceinline__ void gload16(const void* g, void* l) {
  __builtin_amdgcn_global_load_lds((const GLOBAL_AS void*)g, (LDS_AS void*)l, 16, 0, 0);
}

// ---- fused prologue: mean_v, mean_t, cast fc_w, pad-cast w1,w2, pad b1 ------
__global__ __launch_bounds__(256) void prologue_kernel(
    const float* __restrict__ vision, const float* __restrict__ text,
    const float* __restrict__ fc_w, const float* __restrict__ w1,
    const float* __restrict__ w2, const float* __restrict__ b1,
    u16* __restrict__ mean_v, u16* __restrict__ mean_t,
    u16* __restrict__ fcw_bf, u16* __restrict__ w1p, u16* __restrict__ w2p,
    float* __restrict__ b1p)
{
  const int n_mv = 4096 * 192;   // N * D/4
  const int n_mt = 4096 * 128;   // M * Din/4
  const int n_fcw = 768 * 512;
  const int n_w1 = 256 * 768;
  const int n_w2 = 768 * 256;
  int id = blockIdx.x * 256 + threadIdx.x;

  if (id < n_mv) {               // mean over Lv=16 of vision[N][16][768]
    int n = id / 192, c = id % 192;
    const f32x4* x = (const f32x4*)vision + (size_t)n * 16 * 192 + c;
    f32x4 s = {0.f, 0.f, 0.f, 0.f};
#pragma unroll
    for (int l = 0; l < 16; ++l) s += __builtin_nontemporal_load(&x[(size_t)l * 192]);
    s *= (1.f / 16.f);
    ushort4 o; o.x = f2bf(s.x); o.y = f2bf(s.y); o.z = f2bf(s.z); o.w = f2bf(s.w);
    ((ushort4*)mean_v)[id] = o;
    return;
  }
  id -= n_mv;
  if (id < n_mt) {               // mean over Lt=77 of text[M][77][512]
    int n = id / 128, c = id % 128;
    const f32x4* x = (const f32x4*)text + (size_t)n * 77 * 128 + c;
    f32x4 s = {0.f, 0.f, 0.f, 0.f};
#pragma unroll 11
    for (int l = 0; l < 77; ++l) s += __builtin_nontemporal_load(&x[(size_t)l * 128]);
    s *= (1.f / 77.f);
    ushort4 o; o.x = f2bf(s.x); o.y = f2bf(s.y); o.z = f2bf(s.z); o.w = f2bf(s.w);
    ((ushort4*)mean_t)[id] = o;
    return;
  }
  id -= n_mt;
  if (id < n_fcw) { fcw_bf[id] = f2bf(fc_w[id]); return; }
  id -= n_fcw;
  if (id < n_w1) {
    int r = id / 768;
    w1p[id] = (r < 192) ? f2bf(w1[id]) : (u16)0;
    return;
  }
  id -= n_w1;
  if (id < n_w2) {
    int r = id / 256, c = id % 256;
    w2p[id] = (c < 192) ? f2bf(w2[(size_t)r * 192 + c]) : (u16)0;
    return;
  }
  id -= n_w2;
  if (id < 256) b1p[id] = (id < 192) ? b1[id] : 0.f;
}

// ------- 256x256 deep-pipelined NT bf16 GEMM, C bf16 = exp(alpha * A@B^T) ---
// BK=32, 3 LDS buffers, stage-2-ahead, counted vmcnt, 1 raw barrier per iter.
// XCD-swizzled blockIdx. C written via LDS-staged 256x128 stripes. Row
// exp-sums -> dsum[row][gridx] fp32 partials (deterministic, no atomics).
__global__ __launch_bounds__(512, 2) void gemm256_exp_bf16(
    const u16* __restrict__ A, const u16* __restrict__ B, float alpha,
    u16* __restrict__ C, float* __restrict__ dsum, int N, int K, int lda, int ldb)
{
  __shared__ char lds[98304];          // A bufs 0..48K, B bufs 48K..96K
  const int tid = threadIdx.x;
  const int w = tid >> 6, lane = tid & 63;

  // XCD-aware bijective swizzle
  const int gx = gridDim.x;
  const int nb = gx * gridDim.y;
  int b0 = blockIdx.y * gx + blockIdx.x;
  int swz = (b0 & 7) * (nb >> 3) + (b0 >> 3);
  const int bx = swz % gx, by = swz / gx;
  const int brow = by * 256, bcol = bx * 256;
  const int wr = w >> 2, wc = w & 3;   // 2M x 4N wave grid

  f32x4 acc[8][4];
#pragma unroll
  for (int i = 0; i < 8; ++i)
#pragma unroll
    for (int j = 0; j < 4; ++j) acc[i][j] = (f32x4){0.f, 0.f, 0.f, 0.f};

  const int srow = lane >> 2;          // 0..15
  const int scol = (lane & 3) * 8;     // 0,8,16,24
  const size_t ga0 = (size_t)(brow + (w * 2 + 0) * 16 + srow) * lda + scol;
  const size_t ga1 = (size_t)(brow + (w * 2 + 1) * 16 + srow) * lda + scol;
  const size_t gb0 = (size_t)(bcol + (w * 2 + 0) * 16 + srow) * ldb + scol;
  const size_t gb1 = (size_t)(bcol + (w * 2 + 1) * 16 + srow) * ldb + scol;

  const int fr = lane & 15, fk = (lane >> 4) * 8;
  const int NT = K >> 5;

  auto stage = [&](int ti, int b) {
    const int k0 = ti << 5;
    char* la = lds + b * 16384 + w * 2048;
    char* lb = lds + 49152 + b * 16384 + w * 2048;
    gload16(A + ga0 + k0, la);
    gload16(A + ga1 + k0, la + 1024);
    gload16(B + gb0 + k0, lb);
    gload16(B + gb1 + k0, lb + 1024);
  };

  stage(0, 0);
  stage(1, 1);

  int bR = 0;
  for (int it = 0; it < NT; ++it) {
    if (it + 1 < NT) { asm volatile("s_waitcnt vmcnt(4)" ::: "memory"); }
    else             { asm volatile("s_waitcnt vmcnt(0)" ::: "memory"); }
    __builtin_amdgcn_s_barrier();
    asm volatile("" ::: "memory");

    int bW = bR + 2; if (bW >= 3) bW -= 3;
    if (it + 2 < NT) stage(it + 2, bW);

    const u16* la = (const u16*)(lds + bR * 16384);
    const u16* lb = (const u16*)(lds + 49152 + bR * 16384);
    bf16x8 av[8], bv[4];
#pragma unroll
    for (int mi = 0; mi < 8; ++mi)
      av[mi] = *(const bf16x8*)&la[(wr * 128 + mi * 16 + fr) * 32 + fk];
#pragma unroll
    for (int ni = 0; ni < 4; ++ni)
      bv[ni] = *(const bf16x8*)&lb[(wc * 64 + ni * 16 + fr) * 32 + fk];

    __builtin_amdgcn_s_setprio(1);
#pragma unroll
    for (int mi = 0; mi < 8; ++mi)
#pragma unroll
      for (int ni = 0; ni < 4; ++ni)
        acc[mi][ni] = __builtin_amdgcn_mfma_f32_16x16x32_bf16(av[mi], bv[ni], acc[mi][ni], 0, 0, 0);
    __builtin_amdgcn_s_setprio(0);

    bR = (bR + 1 == 3) ? 0 : bR + 1;
  }

  const int fq = lane >> 4;
  __syncthreads();                     // retire all main-loop LDS reads

  // exp in place + per-row partial sums (over this wave's 64-col slice)
  float rsum[8][4];
#pragma unroll
  for (int mi = 0; mi < 8; ++mi) {
#pragma unroll
    for (int r = 0; r < 4; ++r) rsum[mi][r] = 0.f;
#pragma unroll
    for (int ni = 0; ni < 4; ++ni)
#pragma unroll
      for (int r = 0; r < 4; ++r) {
        float v = __expf(acc[mi][ni][r] * alpha);
        acc[mi][ni][r] = v;
        rsum[mi][r] += v;
      }
  }
#pragma unroll
  for (int mi = 0; mi < 8; ++mi)
#pragma unroll
    for (int r = 0; r < 4; ++r) {
      float s = rsum[mi][r];
      s += __shfl_xor(s, 1); s += __shfl_xor(s, 2);
      s += __shfl_xor(s, 4); s += __shfl_xor(s, 8);
      rsum[mi][r] = s;
    }
  float* wsum = (float*)(lds + 73728);   // [4 wc][256 rows], disjoint from tile
  if (fr == 0) {
#pragma unroll
    for (int mi = 0; mi < 8; ++mi)
#pragma unroll
      for (int r = 0; r < 4; ++r)
        wsum[wc * 256 + wr * 128 + mi * 16 + fq * 4 + r] = rsum[mi][r];
  }

  // C-write via two 256x128 LDS stripes (coalesced 256B rows)
  u16* tile = (u16*)lds;                 // [256][136] u16 = 68KB
#pragma unroll
  for (int s = 0; s < 2; ++s) {
    if ((wc >> 1) == s) {
#pragma unroll
      for (int mi = 0; mi < 8; ++mi)
#pragma unroll
        for (int ni = 0; ni < 4; ++ni) {
          int cc = (wc & 1) * 64 + ni * 16 + fr;
#pragma unroll
          for (int r = 0; r < 4; ++r) {
            int rr = wr * 128 + mi * 16 + fq * 4 + r;
            tile[rr * 136 + cc] = f2bf(acc[mi][ni][r]);
          }
        }
    }
    __syncthreads();                     // tile written (also fences wsum)
    {
      int row = tid >> 1, part = tid & 1;
      size_t base = (size_t)(brow + row) * N + bcol + s * 128 + part * 64;
      const u16* tr = &tile[row * 136 + part * 64];
#pragma unroll
      for (int j = 0; j < 8; ++j)
        *(bf16x8*)&C[base + j * 8] = *(const bf16x8*)&tr[j * 8];
    }
    __syncthreads();                     // stores done before tile reuse
  }

  if (tid < 256) {
    float s = wsum[tid] + wsum[256 + tid] + wsum[512 + tid] + wsum[768 + tid];
    dsum[(size_t)(brow + tid) * 16 + bx] = s;
  }
}

// ---------------- NT bf16 MFMA GEMM: C[M,N] = alpha*A[M,K]@B[N,K]^T + bias ----
// 128x128 tile, BK=32, 3 LDS buffers, stage-2-ahead, counted vmcnt,
// XCD-swizzled blockIdx (total grid %8==0 required).
// TRANST: additionally write C^T (bf16) via LDS-transposed coalesced stores.
// blockIdx.z = split-K slice: A/B advance by kofs elements, Cf by cofs.
template<bool RELU, bool BF16OUT, bool TRANST>
__global__ __launch_bounds__(256, 3) void gemm_nt(
    const u16* __restrict__ A, const u16* __restrict__ B,
    const float* __restrict__ bias, float alpha,
    float* __restrict__ Cf, u16* __restrict__ Cb,
    u16* __restrict__ Ct, int ldt,
    int M, int N, int K, int lda, int ldb,
    int kofs, long long cofs)
{
  __shared__ char lds[49152];            // 3 bufs x (A 8KB + B 8KB)
  const int t = threadIdx.x;
  const int w = t >> 6, lane = t & 63;

  // XCD-aware bijective swizzle over the flattened grid
  const int gx = gridDim.x, gy = gridDim.y;
  const int nb = gx * gy * gridDim.z;
  int b0 = (blockIdx.z * gy + blockIdx.y) * gx + blockIdx.x;
  int swz = (b0 & 7) * (nb >> 3) + (b0 >> 3);
  const int bx = swz % gx;
  int tmp = swz / gx;
  const int by = tmp % gy, kz = tmp / gy;

  const int brow = by * 128, bcol = bx * 128;
  const int wr = w >> 1, wc = w & 1;     // wave sub-tile 64x64

  A += (size_t)kz * kofs;
  B += (size_t)kz * kofs;
  Cf += kz * cofs;

  f32x4 acc[4][4];
#pragma unroll
  for (int i = 0; i < 4; ++i)
#pragma unroll
    for (int j = 0; j < 4; ++j) acc[i][j] = (f32x4){0.f, 0.f, 0.f, 0.f};

  const int srow = t >> 2;               // 0..63
  const int scol = (t & 3) * 8;
  const size_t aoff0 = (size_t)(brow + srow) * lda + scol;
  const size_t boff0 = (size_t)(bcol + srow) * ldb + scol;
  const size_t aoff1 = aoff0 + (size_t)64 * lda;
  const size_t boff1 = boff0 + (size_t)64 * ldb;

  const int fr = lane & 15, fk = (lane >> 4) * 8;
  const int NT = K >> 5;

  auto stage = [&](int ti, int b) {
    const int k0 = ti << 5;
    char* la = lds + b * 16384 + w * 1024;
    char* lb = lds + b * 16384 + 8192 + w * 1024;
    gload16(A + aoff0 + k0, la);
    gload16(A + aoff1 + k0, la + 4096);
    gload16(B + boff0 + k0, lb);
    gload16(B + boff1 + k0, lb + 4096);
  };

  stage(0, 0);
  stage(1, 1);

  int bR = 0;
  for (int it = 0; it < NT; ++it) {
    if (it + 1 < NT) { asm volatile("s_waitcnt vmcnt(4)" ::: "memory"); }
    else             { asm volatile("s_waitcnt vmcnt(0)" ::: "memory"); }
    __builtin_amdgcn_s_barrier();
    asm volatile("" ::: "memory");

    int bW = bR + 2; if (bW >= 3) bW -= 3;
    if (it + 2 < NT) stage(it + 2, bW);

    const u16* la = (const u16*)(lds + bR * 16384);
    const u16* lb = (const u16*)(lds + bR * 16384 + 8192);
    bf16x8 av[4], bv[4];
#pragma unroll
    for (int mi = 0; mi < 4; ++mi)
      av[mi] = *(const bf16x8*)&la[(wr * 64 + mi * 16 + fr) * 32 + fk];
#pragma unroll
    for (int ni = 0; ni < 4; ++ni)
      bv[ni] = *(const bf16x8*)&lb[(wc * 64 + ni * 16 + fr) * 32 + fk];

    __builtin_amdgcn_s_setprio(1);
#pragma unroll
    for (int mi = 0; mi < 4; ++mi)
#pragma unroll
      for (int ni = 0; ni < 4; ++ni)
        acc[mi][ni] = __builtin_amdgcn_mfma_f32_16x16x32_bf16(av[mi], bv[ni], acc[mi][ni], 0, 0, 0);
    __builtin_amdgcn_s_setprio(0);

    bR = (bR + 1 == 3) ? 0 : bR + 1;
  }

  const int fq = lane >> 4;
  u16* tileT = (u16*)lds;                // [128 cols][130] when TRANST
  if (TRANST) __syncthreads();           // all waves done reading lds bufs

#pragma unroll
  for (int mi = 0; mi < 4; ++mi) {
#pragma unroll
    for (int ni = 0; ni < 4; ++ni) {
      int cl = wc * 64 + ni * 16 + fr;
      int col = bcol + cl;
      float bb = bias ? bias[col] : 0.f;
#pragma unroll
      for (int r = 0; r < 4; ++r) {
        int rl = wr * 64 + mi * 16 + fq * 4 + r;
        int row = brow + rl;
        float v = acc[mi][ni][r] * alpha + bb;
        if (RELU) v = fmaxf(v, 0.f);
        if (BF16OUT) {
          u16 bf = f2bf(v);
          Cb[(size_t)row * N + col] = bf;
          if (TRANST) tileT[cl * 130 + rl] = bf;
        } else {
          Cf[(size_t)row * N + col] = v;
        }
      }
    }
  }

  if (TRANST) {
    __syncthreads();
    int c2 = t >> 1, off = (t & 1) * 64;
    size_t base = (size_t)(bcol + c2) * ldt + brow + off;
#pragma unroll
    for (int j = 0; j < 8; ++j)
      *(bf16x8*)&Ct[base + j * 8] = *(const bf16x8*)&tileT[c2 * 130 + off + j * 8];
  }
}

// -- LayerNorm rows (D=768): sum 2 split-K partials, scale by 1/denom, LN -----
__global__ __launch_bounds__(256) void ln2_kernel(
    const float* __restrict__ X, long long ps, const float* __restrict__ dsum,
    const float* __restrict__ g, const float* __restrict__ b,
    u16* __restrict__ Y)
{
  __shared__ float red[4];
  int row = blockIdx.x, t = threadIdx.x;
  const float* x = X + (size_t)row * 768;
  const f32x4* dv = (const f32x4*)(dsum + (size_t)row * 16);
  f32x4 d4 = dv[0] + dv[1] + dv[2] + dv[3];
  float inv_d = 1.f / (d4.x + d4.y + d4.z + d4.w);

  float v0 = (x[t]       + x[ps + t])       * inv_d;
  float v1 = (x[t + 256] + x[ps + t + 256]) * inv_d;
  float v2 = (x[t + 512] + x[ps + t + 512]) * inv_d;

  float s = v0 + v1 + v2;
#pragma unroll
  for (int off = 32; off > 0; off >>= 1) s += __shfl_xor(s, off);
  if ((t & 63) == 0) red[t >> 6] = s;
  __syncthreads();
  float mu = (red[0] + red[1] + red[2] + red[3]) * (1.f / 768.f);
  __syncthreads();

  float d0 = v0 - mu, d1 = v1 - mu, d2 = v2 - mu;
  float q = d0 * d0 + d1 * d1 + d2 * d2;
#pragma unroll
  for (int off = 32; off > 0; off >>= 1) q += __shfl_xor(q, off);
  if ((t & 63) == 0) red[t >> 6] = q;
  __syncthreads();
  float var = (red[0] + red[1] + red[2] + red[3]) * (1.f / 768.f);
  float inv = rsqrtf(var + 1e-5f);

  u16* y = Y + (size_t)row * 768;
  y[t]       = f2bf(d0 * inv * g[t]       + b[t]);
  y[t + 256] = f2bf(d1 * inv * g[t + 256] + b[t + 256]);
  y[t + 512] = f2bf(d2 * inv * g[t + 512] + b[t + 512]);
}

// -- broadcast rows: H[N][768] fp32 -> out[N][16][768], f32x4 NT stores -------
__global__ __launch_bounds__(256) void bcast_kernel(
    const f32x4* __restrict__ H, f32x4* __restrict__ O, int total)
{
  int id = blockIdx.x * 256 + threadIdx.x;
  if (id >= total) return;
  int n = id / (16 * 192);
  int c = id % 192;
  f32x4 v = H[(size_t)n * 192 + c];
  __builtin_nontemporal_store(v, &O[id]);
}

extern "C" void kernel_launch(void* const* d_in, const int* in_sizes, int n_in,
                              void* d_out, int out_size, void* d_ws, size_t ws_size,
                              hipStream_t stream)
{
  const float* vision = (const float*)d_in[0];
  const float* text   = (const float*)d_in[1];
  const float* fc_w   = (const float*)d_in[2];
  const float* fc_b   = (const float*)d_in[3];
  const float* ln_g   = (const float*)d_in[4];
  const float* ln_b   = (const float*)d_in[5];
  const float* w1     = (const float*)d_in[6];
  const float* b1     = (const float*)d_in[7];
  const float* w2     = (const float*)d_in[8];
  const float* b2     = (const float*)d_in[9];
  float* out = (float*)d_out;

  const int N = 4096, M = 4096, Din = 512, D = 768, Dhp = 256;

  char* p = (char*)d_ws;
  auto alloc = [&](size_t bytes) { char* r = p; p += (bytes + 255) & ~(size_t)255; return r; };
  u16*   mean_v = (u16*)alloc((size_t)N * D * 2);
  u16*   mean_t = (u16*)alloc((size_t)M * Din * 2);
  u16*   fcw_bf = (u16*)alloc((size_t)D * Din * 2);
  u16*   w1p    = (u16*)alloc((size_t)Dhp * D * 2);
  u16*   w2p    = (u16*)alloc((size_t)D * Dhp * 2);
  float* b1p    = (float*)alloc((size_t)Dhp * 4);
  float* dsum   = (float*)alloc((size_t)N * 16 * 4);
  u16*   t_bf   = (u16*)alloc((size_t)M * D * 2);
  u16*   tT_bf  = (u16*)alloc((size_t)D * M * 2);
  u16*   aff    = (u16*)alloc((size_t)N * M * 2);   // exp(scores), unnormalized
  u16*   ln_o   = (u16*)alloc((size_t)N * D * 2);
  u16*   h1     = (u16*)alloc((size_t)N * Dhp * 2);
  float* aggp   = (float*)alloc((size_t)2 * N * D * 4);  // 2 split-K partials
  float* h2     = (float*)aff;   // aff dead after agg; 12.6MB <= 33.5MB

  // 1. fused prologue: means + weight casts/pads
  {
    int total = 4096 * 192 + 4096 * 128 + 768 * 512 + 256 * 768 + 768 * 256 + 256;
    prologue_kernel<<<(total + 255) / 256, 256, 0, stream>>>(
        vision, text, fc_w, w1, w2, b1, mean_v, mean_t, fcw_bf, w1p, w2p, b1p);
  }

  // 2. t = mean_t @ fc_w^T + fc_b  [M, D] bf16 + fused transpose tT [D, M]
  gemm_nt<false, true, true><<<dim3(D / 128, M / 128), 256, 0, stream>>>(
      mean_t, fcw_bf, fc_b, 1.f, nullptr, t_bf, tT_bf, M, M, D, Din, Din, Din, 0, 0);

  // 3. aff = exp(mean_v @ t^T / sqrt(D))  [N, M] bf16 + fused row-sum partials
  gemm256_exp_bf16<<<dim3(M / 256, N / 256), 512, 0, stream>>>(
      mean_v, t_bf, 1.f / sqrtf(768.f), aff, dsum, M, D, D, D);

  // 4. agg~ = aff @ t  [N, D] fp32, split-K=2 partials (B = tT, NT form)
  gemm_nt<false, false, false><<<dim3(D / 128, N / 128, 2), 256, 0, stream>>>(
      aff, tT_bf, nullptr, 1.f, aggp, nullptr, nullptr, 0, N, D, M / 2, M, M,
      M / 2, (long long)N * D);

  // 5. LayerNorm of (partial-sum / denom) -> bf16
  ln2_kernel<<<N, 256, 0, stream>>>(aggp, (long long)N * D, dsum, ln_g, ln_b, ln_o);

  // 6. h1 = relu(ln @ w1^T + b1)   [N, Dhp] bf16  (padded 192->256)
  gemm_nt<true, true, false><<<dim3(Dhp / 128, N / 128), 256, 0, stream>>>(
      ln_o, w1p, b1p, 1.f, nullptr, h1, nullptr, 0, N, Dhp, D, D, D, 0, 0);

  // 7. h2 = h1 @ w2^T + b2   [N, D] fp32 compact (L3-resident)
  gemm_nt<false, false, false><<<dim3(D / 128, N / 128), 256, 0, stream>>>(
      h1, w2p, b2, 1.f, h2, nullptr, nullptr, 0, N, D, Dhp, Dhp, Dhp, 0, 0);

  // 8. broadcast to out[N][16][768] with fully-coalesced f32x4 NT stores
  {
    int total4 = N * 16 * (D / 4);
    bcast_kernel<<<(total4 + 255) / 256, 256, 0, stream>>>(
        (const f32x4*)h2, (f32x4*)out, total4);
  }
}

// Round 11
// 310.055 us; speedup vs baseline: 1.4988x; 1.0320x over previous
//
#include <hip/hip_runtime.h>
#include <math.h>

typedef unsigned short u16;
typedef __attribute__((ext_vector_type(4))) float f32x4;
typedef __attribute__((ext_vector_type(8))) short bf16x8;

#define GLOBAL_AS __attribute__((address_space(1)))
#define LDS_AS __attribute__((address_space(3)))

__device__ __forceinline__ u16 f2bf(float f) {
  unsigned u = __builtin_bit_cast(unsigned, f);
  unsigned lsb = (u >> 16) & 1u;
  u += 0x7fffu + lsb;            // round-to-nearest-even
  return (u16)(u >> 16);
}

__device__ __forceinline__ float bf2f(u16 b) {
  return __builtin_bit_cast(float, ((unsigned)b) << 16);
}

__device__ __forceinline__ void gload16(const void* g, void* l) {
  __builtin_amdgcn_global_load_lds((const GLOBAL_AS void*)g, (LDS_AS void*)l, 16, 0, 0);
}

// ---- fused prologue: mean_v, mean_t, cast fc_w, pad-cast w1,w2, pad b1 ------
__global__ __launch_bounds__(256) void prologue_kernel(
    const float* __restrict__ vision, const float* __restrict__ text,
    const float* __restrict__ fc_w, const float* __restrict__ w1,
    const float* __restrict__ w2, const float* __restrict__ b1,
    u16* __restrict__ mean_v, u16* __restrict__ mean_t,
    u16* __restrict__ fcw_bf, u16* __restrict__ w1p, u16* __restrict__ w2p,
    float* __restrict__ b1p)
{
  const int n_mv = 4096 * 192;   // N * D/4
  const int n_mt = 4096 * 128;   // M * Din/4
  const int n_fcw = 768 * 512;
  const int n_w1 = 256 * 768;
  const int n_w2 = 768 * 256;
  int id = blockIdx.x * 256 + threadIdx.x;

  if (id < n_mv) {               // mean over Lv=16 of vision[N][16][768]
    int n = id / 192, c = id % 192;
    const f32x4* x = (const f32x4*)vision + (size_t)n * 16 * 192 + c;
    f32x4 s = {0.f, 0.f, 0.f, 0.f};
#pragma unroll
    for (int l = 0; l < 16; ++l) s += __builtin_nontemporal_load(&x[(size_t)l * 192]);
    s *= (1.f / 16.f);
    ushort4 o; o.x = f2bf(s.x); o.y = f2bf(s.y); o.z = f2bf(s.z); o.w = f2bf(s.w);
    ((ushort4*)mean_v)[id] = o;
    return;
  }
  id -= n_mv;
  if (id < n_mt) {               // mean over Lt=77 of text[M][77][512]
    int n = id / 128, c = id % 128;
    const f32x4* x = (const f32x4*)text + (size_t)n * 77 * 128 + c;
    f32x4 s = {0.f, 0.f, 0.f, 0.f};
#pragma unroll 11
    for (int l = 0; l < 77; ++l) s += __builtin_nontemporal_load(&x[(size_t)l * 128]);
    s *= (1.f / 77.f);
    ushort4 o; o.x = f2bf(s.x); o.y = f2bf(s.y); o.z = f2bf(s.z); o.w = f2bf(s.w);
    ((ushort4*)mean_t)[id] = o;
    return;
  }
  id -= n_mt;
  if (id < n_fcw) { fcw_bf[id] = f2bf(fc_w[id]); return; }
  id -= n_fcw;
  if (id < n_w1) {
    int r = id / 768;
    w1p[id] = (r < 192) ? f2bf(w1[id]) : (u16)0;
    return;
  }
  id -= n_w1;
  if (id < n_w2) {
    int r = id / 256, c = id % 256;
    w2p[id] = (c < 192) ? f2bf(w2[(size_t)r * 192 + c]) : (u16)0;
    return;
  }
  id -= n_w2;
  if (id < 256) b1p[id] = (id < 192) ? b1[id] : 0.f;
}

// ------- 256x256 deep-pipelined NT bf16 GEMM, C bf16 = exp(alpha * A@B^T) ---
// BK=32, 3 LDS buffers, stage-2-ahead, counted vmcnt, 1 raw barrier per iter.
// XCD-swizzled blockIdx. C written via LDS-staged 256x128 stripes. Row
// exp-sums -> dsum[row][gridx] fp32 partials (deterministic, no atomics).
__global__ __launch_bounds__(512, 2) void gemm256_exp_bf16(
    const u16* __restrict__ A, const u16* __restrict__ B, float alpha,
    u16* __restrict__ C, float* __restrict__ dsum, int N, int K, int lda, int ldb)
{
  __shared__ char lds[98304];          // A bufs 0..48K, B bufs 48K..96K
  const int tid = threadIdx.x;
  const int w = tid >> 6, lane = tid & 63;

  // XCD-aware bijective swizzle
  const int gx = gridDim.x;
  const int nb = gx * gridDim.y;
  int b0 = blockIdx.y * gx + blockIdx.x;
  int swz = (b0 & 7) * (nb >> 3) + (b0 >> 3);
  const int bx = swz % gx, by = swz / gx;
  const int brow = by * 256, bcol = bx * 256;
  const int wr = w >> 2, wc = w & 3;   // 2M x 4N wave grid

  f32x4 acc[8][4];
#pragma unroll
  for (int i = 0; i < 8; ++i)
#pragma unroll
    for (int j = 0; j < 4; ++j) acc[i][j] = (f32x4){0.f, 0.f, 0.f, 0.f};

  const int srow = lane >> 2;          // 0..15
  const int scol = (lane & 3) * 8;     // 0,8,16,24
  const size_t ga0 = (size_t)(brow + (w * 2 + 0) * 16 + srow) * lda + scol;
  const size_t ga1 = (size_t)(brow + (w * 2 + 1) * 16 + srow) * lda + scol;
  const size_t gb0 = (size_t)(bcol + (w * 2 + 0) * 16 + srow) * ldb + scol;
  const size_t gb1 = (size_t)(bcol + (w * 2 + 1) * 16 + srow) * ldb + scol;

  const int fr = lane & 15, fk = (lane >> 4) * 8;
  const int NT = K >> 5;

  auto stage = [&](int ti, int b) {
    const int k0 = ti << 5;
    char* la = lds + b * 16384 + w * 2048;
    char* lb = lds + 49152 + b * 16384 + w * 2048;
    gload16(A + ga0 + k0, la);
    gload16(A + ga1 + k0, la + 1024);
    gload16(B + gb0 + k0, lb);
    gload16(B + gb1 + k0, lb + 1024);
  };

  stage(0, 0);
  stage(1, 1);

  int bR = 0;
  for (int it = 0; it < NT; ++it) {
    if (it + 1 < NT) { asm volatile("s_waitcnt vmcnt(4)" ::: "memory"); }
    else             { asm volatile("s_waitcnt vmcnt(0)" ::: "memory"); }
    __builtin_amdgcn_s_barrier();
    asm volatile("" ::: "memory");

    int bW = bR + 2; if (bW >= 3) bW -= 3;
    if (it + 2 < NT) stage(it + 2, bW);

    const u16* la = (const u16*)(lds + bR * 16384);
    const u16* lb = (const u16*)(lds + 49152 + bR * 16384);
    bf16x8 av[8], bv[4];
#pragma unroll
    for (int mi = 0; mi < 8; ++mi)
      av[mi] = *(const bf16x8*)&la[(wr * 128 + mi * 16 + fr) * 32 + fk];
#pragma unroll
    for (int ni = 0; ni < 4; ++ni)
      bv[ni] = *(const bf16x8*)&lb[(wc * 64 + ni * 16 + fr) * 32 + fk];

    __builtin_amdgcn_s_setprio(1);
#pragma unroll
    for (int mi = 0; mi < 8; ++mi)
#pragma unroll
      for (int ni = 0; ni < 4; ++ni)
        acc[mi][ni] = __builtin_amdgcn_mfma_f32_16x16x32_bf16(av[mi], bv[ni], acc[mi][ni], 0, 0, 0);
    __builtin_amdgcn_s_setprio(0);

    bR = (bR + 1 == 3) ? 0 : bR + 1;
  }

  const int fq = lane >> 4;
  __syncthreads();                     // retire all main-loop LDS reads

  // exp in place + per-row partial sums (over this wave's 64-col slice)
  float rsum[8][4];
#pragma unroll
  for (int mi = 0; mi < 8; ++mi) {
#pragma unroll
    for (int r = 0; r < 4; ++r) rsum[mi][r] = 0.f;
#pragma unroll
    for (int ni = 0; ni < 4; ++ni)
#pragma unroll
      for (int r = 0; r < 4; ++r) {
        float v = __expf(acc[mi][ni][r] * alpha);
        acc[mi][ni][r] = v;
        rsum[mi][r] += v;
      }
  }
#pragma unroll
  for (int mi = 0; mi < 8; ++mi)
#pragma unroll
    for (int r = 0; r < 4; ++r) {
      float s = rsum[mi][r];
      s += __shfl_xor(s, 1); s += __shfl_xor(s, 2);
      s += __shfl_xor(s, 4); s += __shfl_xor(s, 8);
      rsum[mi][r] = s;
    }
  float* wsum = (float*)(lds + 73728);   // [4 wc][256 rows], disjoint from tile
  if (fr == 0) {
#pragma unroll
    for (int mi = 0; mi < 8; ++mi)
#pragma unroll
      for (int r = 0; r < 4; ++r)
        wsum[wc * 256 + wr * 128 + mi * 16 + fq * 4 + r] = rsum[mi][r];
  }

  // C-write via two 256x128 LDS stripes (coalesced 256B rows)
  u16* tile = (u16*)lds;                 // [256][136] u16 = 68KB
#pragma unroll
  for (int s = 0; s < 2; ++s) {
    if ((wc >> 1) == s) {
#pragma unroll
      for (int mi = 0; mi < 8; ++mi)
#pragma unroll
        for (int ni = 0; ni < 4; ++ni) {
          int cc = (wc & 1) * 64 + ni * 16 + fr;
#pragma unroll
          for (int r = 0; r < 4; ++r) {
            int rr = wr * 128 + mi * 16 + fq * 4 + r;
            tile[rr * 136 + cc] = f2bf(acc[mi][ni][r]);
          }
        }
    }
    __syncthreads();                     // tile written (also fences wsum)
    {
      int row = tid >> 1, part = tid & 1;
      size_t base = (size_t)(brow + row) * N + bcol + s * 128 + part * 64;
      const u16* tr = &tile[row * 136 + part * 64];
#pragma unroll
      for (int j = 0; j < 8; ++j)
        *(bf16x8*)&C[base + j * 8] = *(const bf16x8*)&tr[j * 8];
    }
    __syncthreads();                     // stores done before tile reuse
  }

  if (tid < 256) {
    float s = wsum[tid] + wsum[256 + tid] + wsum[512 + tid] + wsum[768 + tid];
    dsum[(size_t)(brow + tid) * 16 + bx] = s;
  }
}

// ---------------- NT bf16 MFMA GEMM: C[M,N] = alpha*A[M,K]@B[N,K]^T + bias ----
// 128x128 tile, BK=32, 3 LDS buffers, stage-2-ahead, counted vmcnt,
// XCD-swizzled blockIdx (total grid %8==0 required).
// TRANST: additionally write C^T (bf16) via LDS-transposed coalesced stores.
// BCAST16: write each C value to 16 row-copies of out[N][16][768] via
//   LDS-staged 64-row stripes + fully-coalesced f32x4 NT stores.
// blockIdx.z = split-K slice: A/B advance by kofs elements, Cf by cofs.
template<bool RELU, bool BF16OUT, bool TRANST, bool BCAST16>
__global__ __launch_bounds__(256, 3) void gemm_nt(
    const u16* __restrict__ A, const u16* __restrict__ B,
    const float* __restrict__ bias, float alpha,
    float* __restrict__ Cf, u16* __restrict__ Cb,
    u16* __restrict__ Ct, int ldt,
    int M, int N, int K, int lda, int ldb,
    int kofs, long long cofs)
{
  __shared__ char lds[49152];            // 3 bufs x (A 8KB + B 8KB)
  const int t = threadIdx.x;
  const int w = t >> 6, lane = t & 63;

  // XCD-aware bijective swizzle over the flattened grid
  const int gx = gridDim.x, gy = gridDim.y;
  const int nb = gx * gy * gridDim.z;
  int b0 = (blockIdx.z * gy + blockIdx.y) * gx + blockIdx.x;
  int swz = (b0 & 7) * (nb >> 3) + (b0 >> 3);
  const int bx = swz % gx;
  int tmp = swz / gx;
  const int by = tmp % gy, kz = tmp / gy;

  const int brow = by * 128, bcol = bx * 128;
  const int wr = w >> 1, wc = w & 1;     // wave sub-tile 64x64

  A += (size_t)kz * kofs;
  B += (size_t)kz * kofs;
  Cf += kz * cofs;

  f32x4 acc[4][4];
#pragma unroll
  for (int i = 0; i < 4; ++i)
#pragma unroll
    for (int j = 0; j < 4; ++j) acc[i][j] = (f32x4){0.f, 0.f, 0.f, 0.f};

  const int srow = t >> 2;               // 0..63
  const int scol = (t & 3) * 8;
  const size_t aoff0 = (size_t)(brow + srow) * lda + scol;
  const size_t boff0 = (size_t)(bcol + srow) * ldb + scol;
  const size_t aoff1 = aoff0 + (size_t)64 * lda;
  const size_t boff1 = boff0 + (size_t)64 * ldb;

  const int fr = lane & 15, fk = (lane >> 4) * 8;
  const int NT = K >> 5;

  auto stage = [&](int ti, int b) {
    const int k0 = ti << 5;
    char* la = lds + b * 16384 + w * 1024;
    char* lb = lds + b * 16384 + 8192 + w * 1024;
    gload16(A + aoff0 + k0, la);
    gload16(A + aoff1 + k0, la + 4096);
    gload16(B + boff0 + k0, lb);
    gload16(B + boff1 + k0, lb + 4096);
  };

  stage(0, 0);
  stage(1, 1);

  int bR = 0;
  for (int it = 0; it < NT; ++it) {
    if (it + 1 < NT) { asm volatile("s_waitcnt vmcnt(4)" ::: "memory"); }
    else             { asm volatile("s_waitcnt vmcnt(0)" ::: "memory"); }
    __builtin_amdgcn_s_barrier();
    asm volatile("" ::: "memory");

    int bW = bR + 2; if (bW >= 3) bW -= 3;
    if (it + 2 < NT) stage(it + 2, bW);

    const u16* la = (const u16*)(lds + bR * 16384);
    const u16* lb = (const u16*)(lds + bR * 16384 + 8192);
    bf16x8 av[4], bv[4];
#pragma unroll
    for (int mi = 0; mi < 4; ++mi)
      av[mi] = *(const bf16x8*)&la[(wr * 64 + mi * 16 + fr) * 32 + fk];
#pragma unroll
    for (int ni = 0; ni < 4; ++ni)
      bv[ni] = *(const bf16x8*)&lb[(wc * 64 + ni * 16 + fr) * 32 + fk];

    __builtin_amdgcn_s_setprio(1);
#pragma unroll
    for (int mi = 0; mi < 4; ++mi)
#pragma unroll
      for (int ni = 0; ni < 4; ++ni)
        acc[mi][ni] = __builtin_amdgcn_mfma_f32_16x16x32_bf16(av[mi], bv[ni], acc[mi][ni], 0, 0, 0);
    __builtin_amdgcn_s_setprio(0);

    bR = (bR + 1 == 3) ? 0 : bR + 1;
  }

  const int fq = lane >> 4;

  if (BCAST16) {
    // apply alpha+bias in registers, then two 64-row stripes:
    // stage stripe in LDS [64][132] fp32 (33.8KB), then broadcast-write
    // out[n][l][d] with consecutive-tid -> consecutive-address f32x4 NT.
    float* tf = (float*)lds;             // [64][132]
#pragma unroll
    for (int s = 0; s < 2; ++s) {
      __syncthreads();                   // staging bufs / prev stripe free
      if (wr == s) {
#pragma unroll
        for (int mi = 0; mi < 4; ++mi)
#pragma unroll
          for (int ni = 0; ni < 4; ++ni) {
            int cl = wc * 64 + ni * 16 + fr;
            float bb = bias ? bias[bcol + cl] : 0.f;
#pragma unroll
            for (int r = 0; r < 4; ++r) {
              int rl = mi * 16 + fq * 4 + r;   // 0..63
              tf[rl * 132 + cl] = acc[mi][ni][r] * alpha + bb;
            }
          }
      }
      __syncthreads();
      // 64 rows x 16 copies x 128 floats = 32768 f32x4 / 256 thr = 128 each
      f32x4* O = (f32x4*)Cf;             // Cf = out base (fp32)
#pragma unroll 4
      for (int p = 0; p < 128; ++p) {
        int idx = p * 256 + t;
        int within = idx & 31;           // f32x4 within 512B segment
        int seg = idx >> 5;              // 0..1023
        int l = seg & 15, rl = seg >> 4;
        f32x4 v = *(const f32x4*)&tf[rl * 132 + within * 4];
        size_t o4 = ((size_t)(brow + s * 64 + rl) * 16 + l) * 192 + (bcol >> 2) + within;
        __builtin_nontemporal_store(v, &O[o4]);
      }
    }
    return;
  }

  u16* tileT = (u16*)lds;                // [128 cols][130] when TRANST
  if (TRANST) __syncthreads();           // all waves done reading lds bufs

#pragma unroll
  for (int mi = 0; mi < 4; ++mi) {
#pragma unroll
    for (int ni = 0; ni < 4; ++ni) {
      int cl = wc * 64 + ni * 16 + fr;
      int col = bcol + cl;
      float bb = bias ? bias[col] : 0.f;
#pragma unroll
      for (int r = 0; r < 4; ++r) {
        int rl = wr * 64 + mi * 16 + fq * 4 + r;
        int row = brow + rl;
        float v = acc[mi][ni][r] * alpha + bb;
        if (RELU) v = fmaxf(v, 0.f);
        if (BF16OUT) {
          u16 bf = f2bf(v);
          Cb[(size_t)row * N + col] = bf;
          if (TRANST) tileT[cl * 130 + rl] = bf;
        } else {
          Cf[(size_t)row * N + col] = v;
        }
      }
    }
  }

  if (TRANST) {
    __syncthreads();
    int c2 = t >> 1, off = (t & 1) * 64;
    size_t base = (size_t)(bcol + c2) * ldt + brow + off;
#pragma unroll
    for (int j = 0; j < 8; ++j)
      *(bf16x8*)&Ct[base + j * 8] = *(const bf16x8*)&tileT[c2 * 130 + off + j * 8];
  }
}

// -- LayerNorm rows (D=768): sum 2 split-K partials, scale by 1/denom, LN -----
__global__ __launch_bounds__(256) void ln2_kernel(
    const float* __restrict__ X, long long ps, const float* __restrict__ dsum,
    const float* __restrict__ g, const float* __restrict__ b,
    u16* __restrict__ Y)
{
  __shared__ float red[4];
  int row = blockIdx.x, t = threadIdx.x;
  const float* x = X + (size_t)row * 768;
  const f32x4* dv = (const f32x4*)(dsum + (size_t)row * 16);
  f32x4 d4 = dv[0] + dv[1] + dv[2] + dv[3];
  float inv_d = 1.f / (d4.x + d4.y + d4.z + d4.w);

  float v0 = (x[t]       + x[ps + t])       * inv_d;
  float v1 = (x[t + 256] + x[ps + t + 256]) * inv_d;
  float v2 = (x[t + 512] + x[ps + t + 512]) * inv_d;

  float s = v0 + v1 + v2;
#pragma unroll
  for (int off = 32; off > 0; off >>= 1) s += __shfl_xor(s, off);
  if ((t & 63) == 0) red[t >> 6] = s;
  __syncthreads();
  float mu = (red[0] + red[1] + red[2] + red[3]) * (1.f / 768.f);
  __syncthreads();

  float d0 = v0 - mu, d1 = v1 - mu, d2 = v2 - mu;
  float q = d0 * d0 + d1 * d1 + d2 * d2;
#pragma unroll
  for (int off = 32; off > 0; off >>= 1) q += __shfl_xor(q, off);
  if ((t & 63) == 0) red[t >> 6] = q;
  __syncthreads();
  float var = (red[0] + red[1] + red[2] + red[3]) * (1.f / 768.f);
  float inv = rsqrtf(var + 1e-5f);

  u16* y = Y + (size_t)row * 768;
  y[t]       = f2bf(d0 * inv * g[t]       + b[t]);
  y[t + 256] = f2bf(d1 * inv * g[t + 256] + b[t + 256]);
  y[t + 512] = f2bf(d2 * inv * g[t + 512] + b[t + 512]);
}

extern "C" void kernel_launch(void* const* d_in, const int* in_sizes, int n_in,
                              void* d_out, int out_size, void* d_ws, size_t ws_size,
                              hipStream_t stream)
{
  const float* vision = (const float*)d_in[0];
  const float* text   = (const float*)d_in[1];
  const float* fc_w   = (const float*)d_in[2];
  const float* fc_b   = (const float*)d_in[3];
  const float* ln_g   = (const float*)d_in[4];
  const float* ln_b   = (const float*)d_in[5];
  const float* w1     = (const float*)d_in[6];
  const float* b1     = (const float*)d_in[7];
  const float* w2     = (const float*)d_in[8];
  const float* b2     = (const float*)d_in[9];
  float* out = (float*)d_out;

  const int N = 4096, M = 4096, Din = 512, D = 768, Dhp = 256;

  char* p = (char*)d_ws;
  auto alloc = [&](size_t bytes) { char* r = p; p += (bytes + 255) & ~(size_t)255; return r; };
  u16*   mean_v = (u16*)alloc((size_t)N * D * 2);
  u16*   mean_t = (u16*)alloc((size_t)M * Din * 2);
  u16*   fcw_bf = (u16*)alloc((size_t)D * Din * 2);
  u16*   w1p    = (u16*)alloc((size_t)Dhp * D * 2);
  u16*   w2p    = (u16*)alloc((size_t)D * Dhp * 2);
  float* b1p    = (float*)alloc((size_t)Dhp * 4);
  float* dsum   = (float*)alloc((size_t)N * 16 * 4);
  u16*   t_bf   = (u16*)alloc((size_t)M * D * 2);
  u16*   tT_bf  = (u16*)alloc((size_t)D * M * 2);
  u16*   aff    = (u16*)alloc((size_t)N * M * 2);   // exp(scores), unnormalized
  u16*   ln_o   = (u16*)alloc((size_t)N * D * 2);
  u16*   h1     = (u16*)alloc((size_t)N * Dhp * 2);
  float* aggp   = (float*)alloc((size_t)2 * N * D * 4);  // 2 split-K partials

  // 1. fused prologue: means + weight casts/pads
  {
    int total = 4096 * 192 + 4096 * 128 + 768 * 512 + 256 * 768 + 768 * 256 + 256;
    prologue_kernel<<<(total + 255) / 256, 256, 0, stream>>>(
        vision, text, fc_w, w1, w2, b1, mean_v, mean_t, fcw_bf, w1p, w2p, b1p);
  }

  // 2. t = mean_t @ fc_w^T + fc_b  [M, D] bf16 + fused transpose tT [D, M]
  gemm_nt<false, true, true, false><<<dim3(D / 128, M / 128), 256, 0, stream>>>(
      mean_t, fcw_bf, fc_b, 1.f, nullptr, t_bf, tT_bf, M, M, D, Din, Din, Din, 0, 0);

  // 3. aff = exp(mean_v @ t^T / sqrt(D))  [N, M] bf16 + fused row-sum partials
  gemm256_exp_bf16<<<dim3(M / 256, N / 256), 512, 0, stream>>>(
      mean_v, t_bf, 1.f / sqrtf(768.f), aff, dsum, M, D, D, D);

  // 4. agg~ = aff @ t  [N, D] fp32, split-K=2 partials (B = tT, NT form)
  gemm_nt<false, false, false, false><<<dim3(D / 128, N / 128, 2), 256, 0, stream>>>(
      aff, tT_bf, nullptr, 1.f, aggp, nullptr, nullptr, 0, N, D, M / 2, M, M,
      M / 2, (long long)N * D);

  // 5. LayerNorm of (partial-sum / denom) -> bf16
  ln2_kernel<<<N, 256, 0, stream>>>(aggp, (long long)N * D, dsum, ln_g, ln_b, ln_o);

  // 6. h1 = relu(ln @ w1^T + b1)   [N, Dhp] bf16  (padded 192->256)
  gemm_nt<true, true, false, false><<<dim3(Dhp / 128, N / 128), 256, 0, stream>>>(
      ln_o, w1p, b1p, 1.f, nullptr, h1, nullptr, 0, N, Dhp, D, D, D, 0, 0);

  // 7. h2 = h1 @ w2^T + b2, broadcast-written to out[N][16][768]
  //    (LDS-staged stripes, fully-coalesced f32x4 NT stores)
  gemm_nt<false, false, false, true><<<dim3(D / 128, N / 128), 256, 0, stream>>>(
      h1, w2p, b2, 1.f, out, nullptr, nullptr, 0, N, D, Dhp, Dhp, Dhp, 0, 0);
}